// Round 5
// baseline (352.718 us; speedup 1.0000x reference)
//
#include <hip/hip_runtime.h>
#include <math.h>

#define NN 50
#define E2 400
#define ET 450
#define NTHR 256
#define KL 32            // Lanczos iterations (deflated space is 49-dim)

// Intra-wave LDS handoff fence: drain LDS ops, forbid compiler reordering.
#define WSYNC() do { asm volatile("s_waitcnt lgkmcnt(0)" ::: "memory"); \
                     __builtin_amdgcn_sched_barrier(0); } while (0)

__global__ __launch_bounds__(NTHR) void opn_kernel(
    const float* __restrict__ gx, const int* __restrict__ gedge,
    const float* __restrict__ gmask,
    const float* __restrict__ w1, const float* __restrict__ as1,
    const float* __restrict__ ad1, const float* __restrict__ b1,
    const float* __restrict__ w2, const float* __restrict__ as2,
    const float* __restrict__ ad2, const float* __restrict__ b2,
    const float* __restrict__ miw, const float* __restrict__ mib,
    const float* __restrict__ mow, const float* __restrict__ mob,
    const float* __restrict__ wq, const float* __restrict__ bq,
    const float* __restrict__ wk, const float* __restrict__ bk,
    const float* __restrict__ wv, const float* __restrict__ bv,
    const float* __restrict__ ws, const float* __restrict__ bs,
    const float* __restrict__ mw1, const float* __restrict__ mb1,
    const float* __restrict__ mw2, const float* __restrict__ mb2,
    const float* __restrict__ cw, const float* __restrict__ cb,
    float* __restrict__ out)
{
    const int tid = threadIdx.x;

    __shared__ float sM[NN * NN];    // A -> L (kept through Lanczos) -> attn -> logits
    __shared__ float sS[3200];       // GAT1 h8/o8 -> MLP hid64
    __shared__ float sQ[(KL + 2) * NN];  // q_0 = u0, q_1..q_K Lanczos vectors
    __shared__ float sW[NN];         // Fiedler scratch
    __shared__ float sAl_[KL + 2];   // T diagonal (alpha)
    __shared__ float sBe_[KL + 2];   // T off-diagonal (beta)
    __shared__ float sY[KL + 2];     // T eigenvector
    __shared__ float sCp[KL + 2];    // Thomas temp
    __shared__ float sDp2[KL + 2];   // Thomas temp
    __shared__ float sTh[2];         // theta
    __shared__ int   sKeff;
    __shared__ float sX[NN * 5];
    __shared__ float sH5a[NN * 5];
    __shared__ float sH5b[NN * 5];
    __shared__ float sH5c[NN * 5];
    __shared__ float sH5d[NN * 5];
    __shared__ int   sSrc[ET];
    __shared__ int   sDst[ET];
    __shared__ float sE[ET];
    __shared__ float sAl[ET];
    __shared__ float sNm[NN];
    __shared__ float sNs[NN];
    __shared__ float sAs[NN];
    __shared__ float sAd[NN];
    __shared__ float sdis[NN];
    __shared__ float sred[NTHR];
    __shared__ int   sOff[NN + 1];
    __shared__ int   sCnt[NN];
    __shared__ int   sEid[ET];

    // ---------------- edges (with self loops) + adjacency ----------------
    for (int t = tid; t < ET; t += NTHR) {
        int s, d;
        if (t < E2) { s = gedge[t]; d = gedge[E2 + t]; }
        else        { s = t - E2;   d = t - E2; }
        sSrc[t] = s; sDst[t] = d;
    }
    for (int t = tid; t < NN * NN; t += NTHR) sM[t] = 0.0f;
    for (int i = tid; i < NN; i += NTHR) sCnt[i] = 0;
    if (tid == 0) sKeff = KL;
    __syncthreads();
    for (int t = tid; t < E2; t += NTHR)
        atomicAdd(&sM[sSrc[t] * NN + sDst[t]], 1.0f);
    for (int e = tid; e < ET; e += NTHR)
        atomicAdd(&sCnt[sDst[e]], 1);
    __syncthreads();

    // CSR by dst
    if (tid == 0) {
        int acc = 0;
        for (int i = 0; i < NN; ++i) { sOff[i] = acc; acc += sCnt[i]; }
        sOff[NN] = acc;
    }
    __syncthreads();
    if (tid < NN) {
        int pos = sOff[tid];
        for (int e = 0; e < ET; ++e)
            if (sDst[e] == tid) sEid[pos++] = e;
    }

    // ---------------- degree, u0 raw, Laplacian ----------------
    for (int i = tid; i < NN; i += NTHR) {
        float dsum = 0.0f;
        for (int j = 0; j < NN; ++j) dsum += sM[i * NN + j];
        sdis[i] = (dsum > 0.0f) ? (1.0f / sqrtf(fmaxf(dsum, 1e-12f))) : 0.0f;
        sQ[i] = sqrtf(dsum);   // u0 raw = sqrt(deg)
    }
    __syncthreads();
    for (int t = tid; t < NN * NN; t += NTHR) {
        int i = t / NN, j = t % NN;
        sM[t] = ((i == j) ? 1.0f : 0.0f) - sdis[i] * sM[t] * sdis[j];
    }
    // normalize u0; deterministic start q1 orthogonal to u0 (CGS2)
    if (tid < 64) {
        float q0 = (tid < NN) ? sQ[tid] : 0.0f;
        float nn = q0 * q0;
        for (int off = 32; off > 0; off >>= 1) nn += __shfl_xor(nn, off);
        q0 *= rsqrtf(nn);
        unsigned u = (unsigned)tid * 2654435761u + 12345u;
        u ^= u >> 13; u *= 2246822519u; u ^= u >> 11;
        float q1 = (tid < NN) ? ((float)(u & 0xFFFF) * (1.0f / 65536.0f) - 0.5f) : 0.0f;
        for (int pass = 0; pass < 2; ++pass) {
            float d = q0 * q1;
            for (int off = 32; off > 0; off >>= 1) d += __shfl_xor(d, off);
            q1 -= d * q0;
        }
        float n1 = q1 * q1;
        for (int off = 32; off > 0; off >>= 1) n1 += __shfl_xor(n1, off);
        q1 *= rsqrtf(n1);
        if (tid < NN) { sQ[tid] = q0; sQ[NN + tid] = q1; }
    }
    __syncthreads();

    // ---------------- Lanczos on B = 2I - L: single wave, register-resident ----------------
    // Lane i owns row i of L (50 VGPRs, compile-time indexed). Per iteration:
    // matvec = 50 broadcast LDS reads + 50 FMAs; MGS2 reorth = per-m {1 LDS
    // read, butterfly reduce, fused update}. No serial per-lane LDS walks.
    if (tid < 64) {
        const int lane = tid;
        float row[NN];
#pragma unroll
        for (int k = 0; k < NN; ++k)
            row[k] = (lane < NN) ? sM[lane * NN + k] : 0.0f;

        for (int j = 1; j <= KL; ++j) {
            const float* qj = &sQ[j * NN];
            // w_i = 2 q_i - (L q)_i
            float a0 = 0.0f, a1 = 0.0f, a2 = 0.0f, a3 = 0.0f;
#pragma unroll
            for (int k = 0; k < 48; k += 4) {
                a0 += row[k]     * qj[k];
                a1 += row[k + 1] * qj[k + 1];
                a2 += row[k + 2] * qj[k + 2];
                a3 += row[k + 3] * qj[k + 3];
            }
            a0 += row[48] * qj[48];
            a1 += row[49] * qj[49];
            float w = (lane < NN) ? (2.0f * qj[lane] - (a0 + a1 + a2 + a3)) : 0.0f;

            float alpha = 0.0f;
            // MGS, two passes, m = 0..j (deflation against q0 included)
            for (int pass = 0; pass < 2; ++pass) {
                for (int m = 0; m <= j; ++m) {
                    float qm = (lane < NN) ? sQ[m * NN + lane] : 0.0f;
                    float p = qm * w;
#pragma unroll
                    for (int off = 32; off > 0; off >>= 1) p += __shfl_xor(p, off);
                    w -= p * qm;
                    if (m == j) alpha += p;
                }
            }
            float nn2 = w * w;
#pragma unroll
            for (int off = 32; off > 0; off >>= 1) nn2 += __shfl_xor(nn2, off);
            float beta = sqrtf(nn2);
            if (lane == 0) { sAl_[j] = alpha; sBe_[j] = beta; }
            if (j < KL) {
                if (beta > 1e-10f) {
                    if (lane < NN) sQ[(j + 1) * NN + lane] = w * (1.0f / beta);
                    WSYNC();                      // visible before next matvec
                } else {
                    if (lane == 0) sKeff = j;
                    break;                        // beta uniform across lanes
                }
            }
        }
    }
    __syncthreads();

    // ---------------- top Ritz pair of T: bisection + inverse iteration ----------------
    const int keff = sKeff;
    if (tid < 64) {
        float lo = 1e30f, hi = -1e30f;
        for (int m = 1; m <= keff; ++m) {
            float r = ((m > 1) ? fabsf(sBe_[m - 1]) : 0.0f)
                    + ((m < keff) ? fabsf(sBe_[m]) : 0.0f);
            lo = fminf(lo, sAl_[m] - r);
            hi = fmaxf(hi, sAl_[m] + r);
        }
        for (int round = 0; round < 4; ++round) {
            float h = (hi - lo) * (1.0f / 65.0f);
            float x = lo + (float)(tid + 1) * h;
            int cnt = 0;
            float d = sAl_[1] - x;
            if (d < 0.0f) cnt++;
            for (int m = 2; m <= keff; ++m) {
                float b = sBe_[m - 1];
                float dd = (fabsf(d) < 1e-20f) ? ((d >= 0.0f) ? 1e-20f : -1e-20f) : d;
                d = sAl_[m] - x - b * b / dd;
                if (d < 0.0f) cnt++;
            }
            unsigned long long msk = __ballot(cnt >= keff);
            int f = (msk == 0ULL) ? 64 : (__ffsll((unsigned long long)msk) - 1);
            float nlo = (f == 0) ? lo : (lo + (float)f * h);
            float nhi = (f == 64) ? hi : (lo + (float)(f + 1) * h);
            lo = nlo; hi = nhi;
        }
        if (tid == 0) sTh[0] = 0.5f * (lo + hi);
    }
    __syncthreads();
    if (tid == 0) {
        const float th = sTh[0];
        if (keff == 1) {
            sY[1] = 1.0f;
        } else {
            float inv0 = rsqrtf((float)keff);
            for (int m = 1; m <= keff; ++m) sY[m] = inv0;
            for (int it = 0; it < 2; ++it) {
                float d1 = sAl_[1] - th;
                if (fabsf(d1) < 1e-10f) d1 = (d1 >= 0.0f) ? 1e-10f : -1e-10f;
                sCp[1] = sBe_[1] / d1;
                sDp2[1] = sY[1] / d1;
                for (int m = 2; m <= keff; ++m) {
                    float den = sAl_[m] - th - sBe_[m - 1] * sCp[m - 1];
                    if (fabsf(den) < 1e-10f) den = (den >= 0.0f) ? 1e-10f : -1e-10f;
                    if (m < keff) sCp[m] = sBe_[m] / den;
                    sDp2[m] = (sY[m] - sBe_[m - 1] * sDp2[m - 1]) / den;
                }
                sY[keff] = sDp2[keff];
                for (int m = keff - 1; m >= 1; --m)
                    sY[m] = sDp2[m] - sCp[m] * sY[m + 1];
                float nn = 0.0f;
                for (int m = 1; m <= keff; ++m) nn += sY[m] * sY[m];
                float sc = rsqrtf(nn);
                for (int m = 1; m <= keff; ++m) sY[m] *= sc;
            }
        }
    }
    __syncthreads();
    // Fiedler = Q(1..keff) y, normalize, canonical sign (max-|entry| positive)
    if (tid < NN) {
        float acc = 0.0f;
        for (int m = 1; m <= keff; ++m) acc += sY[m] * sQ[m * NN + tid];
        sW[tid] = acc;
    }
    __syncthreads();
    if (tid < 64) {
        float v = (tid < NN) ? sW[tid] : 0.0f;
        float nn = v * v;
        for (int off = 32; off > 0; off >>= 1) nn += __shfl_xor(nn, off);
        float av = fabsf(v);
        for (int off = 32; off > 0; off >>= 1) av = fmaxf(av, __shfl_xor(av, off));
        unsigned long long msk = __ballot((fabsf(v) == av) && (tid < NN));
        int fl = __ffsll((unsigned long long)msk) - 1;
        float sv = __shfl(v, fl);
        float scale = ((sv >= 0.0f) ? 1.0f : -1.0f) * rsqrtf(nn);
        if (tid < NN) sW[tid] = v * scale;
    }
    __syncthreads();
    for (int i = tid; i < NN; i += NTHR) {
        sX[i * 5 + 0] = gx[i * 3 + 0];
        sX[i * 5 + 1] = gx[i * 3 + 1];
        sX[i * 5 + 2] = gx[i * 3 + 2];
        sX[i * 5 + 3] = sQ[i];    // u0 (all-positive, unit norm)
        sX[i * 5 + 4] = sW[i];    // Fiedler
    }
    __syncthreads();

    // ---------------- GAT layer 1 (5 -> 8) + ReLU ----------------
    float* h8 = sS;          // 50x8
    float* o8 = sS + 1600;   // 50x8
    for (int t = tid; t < NN * 8; t += NTHR) {
        int i = t >> 3, o = t & 7;
        float acc = 0.0f;
        for (int k = 0; k < 5; ++k) acc += sX[i * 5 + k] * w1[o * 5 + k];
        h8[t] = acc;
    }
    __syncthreads();
    for (int i = tid; i < NN; i += NTHR) {
        float a = 0.0f, b = 0.0f;
        for (int o = 0; o < 8; ++o) {
            a += h8[i * 8 + o] * as1[o];
            b += h8[i * 8 + o] * ad1[o];
        }
        sAs[i] = a; sAd[i] = b;
    }
    __syncthreads();
    for (int e = tid; e < ET; e += NTHR) {
        float v = sAs[sSrc[e]] + sAd[sDst[e]];
        sE[e] = (v > 0.0f) ? v : 0.2f * v;
    }
    __syncthreads();
    for (int i = tid; i < NN; i += NTHR) {
        float m = -1e30f;
        for (int o = sOff[i]; o < sOff[i + 1]; ++o) m = fmaxf(m, sE[sEid[o]]);
        float su = 0.0f;
        for (int o = sOff[i]; o < sOff[i + 1]; ++o) su += expf(sE[sEid[o]] - m);
        sNm[i] = m; sNs[i] = su;
    }
    __syncthreads();
    for (int e = tid; e < ET; e += NTHR)
        sAl[e] = expf(sE[e] - sNm[sDst[e]]) / (sNs[sDst[e]] + 1e-16f);
    __syncthreads();
    for (int t = tid; t < NN * 8; t += NTHR) {
        int i = t >> 3, o = t & 7;
        float acc = b1[o];
        for (int c = sOff[i]; c < sOff[i + 1]; ++c) {
            int e = sEid[c];
            acc += sAl[e] * h8[sSrc[e] * 8 + o];
        }
        o8[t] = fmaxf(acc, 0.0f);
    }
    __syncthreads();

    // ---------------- GAT layer 2 (8 -> 5) ----------------
    for (int t = tid; t < NN * 5; t += NTHR) {
        int i = t / 5, o = t % 5;
        float acc = 0.0f;
        for (int k = 0; k < 8; ++k) acc += o8[i * 8 + k] * w2[o * 8 + k];
        sH5a[t] = acc;
    }
    __syncthreads();
    for (int i = tid; i < NN; i += NTHR) {
        float a = 0.0f, b = 0.0f;
        for (int o = 0; o < 5; ++o) {
            a += sH5a[i * 5 + o] * as2[o];
            b += sH5a[i * 5 + o] * ad2[o];
        }
        sAs[i] = a; sAd[i] = b;
    }
    __syncthreads();
    for (int e = tid; e < ET; e += NTHR) {
        float v = sAs[sSrc[e]] + sAd[sDst[e]];
        sE[e] = (v > 0.0f) ? v : 0.2f * v;
    }
    __syncthreads();
    for (int i = tid; i < NN; i += NTHR) {
        float m = -1e30f;
        for (int o = sOff[i]; o < sOff[i + 1]; ++o) m = fmaxf(m, sE[sEid[o]]);
        float su = 0.0f;
        for (int o = sOff[i]; o < sOff[i + 1]; ++o) su += expf(sE[sEid[o]] - m);
        sNm[i] = m; sNs[i] = su;
    }
    __syncthreads();
    for (int e = tid; e < ET; e += NTHR)
        sAl[e] = expf(sE[e] - sNm[sDst[e]]) / (sNs[sDst[e]] + 1e-16f);
    __syncthreads();
    for (int t = tid; t < NN * 5; t += NTHR) {
        int i = t / 5, o = t % 5;
        float acc = b2[o];
        for (int c = sOff[i]; c < sOff[i + 1]; ++c) {
            int e = sEid[c];
            acc += sAl[e] * sH5a[sSrc[e] * 5 + o];
        }
        sH5b[t] = acc;
    }
    __syncthreads();

    // ---------------- MultiheadAttention (1 head, seq=N) ----------------
    for (int t = tid; t < NN * 15; t += NTHR) {
        int i = t / 15, o = t % 15;
        float acc = mib[o];
        for (int k = 0; k < 5; ++k) acc += sH5b[i * 5 + k] * miw[o * 5 + k];
        if (o < 5)       sH5c[i * 5 + o] = acc;        // q
        else if (o < 10) sH5d[i * 5 + (o - 5)] = acc;  // k
        else             sH5a[i * 5 + (o - 10)] = acc; // v
    }
    __syncthreads();
    const float inv_sqrt5 = 0.4472135954999579f;
    for (int t = tid; t < NN * NN; t += NTHR) {
        int i = t / NN, j = t % NN;
        float acc = 0.0f;
        for (int k = 0; k < 5; ++k) acc += sH5c[i * 5 + k] * sH5d[j * 5 + k];
        sM[t] = acc * inv_sqrt5;
    }
    __syncthreads();
    for (int i = tid; i < NN; i += NTHR) {
        float m = -1e30f;
        for (int j = 0; j < NN; ++j) m = fmaxf(m, sM[i * NN + j]);
        float su = 0.0f;
        for (int j = 0; j < NN; ++j) su += expf(sM[i * NN + j] - m);
        float inv = 1.0f / su;
        for (int j = 0; j < NN; ++j)
            sM[i * NN + j] = expf(sM[i * NN + j] - m) * inv;
    }
    __syncthreads();
    for (int t = tid; t < NN * 5; t += NTHR) {
        int i = t / 5, f = t % 5;
        float acc = 0.0f;
        for (int j = 0; j < NN; ++j) acc += sM[i * NN + j] * sH5a[j * 5 + f];
        sH5c[t] = acc;  // attn @ v
    }
    __syncthreads();
    for (int t = tid; t < NN * 5; t += NTHR) {
        int i = t / 5, o = t % 5;
        float acc = mob[o];
        for (int k = 0; k < 5; ++k) acc += sH5c[i * 5 + k] * mow[o * 5 + k];
        sH5d[t] = acc;  // hM
    }
    __syncthreads();

    // ---------------- TransformerConv ----------------
    for (int t = tid; t < NN * 5; t += NTHR) {
        int i = t / 5, o = t % 5;
        float q_ = bq[o], k_ = bk[o], v_ = bv[o];
        for (int k = 0; k < 5; ++k) {
            float h = sH5d[i * 5 + k];
            q_ += h * wq[o * 5 + k];
            k_ += h * wk[o * 5 + k];
            v_ += h * wv[o * 5 + k];
        }
        sH5a[t] = q_; sH5b[t] = k_; sH5c[t] = v_;
    }
    __syncthreads();
    for (int e = tid; e < ET; e += NTHR) {
        float acc = 0.0f;
        int s2 = sSrc[e], d2 = sDst[e];
        for (int k = 0; k < 5; ++k) acc += sH5a[d2 * 5 + k] * sH5b[s2 * 5 + k];
        sE[e] = acc * inv_sqrt5;
    }
    __syncthreads();
    for (int i = tid; i < NN; i += NTHR) {
        float m = -1e30f;
        for (int o = sOff[i]; o < sOff[i + 1]; ++o) m = fmaxf(m, sE[sEid[o]]);
        float su = 0.0f;
        for (int o = sOff[i]; o < sOff[i + 1]; ++o) su += expf(sE[sEid[o]] - m);
        sNm[i] = m; sNs[i] = su;
    }
    __syncthreads();
    for (int e = tid; e < ET; e += NTHR)
        sAl[e] = expf(sE[e] - sNm[sDst[e]]) / (sNs[sDst[e]] + 1e-16f);
    __syncthreads();
    for (int t = tid; t < NN * 5; t += NTHR) {
        int i = t / 5, o = t % 5;
        float acc = bs[o];
        for (int k = 0; k < 5; ++k) acc += sH5d[i * 5 + k] * ws[o * 5 + k];
        for (int c = sOff[i]; c < sOff[i + 1]; ++c) {
            int e = sEid[c];
            acc += sAl[e] * sH5c[sSrc[e] * 5 + o];
        }
        sH5a[t] = acc;  // tc output
    }
    __syncthreads();

    // ---------------- MLP aggregation head ----------------
    for (int t = tid; t < NN * 64; t += NTHR) {
        int i = t >> 6, o = t & 63;
        float acc = mb1[o];
        for (int k = 0; k < 5; ++k) acc += sH5a[i * 5 + k] * mw1[o * 250 + k];
        sS[t] = fmaxf(acc, 0.0f);
    }
    __syncthreads();
    for (int t = tid; t < NN * NN; t += NTHR) {
        int i = t / NN, j = t % NN;
        float acc = mb2[j];
        for (int k = 0; k < 64; ++k) acc += sS[i * 64 + k] * mw2[j * 64 + k];
        sM[t] = acc;                 // unmasked logits (for value)
        out[t] = acc * gmask[j];     // masked logits output
    }
    __syncthreads();

    // ---------------- value (critic) ----------------
    float part = 0.0f;
    for (int t = tid; t < NN * NN; t += NTHR) part += sM[t] * cw[t % NN];
    sred[tid] = part;
    __syncthreads();
    for (int off = NTHR / 2; off > 0; off >>= 1) {
        if (tid < off) sred[tid] += sred[tid + off];
        __syncthreads();
    }
    if (tid == 0) out[2500] = sred[0] * (1.0f / NN) + cb[0];

    // ---------------- x_combined + ei outputs ----------------
    for (int t = tid; t < NN * 5; t += NTHR) out[2501 + t] = sX[t];
    for (int t = tid; t < 2 * ET; t += NTHR) {
        int row = t / ET, c2 = t % ET;
        int val = (c2 < E2) ? gedge[row * E2 + c2] : (c2 - E2);
        out[2751 + t] = (float)val;
    }
}

extern "C" void kernel_launch(void* const* d_in, const int* in_sizes, int n_in,
                              void* d_out, int out_size, void* d_ws, size_t ws_size,
                              hipStream_t stream) {
    (void)in_sizes; (void)n_in; (void)d_ws; (void)ws_size; (void)out_size;
    opn_kernel<<<1, NTHR, 0, stream>>>(
        (const float*)d_in[0], (const int*)d_in[1], (const float*)d_in[2],
        (const float*)d_in[3], (const float*)d_in[4], (const float*)d_in[5], (const float*)d_in[6],
        (const float*)d_in[7], (const float*)d_in[8], (const float*)d_in[9], (const float*)d_in[10],
        (const float*)d_in[11], (const float*)d_in[12], (const float*)d_in[13], (const float*)d_in[14],
        (const float*)d_in[15], (const float*)d_in[16], (const float*)d_in[17], (const float*)d_in[18],
        (const float*)d_in[19], (const float*)d_in[20], (const float*)d_in[21], (const float*)d_in[22],
        (const float*)d_in[23], (const float*)d_in[24], (const float*)d_in[25], (const float*)d_in[26],
        (const float*)d_in[27], (const float*)d_in[28],
        (float*)d_out);
}

// Round 6
// 170.430 us; speedup vs baseline: 2.0696x; 2.0696x over previous
//
#include <hip/hip_runtime.h>
#include <math.h>

#define NN 50
#define E2 400
#define ET 450
#define NTHR 256
#define KL 24            // Lanczos iterations (deflated space is 49-dim)
#define QS 52            // padded row stride (16B-aligned rows)

// Intra-wave LDS handoff fence: drain LDS ops, forbid compiler reordering.
#define WSYNC() do { asm volatile("s_waitcnt lgkmcnt(0)" ::: "memory"); \
                     __builtin_amdgcn_sched_barrier(0); } while (0)

__global__ __launch_bounds__(NTHR, 1) void opn_kernel(
    const float* __restrict__ gx, const int* __restrict__ gedge,
    const float* __restrict__ gmask,
    const float* __restrict__ w1, const float* __restrict__ as1,
    const float* __restrict__ ad1, const float* __restrict__ b1,
    const float* __restrict__ w2, const float* __restrict__ as2,
    const float* __restrict__ ad2, const float* __restrict__ b2,
    const float* __restrict__ miw, const float* __restrict__ mib,
    const float* __restrict__ mow, const float* __restrict__ mob,
    const float* __restrict__ wq, const float* __restrict__ bq,
    const float* __restrict__ wk, const float* __restrict__ bk,
    const float* __restrict__ wv, const float* __restrict__ bv,
    const float* __restrict__ ws, const float* __restrict__ bs,
    const float* __restrict__ mw1, const float* __restrict__ mb1,
    const float* __restrict__ mw2, const float* __restrict__ mb2,
    const float* __restrict__ cw, const float* __restrict__ cb,
    float* __restrict__ out)
{
    const int tid = threadIdx.x;

    __shared__ float sM[NN * NN];    // A -> L -> attn -> logits
    __shared__ float sS[3200];       // GAT1 h8/o8 -> MLP hid64
    __shared__ alignas(16) float sL[NN * QS];        // padded L rows (16B-aligned)
    __shared__ alignas(16) float sQ2[(KL + 2) * QS]; // Lanczos vectors, padded rows
    __shared__ float sW[NN];         // Fiedler scratch
    __shared__ float sAl_[KL + 2];   // T diagonal (alpha)
    __shared__ float sBe_[KL + 2];   // T off-diagonal (beta)
    __shared__ float sY[KL + 2];     // T eigenvector
    __shared__ float sCp[KL + 2];    // Thomas temp
    __shared__ float sDp2[KL + 2];   // Thomas temp
    __shared__ float sTh[2];         // theta
    __shared__ int   sKeff;
    __shared__ float sX[NN * 5];
    __shared__ float sH5a[NN * 5];
    __shared__ float sH5b[NN * 5];
    __shared__ float sH5c[NN * 5];
    __shared__ float sH5d[NN * 5];
    __shared__ int   sSrc[ET];
    __shared__ int   sDst[ET];
    __shared__ float sE[ET];
    __shared__ float sAl[ET];
    __shared__ float sNm[NN];
    __shared__ float sNs[NN];
    __shared__ float sAs[NN];
    __shared__ float sAd[NN];
    __shared__ float sdis[NN];
    __shared__ float sred[NTHR];
    __shared__ int   sOff[NN + 1];
    __shared__ int   sCnt[NN];
    __shared__ int   sEid[ET];

    // ---------------- edges (with self loops) + adjacency ----------------
    for (int t = tid; t < ET; t += NTHR) {
        int s, d;
        if (t < E2) { s = gedge[t]; d = gedge[E2 + t]; }
        else        { s = t - E2;   d = t - E2; }
        sSrc[t] = s; sDst[t] = d;
    }
    for (int t = tid; t < NN * NN; t += NTHR) sM[t] = 0.0f;
    for (int i = tid; i < NN; i += NTHR) sCnt[i] = 0;
    if (tid == 0) sKeff = KL;
    __syncthreads();
    for (int t = tid; t < E2; t += NTHR)
        atomicAdd(&sM[sSrc[t] * NN + sDst[t]], 1.0f);
    for (int e = tid; e < ET; e += NTHR)
        atomicAdd(&sCnt[sDst[e]], 1);
    __syncthreads();

    // CSR by dst (deterministic)
    if (tid == 0) {
        int acc = 0;
        for (int i = 0; i < NN; ++i) { sOff[i] = acc; acc += sCnt[i]; }
        sOff[NN] = acc;
    }
    __syncthreads();
    if (tid < NN) {
        int pos = sOff[tid];
        for (int e = 0; e < ET; ++e)
            if (sDst[e] == tid) sEid[pos++] = e;
    }

    // ---------------- degree, u0 raw, Laplacian ----------------
    for (int i = tid; i < NN; i += NTHR) {
        float dsum = 0.0f;
        for (int j = 0; j < NN; ++j) dsum += sM[i * NN + j];
        sdis[i] = (dsum > 0.0f) ? (1.0f / sqrtf(fmaxf(dsum, 1e-12f))) : 0.0f;
        sQ2[i] = sqrtf(dsum);   // u0 raw = sqrt(deg), row 0
    }
    __syncthreads();
    for (int t = tid; t < NN * NN; t += NTHR) {
        int i = t / NN, j = t % NN;
        sM[t] = ((i == j) ? 1.0f : 0.0f) - sdis[i] * sM[t] * sdis[j];
    }
    __syncthreads();
    // padded copy of L for vectorized Lanczos matvec
    for (int t = tid; t < NN * QS; t += NTHR) {
        int i = t / QS, k = t % QS;
        sL[t] = (k < NN) ? sM[i * NN + k] : 0.0f;
    }
    // normalize u0; deterministic start q1 orthogonal to u0
    if (tid < 64) {
        float q0 = (tid < NN) ? sQ2[tid] : 0.0f;
        float nn = q0 * q0;
        for (int off = 32; off > 0; off >>= 1) nn += __shfl_xor(nn, off);
        q0 *= rsqrtf(nn);
        unsigned u = (unsigned)tid * 2654435761u + 12345u;
        u ^= u >> 13; u *= 2246822519u; u ^= u >> 11;
        float q1 = (tid < NN) ? ((float)(u & 0xFFFF) * (1.0f / 65536.0f) - 0.5f) : 0.0f;
        for (int pass = 0; pass < 2; ++pass) {
            float d = q0 * q1;
            for (int off = 32; off > 0; off >>= 1) d += __shfl_xor(d, off);
            q1 -= d * q0;
        }
        float n1 = q1 * q1;
        for (int off = 32; off > 0; off >>= 1) n1 += __shfl_xor(n1, off);
        q1 *= rsqrtf(n1);
        if (tid < NN) { sQ2[tid] = q0; sQ2[QS + tid] = q1; }
    }
    __syncthreads();

    // ---------------- Lanczos on B = 2I - L: single wave, batched LDS ----------------
    // Matvec: 13+13 independent ds_read_b128 (row + broadcast q), no arrays.
    // Reorth: CGS2, groups of 4 independent {read, mul, 6-stage butterfly, update}.
    if (tid < 64) {
        const int lane = tid;
        for (int j = 1; j <= KL; ++j) {
            const float* qp = &sQ2[j * QS];
            float w = 0.0f;
            if (lane < NN) {
                const float* rp = &sL[lane * QS];
                float a0 = 0.0f, a1 = 0.0f, a2 = 0.0f, a3 = 0.0f;
#pragma unroll
                for (int k = 0; k < 48; k += 4) {
                    float4 r = *(const float4*)(rp + k);
                    float4 q = *(const float4*)(qp + k);
                    a0 += r.x * q.x; a1 += r.y * q.y;
                    a2 += r.z * q.z; a3 += r.w * q.w;
                }
                float2 rt = *(const float2*)(rp + 48);
                float2 qt = *(const float2*)(qp + 48);
                a0 += rt.x * qt.x; a1 += rt.y * qt.y;
                w = 2.0f * qp[lane] - (a0 + a1 + a2 + a3);
            }
            float alpha = 0.0f;
            for (int pass = 0; pass < 2; ++pass) {
                const float w0 = w;
                int m = 0;
                for (; m + 4 <= j + 1; m += 4) {
                    float qa = (lane < NN) ? sQ2[(m + 0) * QS + lane] : 0.0f;
                    float qb = (lane < NN) ? sQ2[(m + 1) * QS + lane] : 0.0f;
                    float qc = (lane < NN) ? sQ2[(m + 2) * QS + lane] : 0.0f;
                    float qd = (lane < NN) ? sQ2[(m + 3) * QS + lane] : 0.0f;
                    float pa = qa * w0, pb = qb * w0, pc = qc * w0, pd = qd * w0;
#pragma unroll
                    for (int off = 32; off > 0; off >>= 1) {
                        pa += __shfl_xor(pa, off);
                        pb += __shfl_xor(pb, off);
                        pc += __shfl_xor(pc, off);
                        pd += __shfl_xor(pd, off);
                    }
                    w -= pa * qa + pb * qb + pc * qc + pd * qd;
                    if (m + 3 == j) alpha += pd;   // only m+3 can equal j here
                }
                for (; m <= j; ++m) {
                    float qa = (lane < NN) ? sQ2[m * QS + lane] : 0.0f;
                    float p = qa * w0;
#pragma unroll
                    for (int off = 32; off > 0; off >>= 1) p += __shfl_xor(p, off);
                    w -= p * qa;
                    if (m == j) alpha += p;
                }
            }
            float nn2 = w * w;
#pragma unroll
            for (int off = 32; off > 0; off >>= 1) nn2 += __shfl_xor(nn2, off);
            float beta = sqrtf(nn2);
            if (lane == 0) { sAl_[j] = alpha; sBe_[j] = beta; }
            if (j < KL) {
                if (beta > 1e-10f) {
                    if (lane < NN) sQ2[(j + 1) * QS + lane] = w * (1.0f / beta);
                    WSYNC();                      // visible before next matvec
                } else {
                    if (lane == 0) sKeff = j;
                    break;                        // beta uniform across lanes
                }
            }
        }
    }
    __syncthreads();

    // ---------------- top Ritz pair of T: bisection + inverse iteration ----------------
    const int keff = sKeff;
    if (tid < 64) {
        float lo = 1e30f, hi = -1e30f;
        for (int m = 1; m <= keff; ++m) {
            float r = ((m > 1) ? fabsf(sBe_[m - 1]) : 0.0f)
                    + ((m < keff) ? fabsf(sBe_[m]) : 0.0f);
            lo = fminf(lo, sAl_[m] - r);
            hi = fmaxf(hi, sAl_[m] + r);
        }
        for (int round = 0; round < 4; ++round) {
            float h = (hi - lo) * (1.0f / 65.0f);
            float x = lo + (float)(tid + 1) * h;
            int cnt = 0;
            float d = sAl_[1] - x;
            if (d < 0.0f) cnt++;
            for (int m = 2; m <= keff; ++m) {
                float b = sBe_[m - 1];
                float dd = (fabsf(d) < 1e-20f) ? ((d >= 0.0f) ? 1e-20f : -1e-20f) : d;
                d = sAl_[m] - x - b * b / dd;
                if (d < 0.0f) cnt++;
            }
            unsigned long long msk = __ballot(cnt >= keff);
            int f = (msk == 0ULL) ? 64 : (__ffsll((unsigned long long)msk) - 1);
            float nlo = (f == 0) ? lo : (lo + (float)f * h);
            float nhi = (f == 64) ? hi : (lo + (float)(f + 1) * h);
            lo = nlo; hi = nhi;
        }
        if (tid == 0) sTh[0] = 0.5f * (lo + hi);
    }
    __syncthreads();
    if (tid == 0) {
        const float th = sTh[0];
        if (keff == 1) {
            sY[1] = 1.0f;
        } else {
            float inv0 = rsqrtf((float)keff);
            for (int m = 1; m <= keff; ++m) sY[m] = inv0;
            for (int it = 0; it < 2; ++it) {
                float d1 = sAl_[1] - th;
                if (fabsf(d1) < 1e-10f) d1 = (d1 >= 0.0f) ? 1e-10f : -1e-10f;
                sCp[1] = sBe_[1] / d1;
                sDp2[1] = sY[1] / d1;
                for (int m = 2; m <= keff; ++m) {
                    float den = sAl_[m] - th - sBe_[m - 1] * sCp[m - 1];
                    if (fabsf(den) < 1e-10f) den = (den >= 0.0f) ? 1e-10f : -1e-10f;
                    if (m < keff) sCp[m] = sBe_[m] / den;
                    sDp2[m] = (sY[m] - sBe_[m - 1] * sDp2[m - 1]) / den;
                }
                sY[keff] = sDp2[keff];
                for (int m = keff - 1; m >= 1; --m)
                    sY[m] = sDp2[m] - sCp[m] * sY[m + 1];
                float nn = 0.0f;
                for (int m = 1; m <= keff; ++m) nn += sY[m] * sY[m];
                float sc = rsqrtf(nn);
                for (int m = 1; m <= keff; ++m) sY[m] *= sc;
            }
        }
    }
    __syncthreads();
    // Fiedler = Q(1..keff) y, normalize, canonical sign (max-|entry| positive)
    if (tid < NN) {
        float acc = 0.0f;
        for (int m = 1; m <= keff; ++m) acc += sY[m] * sQ2[m * QS + tid];
        sW[tid] = acc;
    }
    __syncthreads();
    if (tid < 64) {
        float v = (tid < NN) ? sW[tid] : 0.0f;
        float nn = v * v;
        for (int off = 32; off > 0; off >>= 1) nn += __shfl_xor(nn, off);
        float av = fabsf(v);
        for (int off = 32; off > 0; off >>= 1) av = fmaxf(av, __shfl_xor(av, off));
        unsigned long long msk = __ballot((fabsf(v) == av) && (tid < NN));
        int fl = __ffsll((unsigned long long)msk) - 1;
        float sv = __shfl(v, fl);
        float scale = ((sv >= 0.0f) ? 1.0f : -1.0f) * rsqrtf(nn);
        if (tid < NN) sW[tid] = v * scale;
    }
    __syncthreads();
    for (int i = tid; i < NN; i += NTHR) {
        sX[i * 5 + 0] = gx[i * 3 + 0];
        sX[i * 5 + 1] = gx[i * 3 + 1];
        sX[i * 5 + 2] = gx[i * 3 + 2];
        sX[i * 5 + 3] = sQ2[i];   // u0 (all-positive, unit norm)
        sX[i * 5 + 4] = sW[i];    // Fiedler
    }
    __syncthreads();

    // ---------------- GAT layer 1 (5 -> 8) + ReLU ----------------
    float* h8 = sS;          // 50x8
    float* o8 = sS + 1600;   // 50x8
    for (int t = tid; t < NN * 8; t += NTHR) {
        int i = t >> 3, o = t & 7;
        float acc = 0.0f;
        for (int k = 0; k < 5; ++k) acc += sX[i * 5 + k] * w1[o * 5 + k];
        h8[t] = acc;
    }
    __syncthreads();
    for (int i = tid; i < NN; i += NTHR) {
        float a = 0.0f, b = 0.0f;
        for (int o = 0; o < 8; ++o) {
            a += h8[i * 8 + o] * as1[o];
            b += h8[i * 8 + o] * ad1[o];
        }
        sAs[i] = a; sAd[i] = b;
    }
    __syncthreads();
    for (int e = tid; e < ET; e += NTHR) {
        float v = sAs[sSrc[e]] + sAd[sDst[e]];
        sE[e] = (v > 0.0f) ? v : 0.2f * v;
    }
    __syncthreads();
    for (int i = tid; i < NN; i += NTHR) {
        float m = -1e30f;
        for (int o = sOff[i]; o < sOff[i + 1]; ++o) m = fmaxf(m, sE[sEid[o]]);
        float su = 0.0f;
        for (int o = sOff[i]; o < sOff[i + 1]; ++o) su += expf(sE[sEid[o]] - m);
        sNm[i] = m; sNs[i] = su;
    }
    __syncthreads();
    for (int e = tid; e < ET; e += NTHR)
        sAl[e] = expf(sE[e] - sNm[sDst[e]]) / (sNs[sDst[e]] + 1e-16f);
    __syncthreads();
    for (int t = tid; t < NN * 8; t += NTHR) {
        int i = t >> 3, o = t & 7;
        float acc = b1[o];
        for (int c = sOff[i]; c < sOff[i + 1]; ++c) {
            int e = sEid[c];
            acc += sAl[e] * h8[sSrc[e] * 8 + o];
        }
        o8[t] = fmaxf(acc, 0.0f);
    }
    __syncthreads();

    // ---------------- GAT layer 2 (8 -> 5) ----------------
    for (int t = tid; t < NN * 5; t += NTHR) {
        int i = t / 5, o = t % 5;
        float acc = 0.0f;
        for (int k = 0; k < 8; ++k) acc += o8[i * 8 + k] * w2[o * 8 + k];
        sH5a[t] = acc;
    }
    __syncthreads();
    for (int i = tid; i < NN; i += NTHR) {
        float a = 0.0f, b = 0.0f;
        for (int o = 0; o < 5; ++o) {
            a += sH5a[i * 5 + o] * as2[o];
            b += sH5a[i * 5 + o] * ad2[o];
        }
        sAs[i] = a; sAd[i] = b;
    }
    __syncthreads();
    for (int e = tid; e < ET; e += NTHR) {
        float v = sAs[sSrc[e]] + sAd[sDst[e]];
        sE[e] = (v > 0.0f) ? v : 0.2f * v;
    }
    __syncthreads();
    for (int i = tid; i < NN; i += NTHR) {
        float m = -1e30f;
        for (int o = sOff[i]; o < sOff[i + 1]; ++o) m = fmaxf(m, sE[sEid[o]]);
        float su = 0.0f;
        for (int o = sOff[i]; o < sOff[i + 1]; ++o) su += expf(sE[sEid[o]] - m);
        sNm[i] = m; sNs[i] = su;
    }
    __syncthreads();
    for (int e = tid; e < ET; e += NTHR)
        sAl[e] = expf(sE[e] - sNm[sDst[e]]) / (sNs[sDst[e]] + 1e-16f);
    __syncthreads();
    for (int t = tid; t < NN * 5; t += NTHR) {
        int i = t / 5, o = t % 5;
        float acc = b2[o];
        for (int c = sOff[i]; c < sOff[i + 1]; ++c) {
            int e = sEid[c];
            acc += sAl[e] * sH5a[sSrc[e] * 5 + o];
        }
        sH5b[t] = acc;
    }
    __syncthreads();

    // ---------------- MultiheadAttention (1 head, seq=N) ----------------
    for (int t = tid; t < NN * 15; t += NTHR) {
        int i = t / 15, o = t % 15;
        float acc = mib[o];
        for (int k = 0; k < 5; ++k) acc += sH5b[i * 5 + k] * miw[o * 5 + k];
        if (o < 5)       sH5c[i * 5 + o] = acc;        // q
        else if (o < 10) sH5d[i * 5 + (o - 5)] = acc;  // k
        else             sH5a[i * 5 + (o - 10)] = acc; // v
    }
    __syncthreads();
    const float inv_sqrt5 = 0.4472135954999579f;
    for (int t = tid; t < NN * NN; t += NTHR) {
        int i = t / NN, j = t % NN;
        float acc = 0.0f;
        for (int k = 0; k < 5; ++k) acc += sH5c[i * 5 + k] * sH5d[j * 5 + k];
        sM[t] = acc * inv_sqrt5;
    }
    __syncthreads();
    for (int i = tid; i < NN; i += NTHR) {
        float m = -1e30f;
        for (int j = 0; j < NN; ++j) m = fmaxf(m, sM[i * NN + j]);
        float su = 0.0f;
        for (int j = 0; j < NN; ++j) su += expf(sM[i * NN + j] - m);
        float inv = 1.0f / su;
        for (int j = 0; j < NN; ++j)
            sM[i * NN + j] = expf(sM[i * NN + j] - m) * inv;
    }
    __syncthreads();
    for (int t = tid; t < NN * 5; t += NTHR) {
        int i = t / 5, f = t % 5;
        float acc = 0.0f;
        for (int j = 0; j < NN; ++j) acc += sM[i * NN + j] * sH5a[j * 5 + f];
        sH5c[t] = acc;  // attn @ v
    }
    __syncthreads();
    for (int t = tid; t < NN * 5; t += NTHR) {
        int i = t / 5, o = t % 5;
        float acc = mob[o];
        for (int k = 0; k < 5; ++k) acc += sH5c[i * 5 + k] * mow[o * 5 + k];
        sH5d[t] = acc;  // hM
    }
    __syncthreads();

    // ---------------- TransformerConv ----------------
    for (int t = tid; t < NN * 5; t += NTHR) {
        int i = t / 5, o = t % 5;
        float q_ = bq[o], k_ = bk[o], v_ = bv[o];
        for (int k = 0; k < 5; ++k) {
            float h = sH5d[i * 5 + k];
            q_ += h * wq[o * 5 + k];
            k_ += h * wk[o * 5 + k];
            v_ += h * wv[o * 5 + k];
        }
        sH5a[t] = q_; sH5b[t] = k_; sH5c[t] = v_;
    }
    __syncthreads();
    for (int e = tid; e < ET; e += NTHR) {
        float acc = 0.0f;
        int s2 = sSrc[e], d2 = sDst[e];
        for (int k = 0; k < 5; ++k) acc += sH5a[d2 * 5 + k] * sH5b[s2 * 5 + k];
        sE[e] = acc * inv_sqrt5;
    }
    __syncthreads();
    for (int i = tid; i < NN; i += NTHR) {
        float m = -1e30f;
        for (int o = sOff[i]; o < sOff[i + 1]; ++o) m = fmaxf(m, sE[sEid[o]]);
        float su = 0.0f;
        for (int o = sOff[i]; o < sOff[i + 1]; ++o) su += expf(sE[sEid[o]] - m);
        sNm[i] = m; sNs[i] = su;
    }
    __syncthreads();
    for (int e = tid; e < ET; e += NTHR)
        sAl[e] = expf(sE[e] - sNm[sDst[e]]) / (sNs[sDst[e]] + 1e-16f);
    __syncthreads();
    for (int t = tid; t < NN * 5; t += NTHR) {
        int i = t / 5, o = t % 5;
        float acc = bs[o];
        for (int k = 0; k < 5; ++k) acc += sH5d[i * 5 + k] * ws[o * 5 + k];
        for (int c = sOff[i]; c < sOff[i + 1]; ++c) {
            int e = sEid[c];
            acc += sAl[e] * sH5c[sSrc[e] * 5 + o];
        }
        sH5a[t] = acc;  // tc output
    }
    __syncthreads();

    // ---------------- MLP aggregation head ----------------
    for (int t = tid; t < NN * 64; t += NTHR) {
        int i = t >> 6, o = t & 63;
        float acc = mb1[o];
        for (int k = 0; k < 5; ++k) acc += sH5a[i * 5 + k] * mw1[o * 250 + k];
        sS[t] = fmaxf(acc, 0.0f);
    }
    __syncthreads();
    for (int t = tid; t < NN * NN; t += NTHR) {
        int i = t / NN, j = t % NN;
        float acc = mb2[j];
        for (int k = 0; k < 64; ++k) acc += sS[i * 64 + k] * mw2[j * 64 + k];
        sM[t] = acc;                 // unmasked logits (for value)
        out[t] = acc * gmask[j];     // masked logits output
    }
    __syncthreads();

    // ---------------- value (critic) ----------------
    float part = 0.0f;
    for (int t = tid; t < NN * NN; t += NTHR) part += sM[t] * cw[t % NN];
    sred[tid] = part;
    __syncthreads();
    for (int off = NTHR / 2; off > 0; off >>= 1) {
        if (tid < off) sred[tid] += sred[tid + off];
        __syncthreads();
    }
    if (tid == 0) out[2500] = sred[0] * (1.0f / NN) + cb[0];

    // ---------------- x_combined + ei outputs ----------------
    for (int t = tid; t < NN * 5; t += NTHR) out[2501 + t] = sX[t];
    for (int t = tid; t < 2 * ET; t += NTHR) {
        int row = t / ET, c2 = t % ET;
        int val = (c2 < E2) ? gedge[row * E2 + c2] : (c2 - E2);
        out[2751 + t] = (float)val;
    }
}

extern "C" void kernel_launch(void* const* d_in, const int* in_sizes, int n_in,
                              void* d_out, int out_size, void* d_ws, size_t ws_size,
                              hipStream_t stream) {
    (void)in_sizes; (void)n_in; (void)d_ws; (void)ws_size; (void)out_size;
    opn_kernel<<<1, NTHR, 0, stream>>>(
        (const float*)d_in[0], (const int*)d_in[1], (const float*)d_in[2],
        (const float*)d_in[3], (const float*)d_in[4], (const float*)d_in[5], (const float*)d_in[6],
        (const float*)d_in[7], (const float*)d_in[8], (const float*)d_in[9], (const float*)d_in[10],
        (const float*)d_in[11], (const float*)d_in[12], (const float*)d_in[13], (const float*)d_in[14],
        (const float*)d_in[15], (const float*)d_in[16], (const float*)d_in[17], (const float*)d_in[18],
        (const float*)d_in[19], (const float*)d_in[20], (const float*)d_in[21], (const float*)d_in[22],
        (const float*)d_in[23], (const float*)d_in[24], (const float*)d_in[25], (const float*)d_in[26],
        (const float*)d_in[27], (const float*)d_in[28],
        (float*)d_out);
}

// Round 7
// 135.923 us; speedup vs baseline: 2.5950x; 1.2539x over previous
//
#include <hip/hip_runtime.h>
#include <math.h>

#define NN 50
#define E2 400
#define ET 450
#define NTHR 256
#define KL 20            // Lanczos iterations (deflated space is 49-dim)
#define QS 52            // padded row stride (16B-aligned rows)

// Intra-wave LDS handoff fence: drain LDS ops, forbid compiler reordering.
#define WSYNC() do { asm volatile("s_waitcnt lgkmcnt(0)" ::: "memory"); \
                     __builtin_amdgcn_sched_barrier(0); } while (0)

__global__ __launch_bounds__(NTHR, 1) void opn_kernel(
    const float* __restrict__ gx, const int* __restrict__ gedge,
    const float* __restrict__ gmask,
    const float* __restrict__ w1, const float* __restrict__ as1,
    const float* __restrict__ ad1, const float* __restrict__ b1,
    const float* __restrict__ w2, const float* __restrict__ as2,
    const float* __restrict__ ad2, const float* __restrict__ b2,
    const float* __restrict__ miw, const float* __restrict__ mib,
    const float* __restrict__ mow, const float* __restrict__ mob,
    const float* __restrict__ wq, const float* __restrict__ bq,
    const float* __restrict__ wk, const float* __restrict__ bk,
    const float* __restrict__ wv, const float* __restrict__ bv,
    const float* __restrict__ ws, const float* __restrict__ bs,
    const float* __restrict__ mw1, const float* __restrict__ mb1,
    const float* __restrict__ mw2, const float* __restrict__ mb2,
    const float* __restrict__ cw, const float* __restrict__ cb,
    float* __restrict__ out)
{
    const int tid = threadIdx.x;

    __shared__ float sM[NN * NN];    // A -> L -> attn -> logits
    __shared__ float sS[3200];       // GAT1 h8/o8 -> MLP hid64
    __shared__ alignas(16) float sL[NN * QS];        // padded L rows (16B-aligned)
    __shared__ alignas(16) float sQ2[(KL + 2) * QS]; // Lanczos vectors, padded rows
    __shared__ alignas(16) float sW[NN + 2];         // Lanczos work / Fiedler scratch
    __shared__ float sD[KL + 2];     // reorth coefficients
    __shared__ float sAl_[KL + 2];   // T diagonal (alpha)
    __shared__ float sBe_[KL + 2];   // T off-diagonal (beta)
    __shared__ float sY[KL + 2];     // T eigenvector
    __shared__ float sCp[KL + 2];    // Thomas temp
    __shared__ float sDp2[KL + 2];   // Thomas temp
    __shared__ float sTh[2];         // theta
    __shared__ int   sKeff;
    __shared__ float sX[NN * 5];
    __shared__ float sH5a[NN * 5];
    __shared__ float sH5b[NN * 5];
    __shared__ float sH5c[NN * 5];
    __shared__ float sH5d[NN * 5];
    __shared__ int   sSrc[ET];
    __shared__ int   sDst[ET];
    __shared__ float sE[ET];
    __shared__ float sAl[ET];
    __shared__ float sNm[NN];
    __shared__ float sNs[NN];
    __shared__ float sAs[NN];
    __shared__ float sAd[NN];
    __shared__ float sdis[NN];
    __shared__ float sred[NTHR];
    __shared__ int   sOff[NN + 1];
    __shared__ int   sCnt[NN];
    __shared__ int   sEid[ET];

    // ---------------- edges (with self loops) + adjacency ----------------
    for (int t = tid; t < ET; t += NTHR) {
        int s, d;
        if (t < E2) { s = gedge[t]; d = gedge[E2 + t]; }
        else        { s = t - E2;   d = t - E2; }
        sSrc[t] = s; sDst[t] = d;
    }
    for (int t = tid; t < NN * NN; t += NTHR) sM[t] = 0.0f;
    for (int i = tid; i < NN; i += NTHR) sCnt[i] = 0;
    if (tid == 0) sKeff = KL;
    __syncthreads();
    for (int t = tid; t < E2; t += NTHR)
        atomicAdd(&sM[sSrc[t] * NN + sDst[t]], 1.0f);
    for (int e = tid; e < ET; e += NTHR)
        atomicAdd(&sCnt[sDst[e]], 1);
    __syncthreads();

    // CSR by dst (deterministic)
    if (tid == 0) {
        int acc = 0;
        for (int i = 0; i < NN; ++i) { sOff[i] = acc; acc += sCnt[i]; }
        sOff[NN] = acc;
    }
    __syncthreads();
    if (tid < NN) {
        int pos = sOff[tid];
        for (int e = 0; e < ET; ++e)
            if (sDst[e] == tid) sEid[pos++] = e;
    }

    // ---------------- degree, u0 raw, Laplacian ----------------
    for (int i = tid; i < NN; i += NTHR) {
        float dsum = 0.0f;
        for (int j = 0; j < NN; ++j) dsum += sM[i * NN + j];
        sdis[i] = (dsum > 0.0f) ? (1.0f / sqrtf(fmaxf(dsum, 1e-12f))) : 0.0f;
        sQ2[i] = sqrtf(dsum);   // u0 raw = sqrt(deg), row 0
    }
    __syncthreads();
    for (int t = tid; t < NN * NN; t += NTHR) {
        int i = t / NN, j = t % NN;
        sM[t] = ((i == j) ? 1.0f : 0.0f) - sdis[i] * sM[t] * sdis[j];
    }
    __syncthreads();
    // padded copy of L for vectorized Lanczos matvec
    for (int t = tid; t < NN * QS; t += NTHR) {
        int i = t / QS, k = t % QS;
        sL[t] = (k < NN) ? sM[i * NN + k] : 0.0f;
    }
    // normalize u0; deterministic start q1 orthogonal to u0
    if (tid < 64) {
        float q0 = (tid < NN) ? sQ2[tid] : 0.0f;
        float nn = q0 * q0;
        for (int off = 32; off > 0; off >>= 1) nn += __shfl_xor(nn, off);
        q0 *= rsqrtf(nn);
        unsigned u = (unsigned)tid * 2654435761u + 12345u;
        u ^= u >> 13; u *= 2246822519u; u ^= u >> 11;
        float q1 = (tid < NN) ? ((float)(u & 0xFFFF) * (1.0f / 65536.0f) - 0.5f) : 0.0f;
        for (int pass = 0; pass < 2; ++pass) {
            float d = q0 * q1;
            for (int off = 32; off > 0; off >>= 1) d += __shfl_xor(d, off);
            q1 -= d * q0;
        }
        float n1 = q1 * q1;
        for (int off = 32; off > 0; off >>= 1) n1 += __shfl_xor(n1, off);
        q1 *= rsqrtf(n1);
        if (tid < NN) { sQ2[tid] = q0; sQ2[QS + tid] = q1; }
    }
    __syncthreads();

    // ---------------- Lanczos on B = 2I - L: single wave, lane-parallel dots ----------------
    // Reorth pass: (a) snapshot w -> sW; (b) lane m<=j computes c_m = q_m . w
    // via 13 ds_read_b128 row + 13 broadcast sW reads (ALL dots in parallel,
    // no shuffles); (c) lane i updates w -= sum_m c_m q_m[i]. 3 WSYNC/pass.
    if (tid < 64) {
        const int lane = tid;
        for (int j = 1; j <= KL; ++j) {
            const float* qp = &sQ2[j * QS];
            float w = 0.0f;
            if (lane < NN) {
                const float* rp = &sL[lane * QS];
                float a0 = 0.0f, a1 = 0.0f, a2 = 0.0f, a3 = 0.0f;
#pragma unroll
                for (int k = 0; k < 48; k += 4) {
                    float4 r = *(const float4*)(rp + k);
                    float4 q = *(const float4*)(qp + k);
                    a0 += r.x * q.x; a1 += r.y * q.y;
                    a2 += r.z * q.z; a3 += r.w * q.w;
                }
                float2 rt = *(const float2*)(rp + 48);
                float2 qt = *(const float2*)(qp + 48);
                a0 += rt.x * qt.x; a1 += rt.y * qt.y;
                w = 2.0f * qp[lane] - (a0 + a1 + a2 + a3);
            }
            float alpha = 0.0f;
            for (int pass = 0; pass < 2; ++pass) {
                if (lane < NN) sW[lane] = w;
                WSYNC();
                if (lane <= j) {                 // lane m: c_m = q_m . w
                    const float* qm = &sQ2[lane * QS];
                    float a0 = 0.0f, a1 = 0.0f, a2 = 0.0f, a3 = 0.0f;
#pragma unroll
                    for (int k = 0; k < 48; k += 4) {
                        float4 r = *(const float4*)(qm + k);
                        float4 x = *(const float4*)(&sW[k]);
                        a0 += r.x * x.x; a1 += r.y * x.y;
                        a2 += r.z * x.z; a3 += r.w * x.w;
                    }
                    a0 += qm[48] * sW[48];
                    a1 += qm[49] * sW[49];
                    sD[lane] = (a0 + a1) + (a2 + a3);
                }
                WSYNC();
                alpha += sD[j];
                if (lane < NN) {
                    float acc = 0.0f;
                    for (int m = 0; m <= j; ++m) acc += sD[m] * sQ2[m * QS + lane];
                    w -= acc;
                }
                WSYNC();                          // sD reads drained before next pass
            }
            float nn2 = w * w;
#pragma unroll
            for (int off = 32; off > 0; off >>= 1) nn2 += __shfl_xor(nn2, off);
            float beta = sqrtf(nn2);
            if (lane == 0) { sAl_[j] = alpha; sBe_[j] = beta; }
            if (j < KL) {
                if (beta > 1e-10f) {
                    if (lane < NN) sQ2[(j + 1) * QS + lane] = w * (1.0f / beta);
                    WSYNC();                      // visible before next matvec
                } else {
                    if (lane == 0) sKeff = j;
                    break;                        // beta uniform across lanes
                }
            }
        }
    }
    __syncthreads();

    // ---------------- top Ritz pair of T: bisection + inverse iteration ----------------
    const int keff = sKeff;
    if (tid < 64) {
        float lo = 1e30f, hi = -1e30f;
        for (int m = 1; m <= keff; ++m) {
            float r = ((m > 1) ? fabsf(sBe_[m - 1]) : 0.0f)
                    + ((m < keff) ? fabsf(sBe_[m]) : 0.0f);
            lo = fminf(lo, sAl_[m] - r);
            hi = fmaxf(hi, sAl_[m] + r);
        }
        for (int round = 0; round < 4; ++round) {
            float h = (hi - lo) * (1.0f / 65.0f);
            float x = lo + (float)(tid + 1) * h;
            int cnt = 0;
            float d = sAl_[1] - x;
            if (d < 0.0f) cnt++;
            for (int m = 2; m <= keff; ++m) {
                float b = sBe_[m - 1];
                float dd = (fabsf(d) < 1e-20f) ? ((d >= 0.0f) ? 1e-20f : -1e-20f) : d;
                d = sAl_[m] - x - b * b / dd;
                if (d < 0.0f) cnt++;
            }
            unsigned long long msk = __ballot(cnt >= keff);
            int f = (msk == 0ULL) ? 64 : (__ffsll((unsigned long long)msk) - 1);
            float nlo = (f == 0) ? lo : (lo + (float)f * h);
            float nhi = (f == 64) ? hi : (lo + (float)(f + 1) * h);
            lo = nlo; hi = nhi;
        }
        if (tid == 0) sTh[0] = 0.5f * (lo + hi);
    }
    __syncthreads();
    if (tid == 0) {
        const float th = sTh[0];
        if (keff == 1) {
            sY[1] = 1.0f;
        } else {
            float inv0 = rsqrtf((float)keff);
            for (int m = 1; m <= keff; ++m) sY[m] = inv0;
            for (int it = 0; it < 2; ++it) {
                float d1 = sAl_[1] - th;
                if (fabsf(d1) < 1e-10f) d1 = (d1 >= 0.0f) ? 1e-10f : -1e-10f;
                sCp[1] = sBe_[1] / d1;
                sDp2[1] = sY[1] / d1;
                for (int m = 2; m <= keff; ++m) {
                    float den = sAl_[m] - th - sBe_[m - 1] * sCp[m - 1];
                    if (fabsf(den) < 1e-10f) den = (den >= 0.0f) ? 1e-10f : -1e-10f;
                    if (m < keff) sCp[m] = sBe_[m] / den;
                    sDp2[m] = (sY[m] - sBe_[m - 1] * sDp2[m - 1]) / den;
                }
                sY[keff] = sDp2[keff];
                for (int m = keff - 1; m >= 1; --m)
                    sY[m] = sDp2[m] - sCp[m] * sY[m + 1];
                float nn = 0.0f;
                for (int m = 1; m <= keff; ++m) nn += sY[m] * sY[m];
                float sc = rsqrtf(nn);
                for (int m = 1; m <= keff; ++m) sY[m] *= sc;
            }
        }
    }
    __syncthreads();
    // Fiedler = Q(1..keff) y, normalize, canonical sign (max-|entry| positive)
    if (tid < NN) {
        float acc = 0.0f;
        for (int m = 1; m <= keff; ++m) acc += sY[m] * sQ2[m * QS + tid];
        sW[tid] = acc;
    }
    __syncthreads();
    if (tid < 64) {
        float v = (tid < NN) ? sW[tid] : 0.0f;
        float nn = v * v;
        for (int off = 32; off > 0; off >>= 1) nn += __shfl_xor(nn, off);
        float av = fabsf(v);
        for (int off = 32; off > 0; off >>= 1) av = fmaxf(av, __shfl_xor(av, off));
        unsigned long long msk = __ballot((fabsf(v) == av) && (tid < NN));
        int fl = __ffsll((unsigned long long)msk) - 1;
        float sv = __shfl(v, fl);
        float scale = ((sv >= 0.0f) ? 1.0f : -1.0f) * rsqrtf(nn);
        if (tid < NN) sW[tid] = v * scale;
    }
    __syncthreads();
    for (int i = tid; i < NN; i += NTHR) {
        sX[i * 5 + 0] = gx[i * 3 + 0];
        sX[i * 5 + 1] = gx[i * 3 + 1];
        sX[i * 5 + 2] = gx[i * 3 + 2];
        sX[i * 5 + 3] = sQ2[i];   // u0 (all-positive, unit norm)
        sX[i * 5 + 4] = sW[i];    // Fiedler
    }
    __syncthreads();

    // ---------------- GAT layer 1 (5 -> 8) + ReLU ----------------
    float* h8 = sS;          // 50x8
    float* o8 = sS + 1600;   // 50x8
    for (int t = tid; t < NN * 8; t += NTHR) {
        int i = t >> 3, o = t & 7;
        float acc = 0.0f;
        for (int k = 0; k < 5; ++k) acc += sX[i * 5 + k] * w1[o * 5 + k];
        h8[t] = acc;
    }
    __syncthreads();
    for (int i = tid; i < NN; i += NTHR) {
        float a = 0.0f, b = 0.0f;
        for (int o = 0; o < 8; ++o) {
            a += h8[i * 8 + o] * as1[o];
            b += h8[i * 8 + o] * ad1[o];
        }
        sAs[i] = a; sAd[i] = b;
    }
    __syncthreads();
    for (int e = tid; e < ET; e += NTHR) {
        float v = sAs[sSrc[e]] + sAd[sDst[e]];
        sE[e] = (v > 0.0f) ? v : 0.2f * v;
    }
    __syncthreads();
    for (int i = tid; i < NN; i += NTHR) {
        float m = -1e30f;
        for (int o = sOff[i]; o < sOff[i + 1]; ++o) m = fmaxf(m, sE[sEid[o]]);
        float su = 0.0f;
        for (int o = sOff[i]; o < sOff[i + 1]; ++o) su += expf(sE[sEid[o]] - m);
        sNm[i] = m; sNs[i] = su;
    }
    __syncthreads();
    for (int e = tid; e < ET; e += NTHR)
        sAl[e] = expf(sE[e] - sNm[sDst[e]]) / (sNs[sDst[e]] + 1e-16f);
    __syncthreads();
    for (int t = tid; t < NN * 8; t += NTHR) {
        int i = t >> 3, o = t & 7;
        float acc = b1[o];
        for (int c = sOff[i]; c < sOff[i + 1]; ++c) {
            int e = sEid[c];
            acc += sAl[e] * h8[sSrc[e] * 8 + o];
        }
        o8[t] = fmaxf(acc, 0.0f);
    }
    __syncthreads();

    // ---------------- GAT layer 2 (8 -> 5) ----------------
    for (int t = tid; t < NN * 5; t += NTHR) {
        int i = t / 5, o = t % 5;
        float acc = 0.0f;
        for (int k = 0; k < 8; ++k) acc += o8[i * 8 + k] * w2[o * 8 + k];
        sH5a[t] = acc;
    }
    __syncthreads();
    for (int i = tid; i < NN; i += NTHR) {
        float a = 0.0f, b = 0.0f;
        for (int o = 0; o < 5; ++o) {
            a += sH5a[i * 5 + o] * as2[o];
            b += sH5a[i * 5 + o] * ad2[o];
        }
        sAs[i] = a; sAd[i] = b;
    }
    __syncthreads();
    for (int e = tid; e < ET; e += NTHR) {
        float v = sAs[sSrc[e]] + sAd[sDst[e]];
        sE[e] = (v > 0.0f) ? v : 0.2f * v;
    }
    __syncthreads();
    for (int i = tid; i < NN; i += NTHR) {
        float m = -1e30f;
        for (int o = sOff[i]; o < sOff[i + 1]; ++o) m = fmaxf(m, sE[sEid[o]]);
        float su = 0.0f;
        for (int o = sOff[i]; o < sOff[i + 1]; ++o) su += expf(sE[sEid[o]] - m);
        sNm[i] = m; sNs[i] = su;
    }
    __syncthreads();
    for (int e = tid; e < ET; e += NTHR)
        sAl[e] = expf(sE[e] - sNm[sDst[e]]) / (sNs[sDst[e]] + 1e-16f);
    __syncthreads();
    for (int t = tid; t < NN * 5; t += NTHR) {
        int i = t / 5, o = t % 5;
        float acc = b2[o];
        for (int c = sOff[i]; c < sOff[i + 1]; ++c) {
            int e = sEid[c];
            acc += sAl[e] * sH5a[sSrc[e] * 5 + o];
        }
        sH5b[t] = acc;
    }
    __syncthreads();

    // ---------------- MultiheadAttention (1 head, seq=N) ----------------
    for (int t = tid; t < NN * 15; t += NTHR) {
        int i = t / 15, o = t % 15;
        float acc = mib[o];
        for (int k = 0; k < 5; ++k) acc += sH5b[i * 5 + k] * miw[o * 5 + k];
        if (o < 5)       sH5c[i * 5 + o] = acc;        // q
        else if (o < 10) sH5d[i * 5 + (o - 5)] = acc;  // k
        else             sH5a[i * 5 + (o - 10)] = acc; // v
    }
    __syncthreads();
    const float inv_sqrt5 = 0.4472135954999579f;
    for (int t = tid; t < NN * NN; t += NTHR) {
        int i = t / NN, j = t % NN;
        float acc = 0.0f;
        for (int k = 0; k < 5; ++k) acc += sH5c[i * 5 + k] * sH5d[j * 5 + k];
        sM[t] = acc * inv_sqrt5;
    }
    __syncthreads();
    for (int i = tid; i < NN; i += NTHR) {
        float m = -1e30f;
        for (int j = 0; j < NN; ++j) m = fmaxf(m, sM[i * NN + j]);
        float su = 0.0f;
        for (int j = 0; j < NN; ++j) su += expf(sM[i * NN + j] - m);
        float inv = 1.0f / su;
        for (int j = 0; j < NN; ++j)
            sM[i * NN + j] = expf(sM[i * NN + j] - m) * inv;
    }
    __syncthreads();
    for (int t = tid; t < NN * 5; t += NTHR) {
        int i = t / 5, f = t % 5;
        float acc = 0.0f;
        for (int j = 0; j < NN; ++j) acc += sM[i * NN + j] * sH5a[j * 5 + f];
        sH5c[t] = acc;  // attn @ v
    }
    __syncthreads();
    for (int t = tid; t < NN * 5; t += NTHR) {
        int i = t / 5, o = t % 5;
        float acc = mob[o];
        for (int k = 0; k < 5; ++k) acc += sH5c[i * 5 + k] * mow[o * 5 + k];
        sH5d[t] = acc;  // hM
    }
    __syncthreads();

    // ---------------- TransformerConv ----------------
    for (int t = tid; t < NN * 5; t += NTHR) {
        int i = t / 5, o = t % 5;
        float q_ = bq[o], k_ = bk[o], v_ = bv[o];
        for (int k = 0; k < 5; ++k) {
            float h = sH5d[i * 5 + k];
            q_ += h * wq[o * 5 + k];
            k_ += h * wk[o * 5 + k];
            v_ += h * wv[o * 5 + k];
        }
        sH5a[t] = q_; sH5b[t] = k_; sH5c[t] = v_;
    }
    __syncthreads();
    for (int e = tid; e < ET; e += NTHR) {
        float acc = 0.0f;
        int s2 = sSrc[e], d2 = sDst[e];
        for (int k = 0; k < 5; ++k) acc += sH5a[d2 * 5 + k] * sH5b[s2 * 5 + k];
        sE[e] = acc * inv_sqrt5;
    }
    __syncthreads();
    for (int i = tid; i < NN; i += NTHR) {
        float m = -1e30f;
        for (int o = sOff[i]; o < sOff[i + 1]; ++o) m = fmaxf(m, sE[sEid[o]]);
        float su = 0.0f;
        for (int o = sOff[i]; o < sOff[i + 1]; ++o) su += expf(sE[sEid[o]] - m);
        sNm[i] = m; sNs[i] = su;
    }
    __syncthreads();
    for (int e = tid; e < ET; e += NTHR)
        sAl[e] = expf(sE[e] - sNm[sDst[e]]) / (sNs[sDst[e]] + 1e-16f);
    __syncthreads();
    for (int t = tid; t < NN * 5; t += NTHR) {
        int i = t / 5, o = t % 5;
        float acc = bs[o];
        for (int k = 0; k < 5; ++k) acc += sH5d[i * 5 + k] * ws[o * 5 + k];
        for (int c = sOff[i]; c < sOff[i + 1]; ++c) {
            int e = sEid[c];
            acc += sAl[e] * sH5c[sSrc[e] * 5 + o];
        }
        sH5a[t] = acc;  // tc output
    }
    __syncthreads();

    // ---------------- MLP aggregation head ----------------
    for (int t = tid; t < NN * 64; t += NTHR) {
        int i = t >> 6, o = t & 63;
        float acc = mb1[o];
        for (int k = 0; k < 5; ++k) acc += sH5a[i * 5 + k] * mw1[o * 250 + k];
        sS[t] = fmaxf(acc, 0.0f);
    }
    __syncthreads();
    for (int t = tid; t < NN * NN; t += NTHR) {
        int i = t / NN, j = t % NN;
        float acc = mb2[j];
        for (int k = 0; k < 64; ++k) acc += sS[i * 64 + k] * mw2[j * 64 + k];
        sM[t] = acc;                 // unmasked logits (for value)
        out[t] = acc * gmask[j];     // masked logits output
    }
    __syncthreads();

    // ---------------- value (critic) ----------------
    float part = 0.0f;
    for (int t = tid; t < NN * NN; t += NTHR) part += sM[t] * cw[t % NN];
    sred[tid] = part;
    __syncthreads();
    for (int off = NTHR / 2; off > 0; off >>= 1) {
        if (tid < off) sred[tid] += sred[tid + off];
        __syncthreads();
    }
    if (tid == 0) out[2500] = sred[0] * (1.0f / NN) + cb[0];

    // ---------------- x_combined + ei outputs ----------------
    for (int t = tid; t < NN * 5; t += NTHR) out[2501 + t] = sX[t];
    for (int t = tid; t < 2 * ET; t += NTHR) {
        int row = t / ET, c2 = t % ET;
        int val = (c2 < E2) ? gedge[row * E2 + c2] : (c2 - E2);
        out[2751 + t] = (float)val;
    }
}

extern "C" void kernel_launch(void* const* d_in, const int* in_sizes, int n_in,
                              void* d_out, int out_size, void* d_ws, size_t ws_size,
                              hipStream_t stream) {
    (void)in_sizes; (void)n_in; (void)d_ws; (void)ws_size; (void)out_size;
    opn_kernel<<<1, NTHR, 0, stream>>>(
        (const float*)d_in[0], (const int*)d_in[1], (const float*)d_in[2],
        (const float*)d_in[3], (const float*)d_in[4], (const float*)d_in[5], (const float*)d_in[6],
        (const float*)d_in[7], (const float*)d_in[8], (const float*)d_in[9], (const float*)d_in[10],
        (const float*)d_in[11], (const float*)d_in[12], (const float*)d_in[13], (const float*)d_in[14],
        (const float*)d_in[15], (const float*)d_in[16], (const float*)d_in[17], (const float*)d_in[18],
        (const float*)d_in[19], (const float*)d_in[20], (const float*)d_in[21], (const float*)d_in[22],
        (const float*)d_in[23], (const float*)d_in[24], (const float*)d_in[25], (const float*)d_in[26],
        (const float*)d_in[27], (const float*)d_in[28],
        (float*)d_out);
}

// Round 8
// 124.969 us; speedup vs baseline: 2.8224x; 1.0877x over previous
//
#include <hip/hip_runtime.h>
#include <math.h>

#define NN 50
#define E2 400
#define ET 450
#define NTHR 256
#define KL 16            // Lanczos iterations (deflated space is 49-dim)
#define QS 52            // padded row stride (16B-aligned rows)

// Intra-wave LDS handoff fence: drain LDS ops, forbid compiler reordering.
#define WSYNC() do { asm volatile("s_waitcnt lgkmcnt(0)" ::: "memory"); \
                     __builtin_amdgcn_sched_barrier(0); } while (0)

// ---- shared tail helpers (noinline: dedup straight-line code) ----

__device__ __noinline__ void seg_softmax_alpha(
    const int* sOff, const int* sEid, const int* sDst,
    float* sE, float* sAl, float* sNm, float* sNs)
{
    const int tid = threadIdx.x;
    __syncthreads();
    for (int i = tid; i < NN; i += NTHR) {
        float m = -1e30f;
        for (int o = sOff[i]; o < sOff[i + 1]; ++o) m = fmaxf(m, sE[sEid[o]]);
        float su = 0.0f;
        for (int o = sOff[i]; o < sOff[i + 1]; ++o) su += expf(sE[sEid[o]] - m);
        sNm[i] = m; sNs[i] = su;
    }
    __syncthreads();
    for (int e = tid; e < ET; e += NTHR)
        sAl[e] = expf(sE[e] - sNm[sDst[e]]) / (sNs[sDst[e]] + 1e-16f);
    __syncthreads();
}

__device__ __noinline__ void gat_layer(
    const float* in, float* hbuf, float* outb, int din, int dout, int relu,
    const float* W, const float* asrc, const float* adst, const float* bias,
    const int* sSrc, const int* sDst, const int* sOff, const int* sEid,
    float* sE, float* sAl, float* sNm, float* sNs, float* sAs, float* sAd)
{
    const int tid = threadIdx.x;
    for (int t = tid; t < NN * dout; t += NTHR) {
        int i = t / dout, o = t - i * dout;
        float acc = 0.0f;
        for (int k = 0; k < din; ++k) acc += in[i * din + k] * W[o * din + k];
        hbuf[t] = acc;
    }
    __syncthreads();
    for (int i = tid; i < NN; i += NTHR) {
        float a = 0.0f, b = 0.0f;
        for (int o = 0; o < dout; ++o) {
            a += hbuf[i * dout + o] * asrc[o];
            b += hbuf[i * dout + o] * adst[o];
        }
        sAs[i] = a; sAd[i] = b;
    }
    __syncthreads();
    for (int e = tid; e < ET; e += NTHR) {
        float v = sAs[sSrc[e]] + sAd[sDst[e]];
        sE[e] = (v > 0.0f) ? v : 0.2f * v;
    }
    seg_softmax_alpha(sOff, sEid, sDst, sE, sAl, sNm, sNs);
    for (int t = tid; t < NN * dout; t += NTHR) {
        int i = t / dout, o = t - i * dout;
        float acc = bias[o];
        for (int c = sOff[i]; c < sOff[i + 1]; ++c) {
            int e = sEid[c];
            acc += sAl[e] * hbuf[sSrc[e] * dout + o];
        }
        outb[t] = relu ? fmaxf(acc, 0.0f) : acc;
    }
    __syncthreads();
}

__device__ __noinline__ void cpy192(float* d, const float* s, int n, int t0) {
    for (int t = t0; t < n; t += 192) d[t] = s[t];
}

__global__ __launch_bounds__(NTHR, 1) void opn_kernel(
    const float* __restrict__ gx, const int* __restrict__ gedge,
    const float* __restrict__ gmask,
    const float* __restrict__ w1, const float* __restrict__ as1,
    const float* __restrict__ ad1, const float* __restrict__ b1,
    const float* __restrict__ w2, const float* __restrict__ as2,
    const float* __restrict__ ad2, const float* __restrict__ b2,
    const float* __restrict__ miw, const float* __restrict__ mib,
    const float* __restrict__ mow, const float* __restrict__ mob,
    const float* __restrict__ wq, const float* __restrict__ bq,
    const float* __restrict__ wk, const float* __restrict__ bk,
    const float* __restrict__ wv, const float* __restrict__ bv,
    const float* __restrict__ ws, const float* __restrict__ bs,
    const float* __restrict__ mw1, const float* __restrict__ mb1,
    const float* __restrict__ mw2, const float* __restrict__ mb2,
    const float* __restrict__ cw, const float* __restrict__ cb,
    float* __restrict__ out)
{
    const int tid = threadIdx.x;

    __shared__ float sM[NN * NN];                    // adjacency counts
    __shared__ alignas(16) float sS[3200];           // GAT h/o -> MLP hid64
    __shared__ alignas(16) float sL[NN * QS];        // padded L -> MHA scores
    __shared__ alignas(16) float sQ2[(KL + 2) * QS]; // Lanczos vectors
    __shared__ alignas(16) float sW[QS];             // work / Fiedler
    __shared__ float sD[KL + 2];
    __shared__ float sAl_[KL + 2];
    __shared__ float sBe_[KL + 2];
    __shared__ float sY[KL + 2];
    __shared__ float sCp[KL + 2];
    __shared__ float sDp2[KL + 2];
    __shared__ float sTh[2];
    __shared__ int   sKeff;
    __shared__ float sX[NN * 5];
    __shared__ float sH5a[NN * 5];
    __shared__ float sH5b[NN * 5];
    __shared__ float sH5c[NN * 5];
    __shared__ float sH5d[NN * 5];
    __shared__ int   sSrc[ET];
    __shared__ int   sDst[ET];
    __shared__ float sE[ET];
    __shared__ float sAl[ET];
    __shared__ float sNm[NN];
    __shared__ float sNs[NN];
    __shared__ float sAs[NN];
    __shared__ float sAd[NN];
    __shared__ float sdis[NN];
    __shared__ float sred[4];
    __shared__ int   sOff[NN + 1];
    __shared__ int   sCnt[NN];
    __shared__ int   sEid[ET];
    // staged weights (filled by waves 1-3 during Lanczos)
    __shared__ float sW1[40], sAs1[8], sAd1[8], sB1[8];
    __shared__ float sW2[40], sAs2[5], sAd2[5], sB2[5];
    __shared__ float sMiw[75], sMib[15], sMow[25], sMob[5];
    __shared__ float sWq[25], sBq[5], sWk[25], sBk[5];
    __shared__ float sWv[25], sBv[5], sWsk[25], sBsk[5];
    __shared__ float sMw1[320], sMb1[64];
    __shared__ alignas(16) float sMw2[3200];
    __shared__ float sMb2[NN], sCw[NN], sCb0[1], sMask[NN], sGx[NN * 3];

    // ---------------- edges (with self loops) + adjacency ----------------
    for (int t = tid; t < ET; t += NTHR) {
        int s, d;
        if (t < E2) { s = gedge[t]; d = gedge[E2 + t]; }
        else        { s = t - E2;   d = t - E2; }
        sSrc[t] = s; sDst[t] = d;
    }
    for (int t = tid; t < NN * NN; t += NTHR) sM[t] = 0.0f;
    for (int i = tid; i < NN; i += NTHR) sCnt[i] = 0;
    if (tid == 0) sKeff = KL;
    __syncthreads();
    for (int t = tid; t < E2; t += NTHR)
        atomicAdd(&sM[sSrc[t] * NN + sDst[t]], 1.0f);
    for (int e = tid; e < ET; e += NTHR)
        atomicAdd(&sCnt[sDst[e]], 1);
    __syncthreads();

    // CSR by dst (deterministic)
    if (tid == 0) {
        int acc = 0;
        for (int i = 0; i < NN; ++i) { sOff[i] = acc; acc += sCnt[i]; }
        sOff[NN] = acc;
    }
    __syncthreads();
    if (tid < NN) {
        int pos = sOff[tid];
        for (int e = 0; e < ET; ++e)
            if (sDst[e] == tid) sEid[pos++] = e;
    }

    // ---------------- degree, u0 raw, padded Laplacian ----------------
    for (int i = tid; i < NN; i += NTHR) {
        float dsum = 0.0f;
        for (int j = 0; j < NN; ++j) dsum += sM[i * NN + j];
        sdis[i] = (dsum > 0.0f) ? (1.0f / sqrtf(fmaxf(dsum, 1e-12f))) : 0.0f;
        sQ2[i] = sqrtf(dsum);   // u0 raw
    }
    __syncthreads();
    for (int t = tid; t < NN * QS; t += NTHR) {
        int i = t / QS, k = t - i * QS;
        sL[t] = (k < NN)
              ? (((i == k) ? 1.0f : 0.0f) - sdis[i] * sM[i * NN + k] * sdis[k])
              : 0.0f;
    }
    __syncthreads();

    // ============ wave 0: Lanczos  ||  waves 1-3: weight staging ============
    if (tid < 64) {
        const int lane = tid;
        // normalize u0; deterministic start q1 orthogonal to u0
        {
            float q0 = (lane < NN) ? sQ2[lane] : 0.0f;
            float nn = q0 * q0;
            for (int off = 32; off > 0; off >>= 1) nn += __shfl_xor(nn, off);
            q0 *= rsqrtf(nn);
            unsigned u = (unsigned)lane * 2654435761u + 12345u;
            u ^= u >> 13; u *= 2246822519u; u ^= u >> 11;
            float q1 = (lane < NN) ? ((float)(u & 0xFFFF) * (1.0f / 65536.0f) - 0.5f) : 0.0f;
            for (int pass = 0; pass < 2; ++pass) {
                float d = q0 * q1;
                for (int off = 32; off > 0; off >>= 1) d += __shfl_xor(d, off);
                q1 -= d * q0;
            }
            float n1 = q1 * q1;
            for (int off = 32; off > 0; off >>= 1) n1 += __shfl_xor(n1, off);
            q1 *= rsqrtf(n1);
            if (lane < NN) { sQ2[lane] = q0; sQ2[QS + lane] = q1; }
            WSYNC();
        }
        for (int j = 1; j <= KL; ++j) {
            const float* qp = &sQ2[j * QS];
            const float4* qp4 = (const float4*)qp;
            float w = 0.0f;
            if (lane < NN) {
                const float* rp = &sL[lane * QS];
                const float4* rp4 = (const float4*)rp;
                float a0 = 0.0f, a1 = 0.0f, a2 = 0.0f, a3 = 0.0f;
                for (int k = 0; k < 12; ++k) {
                    float4 r = rp4[k], q = qp4[k];
                    a0 += r.x * q.x; a1 += r.y * q.y;
                    a2 += r.z * q.z; a3 += r.w * q.w;
                }
                a0 += rp[48] * qp[48];
                a1 += rp[49] * qp[49];
                w = 2.0f * qp[lane] - (a0 + a1 + a2 + a3);
            }
            float alpha = 0.0f;
            for (int pass = 0; pass < 2; ++pass) {
                if (lane < NN) sW[lane] = w;
                WSYNC();
                if (lane <= j) {                 // lane m: c_m = q_m . w
                    const float* qm = &sQ2[lane * QS];
                    const float4* qm4 = (const float4*)qm;
                    const float4* x4 = (const float4*)sW;
                    float a0 = 0.0f, a1 = 0.0f, a2 = 0.0f, a3 = 0.0f;
                    for (int k = 0; k < 12; ++k) {
                        float4 r = qm4[k], x = x4[k];
                        a0 += r.x * x.x; a1 += r.y * x.y;
                        a2 += r.z * x.z; a3 += r.w * x.w;
                    }
                    a0 += qm[48] * sW[48];
                    a1 += qm[49] * sW[49];
                    sD[lane] = (a0 + a1) + (a2 + a3);
                }
                WSYNC();
                alpha += sD[j];
                if (lane < NN) {
                    float acc = 0.0f;
                    for (int m = 0; m <= j; ++m) acc += sD[m] * sQ2[m * QS + lane];
                    w -= acc;
                }
                WSYNC();
            }
            float nn2 = w * w;
            for (int off = 32; off > 0; off >>= 1) nn2 += __shfl_xor(nn2, off);
            float beta = sqrtf(nn2);
            if (lane == 0) { sAl_[j] = alpha; sBe_[j] = beta; }
            if (j < KL) {
                if (beta > 1e-10f) {
                    if (lane < NN) sQ2[(j + 1) * QS + lane] = w * (1.0f / beta);
                    WSYNC();
                } else {
                    if (lane == 0) sKeff = j;
                    break;
                }
            }
        }
    } else {
        const int t0 = tid - 64;
        cpy192(sW1, w1, 40, t0);   cpy192(sAs1, as1, 8, t0);
        cpy192(sAd1, ad1, 8, t0);  cpy192(sB1, b1, 8, t0);
        cpy192(sW2, w2, 40, t0);   cpy192(sAs2, as2, 5, t0);
        cpy192(sAd2, ad2, 5, t0);  cpy192(sB2, b2, 5, t0);
        cpy192(sMiw, miw, 75, t0); cpy192(sMib, mib, 15, t0);
        cpy192(sMow, mow, 25, t0); cpy192(sMob, mob, 5, t0);
        cpy192(sWq, wq, 25, t0);   cpy192(sBq, bq, 5, t0);
        cpy192(sWk, wk, 25, t0);   cpy192(sBk, bk, 5, t0);
        cpy192(sWv, wv, 25, t0);   cpy192(sBv, bv, 5, t0);
        cpy192(sWsk, ws, 25, t0);  cpy192(sBsk, bs, 5, t0);
        for (int t = t0; t < 320; t += 192) {      // mw1: only 5 used columns
            int o = t / 5, k = t - 5 * o;
            sMw1[t] = mw1[o * 250 + k];
        }
        cpy192(sMb1, mb1, 64, t0); cpy192(sMw2, mw2, 3200, t0);
        cpy192(sMb2, mb2, NN, t0); cpy192(sCw, cw, NN, t0);
        cpy192(sCb0, cb, 1, t0);   cpy192(sMask, gmask, NN, t0);
        cpy192(sGx, gx, NN * 3, t0);
    }
    __syncthreads();

    // ---------------- top Ritz pair of T: bisection + inverse iteration ----------------
    const int keff = sKeff;
    if (tid < 64) {
        float lo = 1e30f, hi = -1e30f;
        for (int m = 1; m <= keff; ++m) {
            float r = ((m > 1) ? fabsf(sBe_[m - 1]) : 0.0f)
                    + ((m < keff) ? fabsf(sBe_[m]) : 0.0f);
            lo = fminf(lo, sAl_[m] - r);
            hi = fmaxf(hi, sAl_[m] + r);
        }
        for (int round = 0; round < 4; ++round) {
            float h = (hi - lo) * (1.0f / 65.0f);
            float x = lo + (float)(tid + 1) * h;
            int cnt = 0;
            float d = sAl_[1] - x;
            if (d < 0.0f) cnt++;
            for (int m = 2; m <= keff; ++m) {
                float b = sBe_[m - 1];
                float dd = (fabsf(d) < 1e-20f) ? ((d >= 0.0f) ? 1e-20f : -1e-20f) : d;
                d = sAl_[m] - x - b * b / dd;
                if (d < 0.0f) cnt++;
            }
            unsigned long long msk = __ballot(cnt >= keff);
            int f = (msk == 0ULL) ? 64 : (__ffsll((unsigned long long)msk) - 1);
            float nlo = (f == 0) ? lo : (lo + (float)f * h);
            float nhi = (f == 64) ? hi : (lo + (float)(f + 1) * h);
            lo = nlo; hi = nhi;
        }
        if (tid == 0) sTh[0] = 0.5f * (lo + hi);
    }
    __syncthreads();
    if (tid == 0) {
        const float th = sTh[0];
        if (keff == 1) {
            sY[1] = 1.0f;
        } else {
            float inv0 = rsqrtf((float)keff);
            for (int m = 1; m <= keff; ++m) sY[m] = inv0;
            for (int it = 0; it < 2; ++it) {
                float d1 = sAl_[1] - th;
                if (fabsf(d1) < 1e-10f) d1 = (d1 >= 0.0f) ? 1e-10f : -1e-10f;
                sCp[1] = sBe_[1] / d1;
                sDp2[1] = sY[1] / d1;
                for (int m = 2; m <= keff; ++m) {
                    float den = sAl_[m] - th - sBe_[m - 1] * sCp[m - 1];
                    if (fabsf(den) < 1e-10f) den = (den >= 0.0f) ? 1e-10f : -1e-10f;
                    if (m < keff) sCp[m] = sBe_[m] / den;
                    sDp2[m] = (sY[m] - sBe_[m - 1] * sDp2[m - 1]) / den;
                }
                sY[keff] = sDp2[keff];
                for (int m = keff - 1; m >= 1; --m)
                    sY[m] = sDp2[m] - sCp[m] * sY[m + 1];
                float nn = 0.0f;
                for (int m = 1; m <= keff; ++m) nn += sY[m] * sY[m];
                float sc = rsqrtf(nn);
                for (int m = 1; m <= keff; ++m) sY[m] *= sc;
            }
        }
    }
    __syncthreads();
    // Fiedler = Q(1..keff) y, normalize, canonical sign
    if (tid < NN) {
        float acc = 0.0f;
        for (int m = 1; m <= keff; ++m) acc += sY[m] * sQ2[m * QS + tid];
        sW[tid] = acc;
    }
    __syncthreads();
    if (tid < 64) {
        float v = (tid < NN) ? sW[tid] : 0.0f;
        float nn = v * v;
        for (int off = 32; off > 0; off >>= 1) nn += __shfl_xor(nn, off);
        float av = fabsf(v);
        for (int off = 32; off > 0; off >>= 1) av = fmaxf(av, __shfl_xor(av, off));
        unsigned long long msk = __ballot((fabsf(v) == av) && (tid < NN));
        int fl = __ffsll((unsigned long long)msk) - 1;
        float sv = __shfl(v, fl);
        float scale = ((sv >= 0.0f) ? 1.0f : -1.0f) * rsqrtf(nn);
        if (tid < NN) sW[tid] = v * scale;
    }
    __syncthreads();
    for (int i = tid; i < NN; i += NTHR) {
        sX[i * 5 + 0] = sGx[i * 3 + 0];
        sX[i * 5 + 1] = sGx[i * 3 + 1];
        sX[i * 5 + 2] = sGx[i * 3 + 2];
        sX[i * 5 + 3] = sQ2[i];
        sX[i * 5 + 4] = sW[i];
    }
    __syncthreads();

    // ---------------- GAT layers (shared code) ----------------
    float* h8 = sS;
    float* o8 = sS + 1600;
    gat_layer(sX, h8, o8, 5, 8, 1, sW1, sAs1, sAd1, sB1,
              sSrc, sDst, sOff, sEid, sE, sAl, sNm, sNs, sAs, sAd);
    gat_layer(o8, sH5a, sH5b, 8, 5, 0, sW2, sAs2, sAd2, sB2,
              sSrc, sDst, sOff, sEid, sE, sAl, sNm, sNs, sAs, sAd);

    // ---------------- MultiheadAttention ----------------
    for (int t = tid; t < NN * 15; t += NTHR) {
        int i = t / 15, o = t - i * 15;
        float acc = sMib[o];
        for (int k = 0; k < 5; ++k) acc += sH5b[i * 5 + k] * sMiw[o * 5 + k];
        if (o < 5)       sH5c[i * 5 + o] = acc;        // q
        else if (o < 10) sH5d[i * 5 + (o - 5)] = acc;  // k
        else             sH5a[i * 5 + (o - 10)] = acc; // v
    }
    __syncthreads();
    const float inv_sqrt5 = 0.4472135954999579f;
    for (int t = tid; t < NN * QS; t += NTHR) {      // scores into padded sL
        int i = t / QS, j = t - i * QS;
        float v = -1e30f;
        if (j < NN) {
            float acc = 0.0f;
            for (int k = 0; k < 5; ++k) acc += sH5c[i * 5 + k] * sH5d[j * 5 + k];
            v = acc * inv_sqrt5;
        }
        sL[t] = v;
    }
    __syncthreads();
    for (int i = tid; i < NN; i += NTHR) {           // vectorized row softmax
        float4* rp = (float4*)&sL[i * QS];
        float4 m4 = rp[0];
        for (int k = 1; k < 13; ++k) {
            float4 v = rp[k];
            m4.x = fmaxf(m4.x, v.x); m4.y = fmaxf(m4.y, v.y);
            m4.z = fmaxf(m4.z, v.z); m4.w = fmaxf(m4.w, v.w);
        }
        float m = fmaxf(fmaxf(m4.x, m4.y), fmaxf(m4.z, m4.w));
        float su = 0.0f;
        for (int k = 0; k < 13; ++k) {
            float4 v = rp[k];
            v.x = expf(v.x - m); v.y = expf(v.y - m);
            v.z = expf(v.z - m); v.w = expf(v.w - m);
            su += (v.x + v.y) + (v.z + v.w);
            rp[k] = v;
        }
        float inv = 1.0f / su;
        for (int k = 0; k < 13; ++k) {
            float4 v = rp[k];
            v.x *= inv; v.y *= inv; v.z *= inv; v.w *= inv;
            rp[k] = v;
        }
    }
    __syncthreads();
    for (int t = tid; t < NN * 5; t += NTHR) {       // attn @ v
        int i = t / 5, f = t - i * 5;
        float acc = 0.0f;
        for (int j = 0; j < NN; ++j) acc += sL[i * QS + j] * sH5a[j * 5 + f];
        sH5c[t] = acc;
    }
    __syncthreads();
    for (int t = tid; t < NN * 5; t += NTHR) {       // out proj
        int i = t / 5, o = t - i * 5;
        float acc = sMob[o];
        for (int k = 0; k < 5; ++k) acc += sH5c[i * 5 + k] * sMow[o * 5 + k];
        sH5d[t] = acc;                               // hM
    }
    __syncthreads();

    // ---------------- TransformerConv ----------------
    for (int t = tid; t < NN * 5; t += NTHR) {
        int i = t / 5, o = t - i * 5;
        float q_ = sBq[o], k_ = sBk[o], v_ = sBv[o];
        for (int k = 0; k < 5; ++k) {
            float h = sH5d[i * 5 + k];
            q_ += h * sWq[o * 5 + k];
            k_ += h * sWk[o * 5 + k];
            v_ += h * sWv[o * 5 + k];
        }
        sH5a[t] = q_; sH5b[t] = k_; sH5c[t] = v_;
    }
    __syncthreads();
    for (int e = tid; e < ET; e += NTHR) {
        float acc = 0.0f;
        int s2 = sSrc[e], d2 = sDst[e];
        for (int k = 0; k < 5; ++k) acc += sH5a[d2 * 5 + k] * sH5b[s2 * 5 + k];
        sE[e] = acc * inv_sqrt5;
    }
    seg_softmax_alpha(sOff, sEid, sDst, sE, sAl, sNm, sNs);
    for (int t = tid; t < NN * 5; t += NTHR) {
        int i = t / 5, o = t - i * 5;
        float acc = sBsk[o];
        for (int k = 0; k < 5; ++k) acc += sH5d[i * 5 + k] * sWsk[o * 5 + k];
        for (int c = sOff[i]; c < sOff[i + 1]; ++c) {
            int e = sEid[c];
            acc += sAl[e] * sH5c[sSrc[e] * 5 + o];
        }
        sH5a[t] = acc;                               // tc output
    }
    __syncthreads();

    // ---------------- MLP head + fused critic ----------------
    for (int t = tid; t < NN * 64; t += NTHR) {
        int i = t >> 6, o = t & 63;
        float acc = sMb1[o];
        for (int k = 0; k < 5; ++k) acc += sH5a[i * 5 + k] * sMw1[o * 5 + k];
        sS[t] = fmaxf(acc, 0.0f);
    }
    __syncthreads();
    float part = 0.0f;
    for (int t = tid; t < NN * NN; t += NTHR) {
        int i = t / NN, j = t - i * NN;
        const float4* sp4 = (const float4*)&sS[i * 64];
        const float4* wp4 = (const float4*)&sMw2[j * 64];
        float a0 = 0.0f, a1 = 0.0f, a2 = 0.0f, a3 = 0.0f;
        for (int k = 0; k < 16; ++k) {
            float4 a = sp4[k], b = wp4[k];
            a0 += a.x * b.x; a1 += a.y * b.y;
            a2 += a.z * b.z; a3 += a.w * b.w;
        }
        float acc = sMb2[j] + (a0 + a1) + (a2 + a3);
        out[t] = acc * sMask[j];
        part += acc * sCw[j];
    }
    for (int off = 32; off > 0; off >>= 1) part += __shfl_xor(part, off);
    if ((tid & 63) == 0) sred[tid >> 6] = part;
    __syncthreads();
    if (tid == 0)
        out[2500] = (sred[0] + sred[1] + sred[2] + sred[3]) * (1.0f / NN) + sCb0[0];

    // ---------------- x_combined + ei outputs (from LDS) ----------------
    for (int t = tid; t < NN * 5; t += NTHR) out[2501 + t] = sX[t];
    for (int t = tid; t < 2 * ET; t += NTHR) {
        int val = (t < ET) ? sSrc[t] : sDst[t - ET];
        out[2751 + t] = (float)val;
    }
}

extern "C" void kernel_launch(void* const* d_in, const int* in_sizes, int n_in,
                              void* d_out, int out_size, void* d_ws, size_t ws_size,
                              hipStream_t stream) {
    (void)in_sizes; (void)n_in; (void)d_ws; (void)ws_size; (void)out_size;
    opn_kernel<<<1, NTHR, 0, stream>>>(
        (const float*)d_in[0], (const int*)d_in[1], (const float*)d_in[2],
        (const float*)d_in[3], (const float*)d_in[4], (const float*)d_in[5], (const float*)d_in[6],
        (const float*)d_in[7], (const float*)d_in[8], (const float*)d_in[9], (const float*)d_in[10],
        (const float*)d_in[11], (const float*)d_in[12], (const float*)d_in[13], (const float*)d_in[14],
        (const float*)d_in[15], (const float*)d_in[16], (const float*)d_in[17], (const float*)d_in[18],
        (const float*)d_in[19], (const float*)d_in[20], (const float*)d_in[21], (const float*)d_in[22],
        (const float*)d_in[23], (const float*)d_in[24], (const float*)d_in[25], (const float*)d_in[26],
        (const float*)d_in[27], (const float*)d_in[28],
        (float*)d_out);
}

// Round 9
// 104.271 us; speedup vs baseline: 3.3827x; 1.1985x over previous
//
#include <hip/hip_runtime.h>
#include <math.h>

#define NN 50
#define E2 400
#define ET 450
#define NTHR 256
#define KL 12            // Lanczos iterations (deflated space is 49-dim)
#define QS 52            // padded row stride (16B-aligned rows)
#define MS 68            // padded sMw2 row stride (16B-aligned, bank-staggered)

// Intra-wave LDS handoff fence: drain LDS ops, forbid compiler reordering.
#define WSYNC() do { asm volatile("s_waitcnt lgkmcnt(0)" ::: "memory"); \
                     __builtin_amdgcn_sched_barrier(0); } while (0)

// ---- shared tail helpers (noinline: dedup straight-line code) ----
// CSR-ordered edge softmax: sECsr (scores in CSR order) -> sAlCsr.
__device__ __noinline__ void seg_softmax_alpha(
    const int* sOff, const int* sDstCsr,
    const float* sECsr, float* sAlCsr, float* sNm, float* sNs)
{
    const int tid = threadIdx.x;
    __syncthreads();
    for (int i = tid; i < NN; i += NTHR) {
        const int c0 = sOff[i], c1 = sOff[i + 1];
        float m = -1e30f;
        for (int c = c0; c < c1; ++c) m = fmaxf(m, sECsr[c]);
        float su = 0.0f;
        for (int c = c0; c < c1; ++c) su += expf(sECsr[c] - m);
        sNm[i] = m; sNs[i] = su;
    }
    __syncthreads();
    for (int c = tid; c < ET; c += NTHR)
        sAlCsr[c] = expf(sECsr[c] - sNm[sDstCsr[c]]) / (sNs[sDstCsr[c]] + 1e-16f);
    __syncthreads();
}

__device__ __noinline__ void gat_layer(
    const float* in, float* hbuf, float* outb, int din, int dout, int relu,
    const float* W, const float* asrc, const float* adst, const float* bias,
    const int* sSrcCsr, const int* sDstCsr, const int* sOff,
    float* sECsr, float* sAlCsr, float* sNm, float* sNs, float* sAs, float* sAd)
{
    const int tid = threadIdx.x;
    for (int t = tid; t < NN * dout; t += NTHR) {
        int i = t / dout, o = t - i * dout;
        float acc = 0.0f;
        for (int k = 0; k < din; ++k) acc += in[i * din + k] * W[o * din + k];
        hbuf[t] = acc;
    }
    __syncthreads();
    for (int i = tid; i < NN; i += NTHR) {
        float a = 0.0f, b = 0.0f;
        for (int o = 0; o < dout; ++o) {
            a += hbuf[i * dout + o] * asrc[o];
            b += hbuf[i * dout + o] * adst[o];
        }
        sAs[i] = a; sAd[i] = b;
    }
    __syncthreads();
    for (int c = tid; c < ET; c += NTHR) {
        float v = sAs[sSrcCsr[c]] + sAd[sDstCsr[c]];
        sECsr[c] = (v > 0.0f) ? v : 0.2f * v;
    }
    seg_softmax_alpha(sOff, sDstCsr, sECsr, sAlCsr, sNm, sNs);
    for (int t = tid; t < NN * dout; t += NTHR) {
        int i = t / dout, o = t - i * dout;
        float acc = bias[o];
        for (int c = sOff[i]; c < sOff[i + 1]; ++c)
            acc += sAlCsr[c] * hbuf[sSrcCsr[c] * dout + o];
        outb[t] = relu ? fmaxf(acc, 0.0f) : acc;
    }
    __syncthreads();
}

__device__ __noinline__ void cpy192(float* d, const float* s, int n, int t0) {
    for (int t = t0; t < n; t += 192) d[t] = s[t];
}

__global__ __launch_bounds__(NTHR, 1) void opn_kernel(
    const float* __restrict__ gx, const int* __restrict__ gedge,
    const float* __restrict__ gmask,
    const float* __restrict__ w1, const float* __restrict__ as1,
    const float* __restrict__ ad1, const float* __restrict__ b1,
    const float* __restrict__ w2, const float* __restrict__ as2,
    const float* __restrict__ ad2, const float* __restrict__ b2,
    const float* __restrict__ miw, const float* __restrict__ mib,
    const float* __restrict__ mow, const float* __restrict__ mob,
    const float* __restrict__ wq, const float* __restrict__ bq,
    const float* __restrict__ wk, const float* __restrict__ bk,
    const float* __restrict__ wv, const float* __restrict__ bv,
    const float* __restrict__ ws, const float* __restrict__ bs,
    const float* __restrict__ mw1, const float* __restrict__ mb1,
    const float* __restrict__ mw2, const float* __restrict__ mb2,
    const float* __restrict__ cw, const float* __restrict__ cb,
    float* __restrict__ out)
{
    const int tid = threadIdx.x;

    __shared__ float sM[NN * NN];                    // adjacency counts
    __shared__ alignas(16) float sS[3200];           // GAT h/o -> MLP hid64
    __shared__ alignas(16) float sL[NN * QS];        // padded L -> MHA scores
    __shared__ alignas(16) float sQ2[(KL + 2) * QS]; // Lanczos vectors
    __shared__ alignas(16) float sW[QS];             // work / Fiedler
    __shared__ float sD[KL + 2];
    __shared__ float sAl_[KL + 2];
    __shared__ float sBe_[KL + 2];
    __shared__ float sY[KL + 2];
    __shared__ float sCp[KL + 2];
    __shared__ float sDp2[KL + 2];
    __shared__ float sTh[2];
    __shared__ int   sKeff;
    __shared__ float sX[NN * 5];
    __shared__ float sH5a[NN * 5];
    __shared__ float sH5b[NN * 5];
    __shared__ float sH5c[NN * 5];
    __shared__ float sH5d[NN * 5];
    __shared__ int   sSrc[ET];
    __shared__ int   sDst[ET];
    __shared__ int   sSrcCsr[ET];
    __shared__ int   sDstCsr[ET];
    __shared__ float sECsr[ET];
    __shared__ float sAlCsr[ET];
    __shared__ float sNm[NN];
    __shared__ float sNs[NN];
    __shared__ float sAs[NN];
    __shared__ float sAd[NN];
    __shared__ float sdis[NN];
    __shared__ float sred[4];
    __shared__ int   sOff[NN + 1];
    __shared__ int   sCnt[NN];
    // staged weights (filled by waves 1-3 during Lanczos)
    __shared__ float sW1[40], sAs1[8], sAd1[8], sB1[8];
    __shared__ float sW2[40], sAs2[5], sAd2[5], sB2[5];
    __shared__ float sMiw[75], sMib[15], sMow[25], sMob[5];
    __shared__ float sWq[25], sBq[5], sWk[25], sBk[5];
    __shared__ float sWv[25], sBv[5], sWsk[25], sBsk[5];
    __shared__ float sMw1[320], sMb1[64];
    __shared__ alignas(16) float sMw2[NN * MS];      // padded rows: bank-staggered
    __shared__ float sMb2[NN], sCw[NN], sCb0[1], sMask[NN], sGx[NN * 3];

    // ---------------- edges (with self loops) + adjacency ----------------
    for (int t = tid; t < ET; t += NTHR) {
        int s, d;
        if (t < E2) { s = gedge[t]; d = gedge[E2 + t]; }
        else        { s = t - E2;   d = t - E2; }
        sSrc[t] = s; sDst[t] = d;
    }
    for (int t = tid; t < NN * NN; t += NTHR) sM[t] = 0.0f;
    for (int i = tid; i < NN; i += NTHR) sCnt[i] = 0;
    if (tid == 0) sKeff = KL;
    __syncthreads();
    for (int t = tid; t < E2; t += NTHR)
        atomicAdd(&sM[sSrc[t] * NN + sDst[t]], 1.0f);
    for (int e = tid; e < ET; e += NTHR)
        atomicAdd(&sCnt[sDst[e]], 1);
    __syncthreads();

    // CSR by dst (deterministic); store src/dst in CSR order (no sEid)
    if (tid == 0) {
        int acc = 0;
        for (int i = 0; i < NN; ++i) { sOff[i] = acc; acc += sCnt[i]; }
        sOff[NN] = acc;
    }
    __syncthreads();
    if (tid < NN) {
        int pos = sOff[tid];
        for (int e = 0; e < ET; ++e)
            if (sDst[e] == tid) { sSrcCsr[pos] = sSrc[e]; sDstCsr[pos] = tid; pos++; }
    }

    // ---------------- degree, u0 raw, padded Laplacian ----------------
    for (int i = tid; i < NN; i += NTHR) {
        float dsum = 0.0f;
        for (int j = 0; j < NN; ++j) dsum += sM[i * NN + j];
        sdis[i] = (dsum > 0.0f) ? (1.0f / sqrtf(fmaxf(dsum, 1e-12f))) : 0.0f;
        sQ2[i] = sqrtf(dsum);   // u0 raw
    }
    __syncthreads();
    for (int t = tid; t < NN * QS; t += NTHR) {
        int i = t / QS, k = t - i * QS;
        sL[t] = (k < NN)
              ? (((i == k) ? 1.0f : 0.0f) - sdis[i] * sM[i * NN + k] * sdis[k])
              : 0.0f;
    }
    __syncthreads();

    // ============ wave 0: Lanczos  ||  waves 1-3: weight staging ============
    if (tid < 64) {
        const int lane = tid;
        // normalize u0; deterministic start q1 orthogonal to u0
        {
            float q0 = (lane < NN) ? sQ2[lane] : 0.0f;
            float nn = q0 * q0;
            for (int off = 32; off > 0; off >>= 1) nn += __shfl_xor(nn, off);
            q0 *= rsqrtf(nn);
            unsigned u = (unsigned)lane * 2654435761u + 12345u;
            u ^= u >> 13; u *= 2246822519u; u ^= u >> 11;
            float q1 = (lane < NN) ? ((float)(u & 0xFFFF) * (1.0f / 65536.0f) - 0.5f) : 0.0f;
            for (int pass = 0; pass < 2; ++pass) {
                float d = q0 * q1;
                for (int off = 32; off > 0; off >>= 1) d += __shfl_xor(d, off);
                q1 -= d * q0;
            }
            float n1 = q1 * q1;
            for (int off = 32; off > 0; off >>= 1) n1 += __shfl_xor(n1, off);
            q1 *= rsqrtf(n1);
            if (lane < NN) { sQ2[lane] = q0; sQ2[QS + lane] = q1; }
            WSYNC();
        }
        for (int j = 1; j <= KL; ++j) {
            const float* qp = &sQ2[j * QS];
            const float4* qp4 = (const float4*)qp;
            float w = 0.0f;
            if (lane < NN) {
                const float* rp = &sL[lane * QS];
                const float4* rp4 = (const float4*)rp;
                float a0 = 0.0f, a1 = 0.0f, a2 = 0.0f, a3 = 0.0f;
                for (int k = 0; k < 12; ++k) {
                    float4 r = rp4[k], q = qp4[k];
                    a0 += r.x * q.x; a1 += r.y * q.y;
                    a2 += r.z * q.z; a3 += r.w * q.w;
                }
                a0 += rp[48] * qp[48];
                a1 += rp[49] * qp[49];
                w = 2.0f * qp[lane] - (a0 + a1 + a2 + a3);
            }
            float alpha = 0.0f;
            for (int pass = 0; pass < 2; ++pass) {
                if (lane < NN) sW[lane] = w;
                WSYNC();
                if (lane <= j) {                 // lane m: c_m = q_m . w
                    const float* qm = &sQ2[lane * QS];
                    const float4* qm4 = (const float4*)qm;
                    const float4* x4 = (const float4*)sW;
                    float a0 = 0.0f, a1 = 0.0f, a2 = 0.0f, a3 = 0.0f;
                    for (int k = 0; k < 12; ++k) {
                        float4 r = qm4[k], x = x4[k];
                        a0 += r.x * x.x; a1 += r.y * x.y;
                        a2 += r.z * x.z; a3 += r.w * x.w;
                    }
                    a0 += qm[48] * sW[48];
                    a1 += qm[49] * sW[49];
                    sD[lane] = (a0 + a1) + (a2 + a3);
                }
                WSYNC();
                alpha += sD[j];
                if (lane < NN) {
                    float acc = 0.0f;
                    for (int m = 0; m <= j; ++m) acc += sD[m] * sQ2[m * QS + lane];
                    w -= acc;
                }
                WSYNC();
            }
            float nn2 = w * w;
            for (int off = 32; off > 0; off >>= 1) nn2 += __shfl_xor(nn2, off);
            float beta = sqrtf(nn2);
            if (lane == 0) { sAl_[j] = alpha; sBe_[j] = beta; }
            if (j < KL) {
                if (beta > 1e-10f) {
                    if (lane < NN) sQ2[(j + 1) * QS + lane] = w * (1.0f / beta);
                    WSYNC();
                } else {
                    if (lane == 0) sKeff = j;
                    break;
                }
            }
        }
    } else {
        const int t0 = tid - 64;
        cpy192(sW1, w1, 40, t0);   cpy192(sAs1, as1, 8, t0);
        cpy192(sAd1, ad1, 8, t0);  cpy192(sB1, b1, 8, t0);
        cpy192(sW2, w2, 40, t0);   cpy192(sAs2, as2, 5, t0);
        cpy192(sAd2, ad2, 5, t0);  cpy192(sB2, b2, 5, t0);
        cpy192(sMiw, miw, 75, t0); cpy192(sMib, mib, 15, t0);
        cpy192(sMow, mow, 25, t0); cpy192(sMob, mob, 5, t0);
        cpy192(sWq, wq, 25, t0);   cpy192(sBq, bq, 5, t0);
        cpy192(sWk, wk, 25, t0);   cpy192(sBk, bk, 5, t0);
        cpy192(sWv, wv, 25, t0);   cpy192(sBv, bv, 5, t0);
        cpy192(sWsk, ws, 25, t0);  cpy192(sBsk, bs, 5, t0);
        for (int t = t0; t < 320; t += 192) {      // mw1: only 5 used columns
            int o = t / 5, k = t - 5 * o;
            sMw1[t] = mw1[o * 250 + k];
        }
        for (int t = t0; t < 3200; t += 192) {     // mw2 into padded rows
            int o = t >> 6, k = t & 63;
            sMw2[o * MS + k] = mw2[t];
        }
        cpy192(sMb1, mb1, 64, t0);
        cpy192(sMb2, mb2, NN, t0); cpy192(sCw, cw, NN, t0);
        cpy192(sCb0, cb, 1, t0);   cpy192(sMask, gmask, NN, t0);
        cpy192(sGx, gx, NN * 3, t0);
    }
    __syncthreads();

    // ---------------- top Ritz pair of T: bisection + inverse iteration ----------------
    const int keff = sKeff;
    if (tid < 64) {
        float lo = 1e30f, hi = -1e30f;
        for (int m = 1; m <= keff; ++m) {
            float r = ((m > 1) ? fabsf(sBe_[m - 1]) : 0.0f)
                    + ((m < keff) ? fabsf(sBe_[m]) : 0.0f);
            lo = fminf(lo, sAl_[m] - r);
            hi = fmaxf(hi, sAl_[m] + r);
        }
        for (int round = 0; round < 4; ++round) {
            float h = (hi - lo) * (1.0f / 65.0f);
            float x = lo + (float)(tid + 1) * h;
            int cnt = 0;
            float d = sAl_[1] - x;
            if (d < 0.0f) cnt++;
            for (int m = 2; m <= keff; ++m) {
                float b = sBe_[m - 1];
                float dd = (fabsf(d) < 1e-20f) ? ((d >= 0.0f) ? 1e-20f : -1e-20f) : d;
                d = sAl_[m] - x - b * b / dd;
                if (d < 0.0f) cnt++;
            }
            unsigned long long msk = __ballot(cnt >= keff);
            int f = (msk == 0ULL) ? 64 : (__ffsll((unsigned long long)msk) - 1);
            float nlo = (f == 0) ? lo : (lo + (float)f * h);
            float nhi = (f == 64) ? hi : (lo + (float)(f + 1) * h);
            lo = nlo; hi = nhi;
        }
        if (tid == 0) sTh[0] = 0.5f * (lo + hi);
    }
    __syncthreads();
    if (tid == 0) {
        const float th = sTh[0];
        if (keff == 1) {
            sY[1] = 1.0f;
        } else {
            float inv0 = rsqrtf((float)keff);
            for (int m = 1; m <= keff; ++m) sY[m] = inv0;
            // single inverse-iteration pass (theta accurate to ~1e-7)
            float d1 = sAl_[1] - th;
            if (fabsf(d1) < 1e-10f) d1 = (d1 >= 0.0f) ? 1e-10f : -1e-10f;
            sCp[1] = sBe_[1] / d1;
            sDp2[1] = sY[1] / d1;
            for (int m = 2; m <= keff; ++m) {
                float den = sAl_[m] - th - sBe_[m - 1] * sCp[m - 1];
                if (fabsf(den) < 1e-10f) den = (den >= 0.0f) ? 1e-10f : -1e-10f;
                if (m < keff) sCp[m] = sBe_[m] / den;
                sDp2[m] = (sY[m] - sBe_[m - 1] * sDp2[m - 1]) / den;
            }
            sY[keff] = sDp2[keff];
            for (int m = keff - 1; m >= 1; --m)
                sY[m] = sDp2[m] - sCp[m] * sY[m + 1];
            float nn = 0.0f;
            for (int m = 1; m <= keff; ++m) nn += sY[m] * sY[m];
            float sc = rsqrtf(nn);
            for (int m = 1; m <= keff; ++m) sY[m] *= sc;
        }
    }
    __syncthreads();
    // Fiedler = Q(1..keff) y, normalize, canonical sign
    if (tid < NN) {
        float acc = 0.0f;
        for (int m = 1; m <= keff; ++m) acc += sY[m] * sQ2[m * QS + tid];
        sW[tid] = acc;
    }
    __syncthreads();
    if (tid < 64) {
        float v = (tid < NN) ? sW[tid] : 0.0f;
        float nn = v * v;
        for (int off = 32; off > 0; off >>= 1) nn += __shfl_xor(nn, off);
        float av = fabsf(v);
        for (int off = 32; off > 0; off >>= 1) av = fmaxf(av, __shfl_xor(av, off));
        unsigned long long msk = __ballot((fabsf(v) == av) && (tid < NN));
        int fl = __ffsll((unsigned long long)msk) - 1;
        float sv = __shfl(v, fl);
        float scale = ((sv >= 0.0f) ? 1.0f : -1.0f) * rsqrtf(nn);
        if (tid < NN) sW[tid] = v * scale;
    }
    __syncthreads();
    for (int i = tid; i < NN; i += NTHR) {
        sX[i * 5 + 0] = sGx[i * 3 + 0];
        sX[i * 5 + 1] = sGx[i * 3 + 1];
        sX[i * 5 + 2] = sGx[i * 3 + 2];
        sX[i * 5 + 3] = sQ2[i];
        sX[i * 5 + 4] = sW[i];
    }
    __syncthreads();

    // ---------------- GAT layers (shared code, CSR edges) ----------------
    float* h8 = sS;
    float* o8 = sS + 1600;
    gat_layer(sX, h8, o8, 5, 8, 1, sW1, sAs1, sAd1, sB1,
              sSrcCsr, sDstCsr, sOff, sECsr, sAlCsr, sNm, sNs, sAs, sAd);
    gat_layer(o8, sH5a, sH5b, 8, 5, 0, sW2, sAs2, sAd2, sB2,
              sSrcCsr, sDstCsr, sOff, sECsr, sAlCsr, sNm, sNs, sAs, sAd);

    // ---------------- MultiheadAttention ----------------
    for (int t = tid; t < NN * 15; t += NTHR) {
        int i = t / 15, o = t - i * 15;
        float acc = sMib[o];
        for (int k = 0; k < 5; ++k) acc += sH5b[i * 5 + k] * sMiw[o * 5 + k];
        if (o < 5)       sH5c[i * 5 + o] = acc;        // q
        else if (o < 10) sH5d[i * 5 + (o - 5)] = acc;  // k
        else             sH5a[i * 5 + (o - 10)] = acc; // v
    }
    __syncthreads();
    const float inv_sqrt5 = 0.4472135954999579f;
    for (int t = tid; t < NN * QS; t += NTHR) {      // scores into padded sL
        int i = t / QS, j = t - i * QS;
        float v = -1e30f;
        if (j < NN) {
            float acc = 0.0f;
            for (int k = 0; k < 5; ++k) acc += sH5c[i * 5 + k] * sH5d[j * 5 + k];
            v = acc * inv_sqrt5;
        }
        sL[t] = v;
    }
    __syncthreads();
    for (int i = tid; i < NN; i += NTHR) {           // vectorized row softmax
        float4* rp = (float4*)&sL[i * QS];
        float4 m4 = rp[0];
        for (int k = 1; k < 13; ++k) {
            float4 v = rp[k];
            m4.x = fmaxf(m4.x, v.x); m4.y = fmaxf(m4.y, v.y);
            m4.z = fmaxf(m4.z, v.z); m4.w = fmaxf(m4.w, v.w);
        }
        float m = fmaxf(fmaxf(m4.x, m4.y), fmaxf(m4.z, m4.w));
        float su = 0.0f;
        for (int k = 0; k < 13; ++k) {
            float4 v = rp[k];
            v.x = expf(v.x - m); v.y = expf(v.y - m);
            v.z = expf(v.z - m); v.w = expf(v.w - m);
            su += (v.x + v.y) + (v.z + v.w);
            rp[k] = v;
        }
        float inv = 1.0f / su;
        for (int k = 0; k < 13; ++k) {
            float4 v = rp[k];
            v.x *= inv; v.y *= inv; v.z *= inv; v.w *= inv;
            rp[k] = v;
        }
    }
    __syncthreads();
    for (int t = tid; t < NN * 5; t += NTHR) {       // attn @ v
        int i = t / 5, f = t - i * 5;
        float acc = 0.0f;
        for (int j = 0; j < NN; ++j) acc += sL[i * QS + j] * sH5a[j * 5 + f];
        sH5c[t] = acc;
    }
    __syncthreads();
    for (int t = tid; t < NN * 5; t += NTHR) {       // out proj
        int i = t / 5, o = t - i * 5;
        float acc = sMob[o];
        for (int k = 0; k < 5; ++k) acc += sH5c[i * 5 + k] * sMow[o * 5 + k];
        sH5d[t] = acc;                               // hM
    }
    __syncthreads();

    // ---------------- TransformerConv (CSR edges) ----------------
    for (int t = tid; t < NN * 5; t += NTHR) {
        int i = t / 5, o = t - i * 5;
        float q_ = sBq[o], k_ = sBk[o], v_ = sBv[o];
        for (int k = 0; k < 5; ++k) {
            float h = sH5d[i * 5 + k];
            q_ += h * sWq[o * 5 + k];
            k_ += h * sWk[o * 5 + k];
            v_ += h * sWv[o * 5 + k];
        }
        sH5a[t] = q_; sH5b[t] = k_; sH5c[t] = v_;
    }
    __syncthreads();
    for (int c = tid; c < ET; c += NTHR) {
        int s2 = sSrcCsr[c], d2 = sDstCsr[c];
        float acc = 0.0f;
        for (int k = 0; k < 5; ++k) acc += sH5a[d2 * 5 + k] * sH5b[s2 * 5 + k];
        sECsr[c] = acc * inv_sqrt5;
    }
    seg_softmax_alpha(sOff, sDstCsr, sECsr, sAlCsr, sNm, sNs);
    for (int t = tid; t < NN * 5; t += NTHR) {
        int i = t / 5, o = t - i * 5;
        float acc = sBsk[o];
        for (int k = 0; k < 5; ++k) acc += sH5d[i * 5 + k] * sWsk[o * 5 + k];
        for (int c = sOff[i]; c < sOff[i + 1]; ++c)
            acc += sAlCsr[c] * sH5c[sSrcCsr[c] * 5 + o];
        sH5a[t] = acc;                               // tc output
    }
    __syncthreads();

    // ---------------- MLP head + fused critic ----------------
    for (int t = tid; t < NN * 64; t += NTHR) {
        int i = t >> 6, o = t & 63;
        float acc = sMb1[o];
        for (int k = 0; k < 5; ++k) acc += sH5a[i * 5 + k] * sMw1[o * 5 + k];
        sS[t] = fmaxf(acc, 0.0f);
    }
    __syncthreads();
    float part = 0.0f;
    for (int t = tid; t < NN * NN; t += NTHR) {
        int i = t / NN, j = t - i * NN;
        const float4* sp4 = (const float4*)&sS[i * 64];
        const float4* wp4 = (const float4*)&sMw2[j * MS];
        float a0 = 0.0f, a1 = 0.0f, a2 = 0.0f, a3 = 0.0f;
        for (int k = 0; k < 16; ++k) {
            float4 a = sp4[k], b = wp4[k];
            a0 += a.x * b.x; a1 += a.y * b.y;
            a2 += a.z * b.z; a3 += a.w * b.w;
        }
        float acc = sMb2[j] + (a0 + a1) + (a2 + a3);
        out[t] = acc * sMask[j];
        part += acc * sCw[j];
    }
    for (int off = 32; off > 0; off >>= 1) part += __shfl_xor(part, off);
    if ((tid & 63) == 0) sred[tid >> 6] = part;
    __syncthreads();
    if (tid == 0)
        out[2500] = (sred[0] + sred[1] + sred[2] + sred[3]) * (1.0f / NN) + sCb0[0];

    // ---------------- x_combined + ei outputs (from LDS) ----------------
    for (int t = tid; t < NN * 5; t += NTHR) out[2501 + t] = sX[t];
    for (int t = tid; t < 2 * ET; t += NTHR) {
        int val = (t < ET) ? sSrc[t] : sDst[t - ET];
        out[2751 + t] = (float)val;
    }
}

extern "C" void kernel_launch(void* const* d_in, const int* in_sizes, int n_in,
                              void* d_out, int out_size, void* d_ws, size_t ws_size,
                              hipStream_t stream) {
    (void)in_sizes; (void)n_in; (void)d_ws; (void)ws_size; (void)out_size;
    opn_kernel<<<1, NTHR, 0, stream>>>(
        (const float*)d_in[0], (const int*)d_in[1], (const float*)d_in[2],
        (const float*)d_in[3], (const float*)d_in[4], (const float*)d_in[5], (const float*)d_in[6],
        (const float*)d_in[7], (const float*)d_in[8], (const float*)d_in[9], (const float*)d_in[10],
        (const float*)d_in[11], (const float*)d_in[12], (const float*)d_in[13], (const float*)d_in[14],
        (const float*)d_in[15], (const float*)d_in[16], (const float*)d_in[17], (const float*)d_in[18],
        (const float*)d_in[19], (const float*)d_in[20], (const float*)d_in[21], (const float*)d_in[22],
        (const float*)d_in[23], (const float*)d_in[24], (const float*)d_in[25], (const float*)d_in[26],
        (const float*)d_in[27], (const float*)d_in[28],
        (float*)d_out);
}

// Round 10
// 77.518 us; speedup vs baseline: 4.5501x; 1.3451x over previous
//
#include <hip/hip_runtime.h>
#include <math.h>

#define NN 50
#define E2 400
#define ET 450
#define NTHR 256
#define KL 12            // Lanczos iterations
#define QS 52            // padded row stride (16B-aligned rows)
#define MS 68            // padded sMw2 row stride
#define LS 53            // MHA score-row stride (odd -> conflict-free columns)

// Intra-wave LDS handoff fence: drain LDS ops, forbid compiler reordering.
#define WSYNC() do { asm volatile("s_waitcnt lgkmcnt(0)" ::: "memory"); \
                     __builtin_amdgcn_sched_barrier(0); } while (0)

__device__ __noinline__ void cpy128(float* d, const float* s, int n, int t0) {
    for (int t = t0; t < n; t += 128) d[t] = s[t];
}

__global__ __launch_bounds__(NTHR, 1) void opn_kernel(
    const float* __restrict__ gx, const int* __restrict__ gedge,
    const float* __restrict__ gmask,
    const float* __restrict__ w1, const float* __restrict__ as1,
    const float* __restrict__ ad1, const float* __restrict__ b1,
    const float* __restrict__ w2, const float* __restrict__ as2,
    const float* __restrict__ ad2, const float* __restrict__ b2,
    const float* __restrict__ miw, const float* __restrict__ mib,
    const float* __restrict__ mow, const float* __restrict__ mob,
    const float* __restrict__ wq, const float* __restrict__ bq,
    const float* __restrict__ wk, const float* __restrict__ bk,
    const float* __restrict__ wv, const float* __restrict__ bv,
    const float* __restrict__ ws, const float* __restrict__ bs,
    const float* __restrict__ mw1, const float* __restrict__ mb1,
    const float* __restrict__ mw2, const float* __restrict__ mb2,
    const float* __restrict__ cw, const float* __restrict__ cb,
    float* __restrict__ out)
{
    const int tid = threadIdx.x;

    __shared__ float sM[NN * NN];                    // adjacency counts
    __shared__ alignas(16) float sS[3200];           // GAT1 h8/o8 -> MLP hid64
    __shared__ alignas(16) float sL[2656];           // padded L (QS) -> MHA scores (LS)
    __shared__ alignas(16) float sQ2[(KL + 2) * QS]; // Lanczos vectors
    __shared__ alignas(16) float sW[QS];             // work / Fiedler
    __shared__ float sD[KL + 2];
    __shared__ float sAl_[KL + 2];
    __shared__ float sBe_[KL + 2];
    __shared__ float sY[KL + 2];
    __shared__ float sCp[KL + 2];
    __shared__ float sDp2[KL + 2];
    __shared__ float sTh[2];
    __shared__ int   sKeff;
    __shared__ float sX[NN * 5];
    __shared__ float sH5a[NN * 5];   // v / tv
    __shared__ float sH5b[NN * 5];   // tq / tc-out
    __shared__ float sH5c[NN * 5];   // hM
    __shared__ float sH5d[NN * 5];   // k / tk
    __shared__ int   sSrc[ET];
    __shared__ int   sDst[ET];
    __shared__ int   sSrcCsr[ET];
    __shared__ int   sDstCsr[ET];
    __shared__ float sECsr[ET];
    __shared__ float sAs[NN];
    __shared__ float sAd[NN];
    __shared__ float sdis[NN];
    __shared__ float sred[4];
    __shared__ int   sOff[NN + 1];
    __shared__ int   sCnt[NN];
    // staged weights (filled by waves 2-3 during Lanczos)
    __shared__ float sW1[40], sAs1[8], sAd1[8], sB1[8];
    __shared__ float sW2[40], sAs2[5], sAd2[5], sB2[5];
    __shared__ float sMiw[75], sMib[15], sMow[25], sMob[5];
    __shared__ float sWq[25], sBq[5], sWk[25], sBk[5];
    __shared__ float sWv[25], sBv[5], sWsk[25], sBsk[5];
    __shared__ float sMw1[320], sMb1[64];
    __shared__ alignas(16) float sMw2[NN * MS];
    __shared__ float sMb2[NN], sCw[NN], sCb0[1], sMask[NN], sGx[NN * 3];

    // ---------------- edges (with self loops) + adjacency + counts ----------------
    for (int t = tid; t < ET; t += NTHR) {
        int s, d;
        if (t < E2) { s = gedge[t]; d = gedge[E2 + t]; }
        else        { s = t - E2;   d = t - E2; }
        sSrc[t] = s; sDst[t] = d;
    }
    for (int t = tid; t < NN * NN; t += NTHR) sM[t] = 0.0f;
    for (int i = tid; i < NN; i += NTHR) sCnt[i] = 0;
    if (tid == 0) sKeff = KL;
    __syncthreads();
    for (int t = tid; t < E2; t += NTHR)
        atomicAdd(&sM[sSrc[t] * NN + sDst[t]], 1.0f);
    for (int e = tid; e < ET; e += NTHR)
        atomicAdd(&sCnt[sDst[e]], 1);
    __syncthreads();
    if (tid == 0) {
        int acc = 0;
        for (int i = 0; i < NN; ++i) { sOff[i] = acc; acc += sCnt[i]; }
        sOff[NN] = acc;
    }
    __syncthreads();
    // (CSR scatter deferred to wave 1, under Lanczos)

    // ---------------- degree, u0 raw, padded Laplacian ----------------
    for (int i = tid; i < NN; i += NTHR) {
        float dsum = 0.0f;
        for (int j = 0; j < NN; ++j) dsum += sM[i * NN + j];
        sdis[i] = (dsum > 0.0f) ? (1.0f / sqrtf(fmaxf(dsum, 1e-12f))) : 0.0f;
        sQ2[i] = sqrtf(dsum);
    }
    __syncthreads();
    for (int t = tid; t < NN * QS; t += NTHR) {
        int i = t / QS, k = t - i * QS;
        sL[t] = (k < NN)
              ? (((i == k) ? 1.0f : 0.0f) - sdis[i] * sM[i * NN + k] * sdis[k])
              : 0.0f;
    }
    __syncthreads();

    // ==== wave0: Lanczos (CGS1) | wave1: CSR scatter | waves2-3: staging ====
    if (tid < 64) {
        const int lane = tid;
        {   // normalize u0; deterministic start q1 orthogonal to u0
            float q0 = (lane < NN) ? sQ2[lane] : 0.0f;
            float nn = q0 * q0;
            for (int off = 32; off > 0; off >>= 1) nn += __shfl_xor(nn, off);
            q0 *= rsqrtf(nn);
            unsigned u = (unsigned)lane * 2654435761u + 12345u;
            u ^= u >> 13; u *= 2246822519u; u ^= u >> 11;
            float q1 = (lane < NN) ? ((float)(u & 0xFFFF) * (1.0f / 65536.0f) - 0.5f) : 0.0f;
            for (int pass = 0; pass < 2; ++pass) {
                float d = q0 * q1;
                for (int off = 32; off > 0; off >>= 1) d += __shfl_xor(d, off);
                q1 -= d * q0;
            }
            float n1 = q1 * q1;
            for (int off = 32; off > 0; off >>= 1) n1 += __shfl_xor(n1, off);
            q1 *= rsqrtf(n1);
            if (lane < NN) { sQ2[lane] = q0; sQ2[QS + lane] = q1; }
            WSYNC();
        }
        for (int j = 1; j <= KL; ++j) {
            const float* qp = &sQ2[j * QS];
            const float4* qp4 = (const float4*)qp;
            float w = 0.0f;
            if (lane < NN) {
                const float* rp = &sL[lane * QS];
                const float4* rp4 = (const float4*)rp;
                float a0 = 0.0f, a1 = 0.0f, a2 = 0.0f, a3 = 0.0f;
                for (int k = 0; k < 12; ++k) {
                    float4 r = rp4[k], q = qp4[k];
                    a0 += r.x * q.x; a1 += r.y * q.y;
                    a2 += r.z * q.z; a3 += r.w * q.w;
                }
                a0 += rp[48] * qp[48];
                a1 += rp[49] * qp[49];
                w = 2.0f * qp[lane] - (a0 + a1 + a2 + a3);
            }
            // single-pass CGS reorth against q_0..q_j
            if (lane < NN) sW[lane] = w;
            WSYNC();
            if (lane <= j) {
                const float* qm = &sQ2[lane * QS];
                const float4* qm4 = (const float4*)qm;
                const float4* x4 = (const float4*)sW;
                float a0 = 0.0f, a1 = 0.0f, a2 = 0.0f, a3 = 0.0f;
                for (int k = 0; k < 12; ++k) {
                    float4 r = qm4[k], x = x4[k];
                    a0 += r.x * x.x; a1 += r.y * x.y;
                    a2 += r.z * x.z; a3 += r.w * x.w;
                }
                a0 += qm[48] * sW[48];
                a1 += qm[49] * sW[49];
                sD[lane] = (a0 + a1) + (a2 + a3);
            }
            WSYNC();
            float alpha = sD[j];
            if (lane < NN) {
                float acc = 0.0f;
                for (int m = 0; m <= j; ++m) acc += sD[m] * sQ2[m * QS + lane];
                w -= acc;
            }
            WSYNC();
            float nn2 = w * w;
            for (int off = 32; off > 0; off >>= 1) nn2 += __shfl_xor(nn2, off);
            float beta = sqrtf(nn2);
            if (lane == 0) { sAl_[j] = alpha; sBe_[j] = beta; }
            if (j < KL) {
                if (beta > 1e-10f) {
                    if (lane < NN) sQ2[(j + 1) * QS + lane] = w * (1.0f / beta);
                    WSYNC();
                } else {
                    if (lane == 0) sKeff = j;
                    break;
                }
            }
        }
    } else if (tid < 128) {
        const int d = tid - 64;
        if (d < NN) {                         // CSR scatter (deterministic order)
            int pos = sOff[d];
            for (int e = 0; e < ET; ++e)
                if (sDst[e] == d) { sSrcCsr[pos] = sSrc[e]; sDstCsr[pos] = d; pos++; }
        }
    } else {
        const int t0 = tid - 128;
        cpy128(sW1, w1, 40, t0);   cpy128(sAs1, as1, 8, t0);
        cpy128(sAd1, ad1, 8, t0);  cpy128(sB1, b1, 8, t0);
        cpy128(sW2, w2, 40, t0);   cpy128(sAs2, as2, 5, t0);
        cpy128(sAd2, ad2, 5, t0);  cpy128(sB2, b2, 5, t0);
        cpy128(sMiw, miw, 75, t0); cpy128(sMib, mib, 15, t0);
        cpy128(sMow, mow, 25, t0); cpy128(sMob, mob, 5, t0);
        cpy128(sWq, wq, 25, t0);   cpy128(sBq, bq, 5, t0);
        cpy128(sWk, wk, 25, t0);   cpy128(sBk, bk, 5, t0);
        cpy128(sWv, wv, 25, t0);   cpy128(sBv, bv, 5, t0);
        cpy128(sWsk, ws, 25, t0);  cpy128(sBsk, bs, 5, t0);
        for (int t = t0; t < 320; t += 128) {
            int o = t / 5, k = t - 5 * o;
            sMw1[t] = mw1[o * 250 + k];
        }
        for (int t = t0; t < 3200; t += 128) {
            int o = t >> 6, k = t & 63;
            sMw2[o * MS + k] = mw2[t];
        }
        cpy128(sMb1, mb1, 64, t0);
        cpy128(sMb2, mb2, NN, t0); cpy128(sCw, cw, NN, t0);
        cpy128(sCb0, cb, 1, t0);   cpy128(sMask, gmask, NN, t0);
        cpy128(sGx, gx, NN * 3, t0);
    }
    __syncthreads();

    // ---------------- top Ritz pair of T ----------------
    const int keff = sKeff;
    if (tid < 64) {
        float lo = 1e30f, hi = -1e30f;
        for (int m = 1; m <= keff; ++m) {
            float r = ((m > 1) ? fabsf(sBe_[m - 1]) : 0.0f)
                    + ((m < keff) ? fabsf(sBe_[m]) : 0.0f);
            lo = fminf(lo, sAl_[m] - r);
            hi = fmaxf(hi, sAl_[m] + r);
        }
        for (int round = 0; round < 4; ++round) {
            float h = (hi - lo) * (1.0f / 65.0f);
            float x = lo + (float)(tid + 1) * h;
            int cnt = 0;
            float d = sAl_[1] - x;
            if (d < 0.0f) cnt++;
            for (int m = 2; m <= keff; ++m) {
                float b = sBe_[m - 1];
                float dd = (fabsf(d) < 1e-20f) ? ((d >= 0.0f) ? 1e-20f : -1e-20f) : d;
                d = sAl_[m] - x - b * b / dd;
                if (d < 0.0f) cnt++;
            }
            unsigned long long msk = __ballot(cnt >= keff);
            int f = (msk == 0ULL) ? 64 : (__ffsll((unsigned long long)msk) - 1);
            float nlo = (f == 0) ? lo : (lo + (float)f * h);
            float nhi = (f == 64) ? hi : (lo + (float)(f + 1) * h);
            lo = nlo; hi = nhi;
        }
        if (tid == 0) sTh[0] = 0.5f * (lo + hi);
    }
    __syncthreads();
    if (tid == 0) {
        const float th = sTh[0];
        if (keff == 1) {
            sY[1] = 1.0f;
        } else {
            float inv0 = rsqrtf((float)keff);
            for (int m = 1; m <= keff; ++m) sY[m] = inv0;
            float d1 = sAl_[1] - th;
            if (fabsf(d1) < 1e-10f) d1 = (d1 >= 0.0f) ? 1e-10f : -1e-10f;
            sCp[1] = sBe_[1] / d1;
            sDp2[1] = sY[1] / d1;
            for (int m = 2; m <= keff; ++m) {
                float den = sAl_[m] - th - sBe_[m - 1] * sCp[m - 1];
                if (fabsf(den) < 1e-10f) den = (den >= 0.0f) ? 1e-10f : -1e-10f;
                if (m < keff) sCp[m] = sBe_[m] / den;
                sDp2[m] = (sY[m] - sBe_[m - 1] * sDp2[m - 1]) / den;
            }
            sY[keff] = sDp2[keff];
            for (int m = keff - 1; m >= 1; --m)
                sY[m] = sDp2[m] - sCp[m] * sY[m + 1];
            float nn = 0.0f;
            for (int m = 1; m <= keff; ++m) nn += sY[m] * sY[m];
            float sc = rsqrtf(nn);
            for (int m = 1; m <= keff; ++m) sY[m] *= sc;
        }
    }
    __syncthreads();
    if (tid < NN) {
        float acc = 0.0f;
        for (int m = 1; m <= keff; ++m) acc += sY[m] * sQ2[m * QS + tid];
        sW[tid] = acc;
    }
    __syncthreads();
    if (tid < 64) {
        float v = (tid < NN) ? sW[tid] : 0.0f;
        float nn = v * v;
        for (int off = 32; off > 0; off >>= 1) nn += __shfl_xor(nn, off);
        float av = fabsf(v);
        for (int off = 32; off > 0; off >>= 1) av = fmaxf(av, __shfl_xor(av, off));
        unsigned long long msk = __ballot((fabsf(v) == av) && (tid < NN));
        int fl = __ffsll((unsigned long long)msk) - 1;
        float sv = __shfl(v, fl);
        float scale = ((sv >= 0.0f) ? 1.0f : -1.0f) * rsqrtf(nn);
        if (tid < NN) sW[tid] = v * scale;
    }
    __syncthreads();
    for (int i = tid; i < NN; i += NTHR) {
        sX[i * 5 + 0] = sGx[i * 3 + 0];
        sX[i * 5 + 1] = sGx[i * 3 + 1];
        sX[i * 5 + 2] = sGx[i * 3 + 2];
        sX[i * 5 + 3] = sQ2[i];
        sX[i * 5 + 4] = sW[i];
    }
    __syncthreads();

    const float inv_sqrt5 = 0.4472135954999579f;

    // ==== wave0: fused single-wave GNN tail | waves1-3: aux outputs ====
    if (tid < 64) {
        const int lane = tid;
        float* h8 = sS;                       // 50x8
        // ---- GAT1 phase A: per-node linear + attn coeffs ----
        float h8r[8];
        if (lane < NN) {
            float xr[5];
#pragma unroll
            for (int k = 0; k < 5; ++k) xr[k] = sX[lane * 5 + k];
            float a = 0.0f, b = 0.0f;
#pragma unroll
            for (int o = 0; o < 8; ++o) {
                float acc = 0.0f;
#pragma unroll
                for (int k = 0; k < 5; ++k) acc += xr[k] * sW1[o * 5 + k];
                h8r[o] = acc;
                h8[lane * 8 + o] = acc;
                a += acc * sAs1[o];
                b += acc * sAd1[o];
            }
            sAs[lane] = a; sAd[lane] = b;
        }
        WSYNC();
        // ---- GAT1 phase B: edge scores ----
#pragma unroll
        for (int c = 0; c < 8; ++c) {
            int e = lane + 64 * c;
            if (e < ET) {
                float v = sAs[sSrcCsr[e]] + sAd[sDstCsr[e]];
                sECsr[e] = (v > 0.0f) ? v : 0.2f * v;
            }
        }
        WSYNC();
        // ---- GAT1 phase C: fused softmax + aggregate + ReLU ----
        float o8r[8];
        if (lane < NN) {
            const int c0 = sOff[lane], c1 = sOff[lane + 1];
            float m = -1e30f;
            for (int c = c0; c < c1; ++c) m = fmaxf(m, sECsr[c]);
            float su = 0.0f;
            for (int c = c0; c < c1; ++c) su += expf(sECsr[c] - m);
            float inv = 1.0f / (su + 1e-16f);
            float acc[8];
#pragma unroll
            for (int o = 0; o < 8; ++o) acc[o] = sB1[o];
            for (int c = c0; c < c1; ++c) {
                float p = expf(sECsr[c] - m) * inv;
                const int s2 = sSrcCsr[c];
#pragma unroll
                for (int o = 0; o < 8; ++o) acc[o] += p * h8[s2 * 8 + o];
            }
#pragma unroll
            for (int o = 0; o < 8; ++o) {
                o8r[o] = fmaxf(acc[o], 0.0f);
                h8[1600 + lane * 8 + o] = o8r[o];   // o8 region
            }
        }
        WSYNC();
        // ---- GAT2 phase A (din=8, dout=5): own row in regs ----
        if (lane < NN) {
            float a = 0.0f, b = 0.0f;
#pragma unroll
            for (int o = 0; o < 5; ++o) {
                float acc = 0.0f;
#pragma unroll
                for (int k = 0; k < 8; ++k) acc += o8r[k] * sW2[o * 8 + k];
                sH5a[lane * 5 + o] = acc;          // h5 rows
                a += acc * sAs2[o];
                b += acc * sAd2[o];
            }
            sAs[lane] = a; sAd[lane] = b;
        }
        WSYNC();
#pragma unroll
        for (int c = 0; c < 8; ++c) {
            int e = lane + 64 * c;
            if (e < ET) {
                float v = sAs[sSrcCsr[e]] + sAd[sDstCsr[e]];
                sECsr[e] = (v > 0.0f) ? v : 0.2f * v;
            }
        }
        WSYNC();
        float hr[5];                                // GAT2 out (MHA input), regs
        if (lane < NN) {
            const int c0 = sOff[lane], c1 = sOff[lane + 1];
            float m = -1e30f;
            for (int c = c0; c < c1; ++c) m = fmaxf(m, sECsr[c]);
            float su = 0.0f;
            for (int c = c0; c < c1; ++c) su += expf(sECsr[c] - m);
            float inv = 1.0f / (su + 1e-16f);
#pragma unroll
            for (int o = 0; o < 5; ++o) hr[o] = sB2[o];
            for (int c = c0; c < c1; ++c) {
                float p = expf(sECsr[c] - m) * inv;
                const int s2 = sSrcCsr[c];
#pragma unroll
                for (int o = 0; o < 5; ++o) hr[o] += p * sH5a[s2 * 5 + o];
            }
        }
        WSYNC();
        // ---- MHA phase A: q (regs), k -> sH5d, v -> sH5a ----
        float qr[5];
        if (lane < NN) {
#pragma unroll
            for (int o = 0; o < 5; ++o) {
                float q_ = sMib[o], k_ = sMib[o + 5], v_ = sMib[o + 10];
#pragma unroll
                for (int k = 0; k < 5; ++k) {
                    q_ += hr[k] * sMiw[o * 5 + k];
                    k_ += hr[k] * sMiw[(o + 5) * 5 + k];
                    v_ += hr[k] * sMiw[(o + 10) * 5 + k];
                }
                qr[o] = q_;
                sH5d[lane * 5 + o] = k_;
                sH5a[lane * 5 + o] = v_;
            }
        }
        WSYNC();
        // ---- MHA phase B: row softmax + attn@v + out proj (lane-local) ----
        float hm[5];
        if (lane < NN) {
            float* srow = &sL[lane * LS];
            float m = -1e30f;
            for (int j = 0; j < NN; ++j) {
                float acc = 0.0f;
#pragma unroll
                for (int k = 0; k < 5; ++k) acc += qr[k] * sH5d[j * 5 + k];
                acc *= inv_sqrt5;
                srow[j] = acc;
                m = fmaxf(m, acc);
            }
            float su = 0.0f;
            for (int j = 0; j < NN; ++j) {
                float p = expf(srow[j] - m);
                srow[j] = p;
                su += p;
            }
            float inv = 1.0f / su;
            float a5[5] = {0.0f, 0.0f, 0.0f, 0.0f, 0.0f};
            for (int j = 0; j < NN; ++j) {
                float p = srow[j];
#pragma unroll
                for (int f = 0; f < 5; ++f) a5[f] += p * sH5a[j * 5 + f];
            }
#pragma unroll
            for (int f = 0; f < 5; ++f) a5[f] *= inv;
#pragma unroll
            for (int o = 0; o < 5; ++o) {
                float acc = sMob[o];
#pragma unroll
                for (int k = 0; k < 5; ++k) acc += a5[k] * sMow[o * 5 + k];
                hm[o] = acc;
                sH5c[lane * 5 + o] = acc;
            }
        }
        WSYNC();
        // ---- TC phase A: tq -> sH5b, tk -> sH5d, tv -> sH5a, skip (regs) ----
        float skip[5];
        if (lane < NN) {
#pragma unroll
            for (int o = 0; o < 5; ++o) {
                float q_ = sBq[o], k_ = sBk[o], v_ = sBv[o], s_ = sBsk[o];
#pragma unroll
                for (int k = 0; k < 5; ++k) {
                    q_ += hm[k] * sWq[o * 5 + k];
                    k_ += hm[k] * sWk[o * 5 + k];
                    v_ += hm[k] * sWv[o * 5 + k];
                    s_ += hm[k] * sWsk[o * 5 + k];
                }
                sH5b[lane * 5 + o] = q_;
                sH5d[lane * 5 + o] = k_;
                sH5a[lane * 5 + o] = v_;
                skip[o] = s_;
            }
        }
        WSYNC();
        // ---- TC phase B: edge scores ----
#pragma unroll
        for (int c = 0; c < 8; ++c) {
            int e = lane + 64 * c;
            if (e < ET) {
                const int s2 = sSrcCsr[e], d2 = sDstCsr[e];
                float acc = 0.0f;
#pragma unroll
                for (int k = 0; k < 5; ++k) acc += sH5b[d2 * 5 + k] * sH5d[s2 * 5 + k];
                sECsr[e] = acc * inv_sqrt5;
            }
        }
        WSYNC();
        // ---- TC phase C: fused softmax + aggregate + skip ----
        if (lane < NN) {
            const int c0 = sOff[lane], c1 = sOff[lane + 1];
            float m = -1e30f;
            for (int c = c0; c < c1; ++c) m = fmaxf(m, sECsr[c]);
            float su = 0.0f;
            for (int c = c0; c < c1; ++c) su += expf(sECsr[c] - m);
            float inv = 1.0f / (su + 1e-16f);
            float acc[5];
#pragma unroll
            for (int o = 0; o < 5; ++o) acc[o] = skip[o];
            for (int c = c0; c < c1; ++c) {
                float p = expf(sECsr[c] - m) * inv;
                const int s2 = sSrcCsr[c];
#pragma unroll
                for (int o = 0; o < 5; ++o) acc[o] += p * sH5a[s2 * 5 + o];
            }
#pragma unroll
            for (int o = 0; o < 5; ++o) sH5b[lane * 5 + o] = acc[o];  // tc out
        }
        WSYNC();
        // ---- MLP1 (lane = hidden unit) ----
        {
            float wv5[5];
#pragma unroll
            for (int k = 0; k < 5; ++k) wv5[k] = sMw1[lane * 5 + k];
            const float bo = sMb1[lane];
            for (int i = 0; i < NN; ++i) {
                float acc = bo;
#pragma unroll
                for (int k = 0; k < 5; ++k) acc += sH5b[i * 5 + k] * wv5[k];
                sS[i * 64 + lane] = fmaxf(acc, 0.0f);
            }
        }
    } else {
        // waves 1-3: x_combined + ei outputs (off critical path)
        for (int t = tid - 64; t < NN * 5; t += 192) out[2501 + t] = sX[t];
        for (int t = tid - 64; t < 2 * ET; t += 192) {
            int val = (t < ET) ? sSrc[t] : sDst[t - ET];
            out[2751 + t] = (float)val;
        }
    }
    __syncthreads();

    // ---------------- MLP2 + fused critic (4 waves) ----------------
    float part = 0.0f;
    for (int t = tid; t < NN * NN; t += NTHR) {
        int i = t / NN, j = t - i * NN;
        const float4* sp4 = (const float4*)&sS[i * 64];
        const float4* wp4 = (const float4*)&sMw2[j * MS];
        float a0 = 0.0f, a1 = 0.0f, a2 = 0.0f, a3 = 0.0f;
        for (int k = 0; k < 16; ++k) {
            float4 a = sp4[k], b = wp4[k];
            a0 += a.x * b.x; a1 += a.y * b.y;
            a2 += a.z * b.z; a3 += a.w * b.w;
        }
        float acc = sMb2[j] + (a0 + a1) + (a2 + a3);
        out[t] = acc * sMask[j];
        part += acc * sCw[j];
    }
    for (int off = 32; off > 0; off >>= 1) part += __shfl_xor(part, off);
    if ((tid & 63) == 0) sred[tid >> 6] = part;
    __syncthreads();
    if (tid == 0)
        out[2500] = (sred[0] + sred[1] + sred[2] + sred[3]) * (1.0f / NN) + sCb0[0];
}

extern "C" void kernel_launch(void* const* d_in, const int* in_sizes, int n_in,
                              void* d_out, int out_size, void* d_ws, size_t ws_size,
                              hipStream_t stream) {
    (void)in_sizes; (void)n_in; (void)d_ws; (void)ws_size; (void)out_size;
    opn_kernel<<<1, NTHR, 0, stream>>>(
        (const float*)d_in[0], (const int*)d_in[1], (const float*)d_in[2],
        (const float*)d_in[3], (const float*)d_in[4], (const float*)d_in[5], (const float*)d_in[6],
        (const float*)d_in[7], (const float*)d_in[8], (const float*)d_in[9], (const float*)d_in[10],
        (const float*)d_in[11], (const float*)d_in[12], (const float*)d_in[13], (const float*)d_in[14],
        (const float*)d_in[15], (const float*)d_in[16], (const float*)d_in[17], (const float*)d_in[18],
        (const float*)d_in[19], (const float*)d_in[20], (const float*)d_in[21], (const float*)d_in[22],
        (const float*)d_in[23], (const float*)d_in[24], (const float*)d_in[25], (const float*)d_in[26],
        (const float*)d_in[27], (const float*)d_in[28],
        (float*)d_out);
}

// Round 11
// 76.954 us; speedup vs baseline: 4.5835x; 1.0073x over previous
//
#include <hip/hip_runtime.h>
#include <math.h>

#define NN 50
#define E2 400
#define ET 450
#define NTHR 256
#define KL 12            // Lanczos iterations
#define QS 52            // padded row stride (16B-aligned rows)
#define MS 68            // padded sMw2 row stride
#define LS 53            // MHA score-row stride (odd -> conflict-free)

// Intra-wave LDS handoff fence: drain LDS ops, forbid compiler reordering.
#define WSYNC() do { asm volatile("s_waitcnt lgkmcnt(0)" ::: "memory"); \
                     __builtin_amdgcn_sched_barrier(0); } while (0)

__device__ __noinline__ void cpy128(float* d, const float* s, int n, int t0) {
    for (int t = t0; t < n; t += 128) d[t] = s[t];
}

__global__ __launch_bounds__(NTHR, 1) void opn_kernel(
    const float* __restrict__ gx, const int* __restrict__ gedge,
    const float* __restrict__ gmask,
    const float* __restrict__ w1, const float* __restrict__ as1,
    const float* __restrict__ ad1, const float* __restrict__ b1,
    const float* __restrict__ w2, const float* __restrict__ as2,
    const float* __restrict__ ad2, const float* __restrict__ b2,
    const float* __restrict__ miw, const float* __restrict__ mib,
    const float* __restrict__ mow, const float* __restrict__ mob,
    const float* __restrict__ wq, const float* __restrict__ bq,
    const float* __restrict__ wk, const float* __restrict__ bk,
    const float* __restrict__ wv, const float* __restrict__ bv,
    const float* __restrict__ ws, const float* __restrict__ bs,
    const float* __restrict__ mw1, const float* __restrict__ mb1,
    const float* __restrict__ mw2, const float* __restrict__ mb2,
    const float* __restrict__ cw, const float* __restrict__ cb,
    float* __restrict__ out)
{
    const int tid = threadIdx.x;

    __shared__ float sM[NN * NN];                    // adjacency counts
    __shared__ alignas(16) float sS[3200];           // GAT1 h8 -> MLP hid64
    __shared__ alignas(16) float sL[2656];           // padded L (QS) -> MHA scores (LS)
    __shared__ alignas(16) float sQ2[(KL + 2) * QS]; // Lanczos vectors
    __shared__ float sAl_[KL + 2];
    __shared__ float sBe_[KL + 2];
    __shared__ float sY[KL + 2];
    __shared__ float sCp[KL + 2];
    __shared__ float sDp2[KL + 2];
    __shared__ int   sKeff;
    __shared__ float sH5a[NN * 5];   // h5 / v / tv
    __shared__ float sH5b[NN * 5];   // tq / tc-out
    __shared__ float sH5d[NN * 5];   // k / tk
    __shared__ int   sSrc[ET];
    __shared__ int   sDst[ET];
    __shared__ int   sSrcCsr[ET];
    __shared__ int   sDstCsr[ET];
    __shared__ float sECsr[ET];
    __shared__ float sAs[NN];
    __shared__ float sAd[NN];
    __shared__ float sdis[NN];
    __shared__ float sred[4];
    __shared__ int   sOff[NN + 1];
    __shared__ int   sCnt[NN];
    // staged weights (filled by waves 2-3 during Lanczos)
    __shared__ float sW1[40], sAs1[8], sAd1[8], sB1[8];
    __shared__ float sW2[40], sAs2[5], sAd2[5], sB2[5];
    __shared__ float sMiw[75], sMib[15], sMow[25], sMob[5];
    __shared__ float sWq[25], sBq[5], sWk[25], sBk[5];
    __shared__ float sWv[25], sBv[5], sWsk[25], sBsk[5];
    __shared__ float sMw1[320], sMb1[64];
    __shared__ alignas(16) float sMw2[NN * MS];
    __shared__ float sMb2[NN], sCw[NN], sCb0[1], sMask[NN], sGx[NN * 3];

    // ---------------- edges (with self loops) + adjacency + counts ----------------
    for (int t = tid; t < ET; t += NTHR) {
        int s, d;
        if (t < E2) { s = gedge[t]; d = gedge[E2 + t]; }
        else        { s = t - E2;   d = t - E2; }
        sSrc[t] = s; sDst[t] = d;
    }
    for (int t = tid; t < NN * NN; t += NTHR) sM[t] = 0.0f;
    for (int i = tid; i < NN; i += NTHR) sCnt[i] = 0;
    if (tid == 0) sKeff = KL;
    __syncthreads();
    for (int t = tid; t < E2; t += NTHR)
        atomicAdd(&sM[sSrc[t] * NN + sDst[t]], 1.0f);
    for (int e = tid; e < ET; e += NTHR)
        atomicAdd(&sCnt[sDst[e]], 1);
    __syncthreads();
    if (tid == 0) {
        int acc = 0;
        for (int i = 0; i < NN; ++i) { sOff[i] = acc; acc += sCnt[i]; }
        sOff[NN] = acc;
    }
    __syncthreads();

    // ---------------- degree, u0 raw, padded Laplacian ----------------
    for (int i = tid; i < NN; i += NTHR) {
        float dsum = 0.0f;
        for (int j = 0; j < NN; ++j) dsum += sM[i * NN + j];
        sdis[i] = (dsum > 0.0f) ? (1.0f / sqrtf(fmaxf(dsum, 1e-12f))) : 0.0f;
        sQ2[i] = sqrtf(dsum);
    }
    __syncthreads();
    for (int t = tid; t < NN * QS; t += NTHR) {
        int i = t / QS, k = t - i * QS;
        sL[t] = (k < NN)
              ? (((i == k) ? 1.0f : 0.0f) - sdis[i] * sM[i * NN + k] * sdis[k])
              : 0.0f;
    }
    __syncthreads();

    // ==== wave0: 3-term Lanczos | wave1: CSR + ei out | waves2-3: staging ====
    if (tid < 64) {
        const int lane = tid;
        float q0r, qprev = 0.0f, qcur;
        {   // normalize u0; deterministic start q1 orthogonal to u0
            float q0 = (lane < NN) ? sQ2[lane] : 0.0f;
            float nn = q0 * q0;
            for (int off = 32; off > 0; off >>= 1) nn += __shfl_xor(nn, off);
            q0 *= rsqrtf(nn);
            unsigned u = (unsigned)lane * 2654435761u + 12345u;
            u ^= u >> 13; u *= 2246822519u; u ^= u >> 11;
            float q1 = (lane < NN) ? ((float)(u & 0xFFFF) * (1.0f / 65536.0f) - 0.5f) : 0.0f;
            for (int pass = 0; pass < 2; ++pass) {
                float d = q0 * q1;
                for (int off = 32; off > 0; off >>= 1) d += __shfl_xor(d, off);
                q1 -= d * q0;
            }
            float n1 = q1 * q1;
            for (int off = 32; off > 0; off >>= 1) n1 += __shfl_xor(n1, off);
            q1 *= rsqrtf(n1);
            q0r = q0; qcur = q1;
            if (lane < NN) { sQ2[lane] = q0; sQ2[QS + lane] = q1; }
            WSYNC();
        }
        for (int j = 1; j <= KL; ++j) {
            const float* qp = &sQ2[j * QS];
            const float4* qp4 = (const float4*)qp;
            float w = 0.0f;
            if (lane < NN) {
                const float* rp = &sL[lane * QS];
                const float4* rp4 = (const float4*)rp;
                float a0 = 0.0f, a1 = 0.0f, a2 = 0.0f, a3 = 0.0f;
                for (int k = 0; k < 12; ++k) {
                    float4 r = rp4[k], q = qp4[k];
                    a0 += r.x * q.x; a1 += r.y * q.y;
                    a2 += r.z * q.z; a3 += r.w * q.w;
                }
                a0 += rp[48] * qp[48];
                a1 += rp[49] * qp[49];
                w = 2.0f * qcur - (a0 + a1 + a2 + a3);
            }
            // register-only reorth: q0 (deflation) + q_{j-1} + q_j
            float c0 = q0r * w, c1 = qprev * w, ca = qcur * w;
#pragma unroll
            for (int off = 32; off > 0; off >>= 1) {
                c0 += __shfl_xor(c0, off);
                c1 += __shfl_xor(c1, off);
                ca += __shfl_xor(ca, off);
            }
            w -= c0 * q0r + c1 * qprev + ca * qcur;
            float nn2 = w * w;
#pragma unroll
            for (int off = 32; off > 0; off >>= 1) nn2 += __shfl_xor(nn2, off);
            float beta = sqrtf(nn2);
            if (lane == 0) { sAl_[j] = ca; sBe_[j] = beta; }
            if (j < KL) {
                if (beta > 1e-10f) {
                    qprev = qcur;
                    qcur = w * (1.0f / beta);
                    if (lane < NN) sQ2[(j + 1) * QS + lane] = qcur;
                    WSYNC();
                } else {
                    if (lane == 0) sKeff = j;
                    break;
                }
            }
        }
        WSYNC();                                  // sAl_/sBe_/sKeff visible in-wave
    } else if (tid < 128) {
        const int d = tid - 64;
        if (d < NN) {                             // CSR scatter (deterministic)
            int pos = sOff[d];
            for (int e = 0; e < ET; ++e)
                if (sDst[e] == d) { sSrcCsr[pos] = sSrc[e]; sDstCsr[pos] = d; pos++; }
        }
        // ei outputs (only need sSrc/sDst — off critical path)
        for (int t = tid - 64; t < 2 * ET; t += 64) {
            int val = (t < ET) ? sSrc[t] : sDst[t - ET];
            out[2751 + t] = (float)val;
        }
    } else {
        const int t0 = tid - 128;
        cpy128(sW1, w1, 40, t0);   cpy128(sAs1, as1, 8, t0);
        cpy128(sAd1, ad1, 8, t0);  cpy128(sB1, b1, 8, t0);
        cpy128(sW2, w2, 40, t0);   cpy128(sAs2, as2, 5, t0);
        cpy128(sAd2, ad2, 5, t0);  cpy128(sB2, b2, 5, t0);
        cpy128(sMiw, miw, 75, t0); cpy128(sMib, mib, 15, t0);
        cpy128(sMow, mow, 25, t0); cpy128(sMob, mob, 5, t0);
        cpy128(sWq, wq, 25, t0);   cpy128(sBq, bq, 5, t0);
        cpy128(sWk, wk, 25, t0);   cpy128(sBk, bk, 5, t0);
        cpy128(sWv, wv, 25, t0);   cpy128(sBv, bv, 5, t0);
        cpy128(sWsk, ws, 25, t0);  cpy128(sBsk, bs, 5, t0);
        for (int t = t0; t < 320; t += 128) {
            int o = t / 5, k = t - 5 * o;
            sMw1[t] = mw1[o * 250 + k];
        }
        for (int t = t0; t < 3200; t += 128) {
            int o = t >> 6, k = t & 63;
            sMw2[o * MS + k] = mw2[t];
        }
        cpy128(sMb1, mb1, 64, t0);
        cpy128(sMb2, mb2, NN, t0); cpy128(sCw, cw, NN, t0);
        cpy128(sCb0, cb, 1, t0);   cpy128(sMask, gmask, NN, t0);
        cpy128(sGx, gx, NN * 3, t0);
    }
    __syncthreads();   // staged weights + CSR visible to wave 0

    const float inv_sqrt5 = 0.4472135954999579f;

    // ==== wave 0: extraction + full GNN tail (zero barriers inside) ====
    if (tid < 64) {
        const int lane = tid;
        const int keff = sKeff;
        // ---- bisection for top Ritz value (lo/hi lane-uniform) ----
        float lo = 1e30f, hi = -1e30f;
        for (int m = 1; m <= keff; ++m) {
            float r = ((m > 1) ? fabsf(sBe_[m - 1]) : 0.0f)
                    + ((m < keff) ? fabsf(sBe_[m]) : 0.0f);
            lo = fminf(lo, sAl_[m] - r);
            hi = fmaxf(hi, sAl_[m] + r);
        }
        for (int round = 0; round < 4; ++round) {
            float h = (hi - lo) * (1.0f / 65.0f);
            float x = lo + (float)(lane + 1) * h;
            int cnt = 0;
            float d = sAl_[1] - x;
            if (d < 0.0f) cnt++;
            for (int m = 2; m <= keff; ++m) {
                float b = sBe_[m - 1];
                float dd = (fabsf(d) < 1e-20f) ? ((d >= 0.0f) ? 1e-20f : -1e-20f) : d;
                d = sAl_[m] - x - b * b / dd;
                if (d < 0.0f) cnt++;
            }
            unsigned long long msk = __ballot(cnt >= keff);
            int f = (msk == 0ULL) ? 64 : (__ffsll((unsigned long long)msk) - 1);
            float nlo = (f == 0) ? lo : (lo + (float)f * h);
            float nhi = (f == 64) ? hi : (lo + (float)(f + 1) * h);
            lo = nlo; hi = nhi;
        }
        const float th = 0.5f * (lo + hi);
        // ---- inverse iteration on T (lane 0, Thomas) ----
        if (lane == 0) {
            if (keff == 1) {
                sY[1] = 1.0f;
            } else {
                float inv0 = rsqrtf((float)keff);
                for (int m = 1; m <= keff; ++m) sY[m] = inv0;
                float d1 = sAl_[1] - th;
                if (fabsf(d1) < 1e-10f) d1 = (d1 >= 0.0f) ? 1e-10f : -1e-10f;
                sCp[1] = sBe_[1] / d1;
                sDp2[1] = sY[1] / d1;
                for (int m = 2; m <= keff; ++m) {
                    float den = sAl_[m] - th - sBe_[m - 1] * sCp[m - 1];
                    if (fabsf(den) < 1e-10f) den = (den >= 0.0f) ? 1e-10f : -1e-10f;
                    if (m < keff) sCp[m] = sBe_[m] / den;
                    sDp2[m] = (sY[m] - sBe_[m - 1] * sDp2[m - 1]) / den;
                }
                sY[keff] = sDp2[keff];
                for (int m = keff - 1; m >= 1; --m)
                    sY[m] = sDp2[m] - sCp[m] * sY[m + 1];
                float nn = 0.0f;
                for (int m = 1; m <= keff; ++m) nn += sY[m] * sY[m];
                float sc = rsqrtf(nn);
                for (int m = 1; m <= keff; ++m) sY[m] *= sc;
            }
        }
        WSYNC();
        // ---- Fiedler = Q y, normalize, canonical sign (registers) ----
        float v = 0.0f;
        if (lane < NN)
            for (int m = 1; m <= keff; ++m) v += sY[m] * sQ2[m * QS + lane];
        {
            float nn = v * v;
            for (int off = 32; off > 0; off >>= 1) nn += __shfl_xor(nn, off);
            float av = fabsf(v);
            for (int off = 32; off > 0; off >>= 1) av = fmaxf(av, __shfl_xor(av, off));
            unsigned long long msk = __ballot((fabsf(v) == av) && (lane < NN));
            int fl = __ffsll((unsigned long long)msk) - 1;
            float sv = __shfl(v, fl);
            v *= ((sv >= 0.0f) ? 1.0f : -1.0f) * rsqrtf(nn);
        }
        // ---- x_combined (registers + output) ----
        float xr[5];
        if (lane < NN) {
            xr[0] = sGx[lane * 3 + 0];
            xr[1] = sGx[lane * 3 + 1];
            xr[2] = sGx[lane * 3 + 2];
            xr[3] = sQ2[lane];      // u0
            xr[4] = v;              // Fiedler
#pragma unroll
            for (int k = 0; k < 5; ++k) out[2501 + lane * 5 + k] = xr[k];
        }

        float* h8 = sS;                       // 50x8
        // ---- GAT1 A: linear + attn coeffs ----
        float h8r[8];
        if (lane < NN) {
            float a = 0.0f, b = 0.0f;
#pragma unroll
            for (int o = 0; o < 8; ++o) {
                float acc = 0.0f;
#pragma unroll
                for (int k = 0; k < 5; ++k) acc += xr[k] * sW1[o * 5 + k];
                h8r[o] = acc;
                h8[lane * 8 + o] = acc;
                a += acc * sAs1[o];
                b += acc * sAd1[o];
            }
            sAs[lane] = a; sAd[lane] = b;
        }
        WSYNC();
        // ---- GAT1 B: edge scores ----
#pragma unroll
        for (int c = 0; c < 8; ++c) {
            int e = lane + 64 * c;
            if (e < ET) {
                float vv = sAs[sSrcCsr[e]] + sAd[sDstCsr[e]];
                sECsr[e] = (vv > 0.0f) ? vv : 0.2f * vv;
            }
        }
        WSYNC();
        // ---- GAT1 C: fused softmax + aggregate + ReLU ----
        float o8r[8];
        if (lane < NN) {
            const int c0 = sOff[lane], c1 = sOff[lane + 1];
            float m = -1e30f;
            for (int c = c0; c < c1; ++c) m = fmaxf(m, sECsr[c]);
            float su = 0.0f;
            for (int c = c0; c < c1; ++c) su += expf(sECsr[c] - m);
            float inv = 1.0f / (su + 1e-16f);
            float acc[8];
#pragma unroll
            for (int o = 0; o < 8; ++o) acc[o] = sB1[o];
            for (int c = c0; c < c1; ++c) {
                float p = expf(sECsr[c] - m) * inv;
                const int s2 = sSrcCsr[c];
#pragma unroll
                for (int o = 0; o < 8; ++o) acc[o] += p * h8[s2 * 8 + o];
            }
#pragma unroll
            for (int o = 0; o < 8; ++o) o8r[o] = fmaxf(acc[o], 0.0f);
        }
        WSYNC();
        // ---- GAT2 A ----
        if (lane < NN) {
            float a = 0.0f, b = 0.0f;
#pragma unroll
            for (int o = 0; o < 5; ++o) {
                float acc = 0.0f;
#pragma unroll
                for (int k = 0; k < 8; ++k) acc += o8r[k] * sW2[o * 8 + k];
                sH5a[lane * 5 + o] = acc;
                a += acc * sAs2[o];
                b += acc * sAd2[o];
            }
            sAs[lane] = a; sAd[lane] = b;
        }
        WSYNC();
#pragma unroll
        for (int c = 0; c < 8; ++c) {
            int e = lane + 64 * c;
            if (e < ET) {
                float vv = sAs[sSrcCsr[e]] + sAd[sDstCsr[e]];
                sECsr[e] = (vv > 0.0f) ? vv : 0.2f * vv;
            }
        }
        WSYNC();
        float hr[5];
        if (lane < NN) {
            const int c0 = sOff[lane], c1 = sOff[lane + 1];
            float m = -1e30f;
            for (int c = c0; c < c1; ++c) m = fmaxf(m, sECsr[c]);
            float su = 0.0f;
            for (int c = c0; c < c1; ++c) su += expf(sECsr[c] - m);
            float inv = 1.0f / (su + 1e-16f);
#pragma unroll
            for (int o = 0; o < 5; ++o) hr[o] = sB2[o];
            for (int c = c0; c < c1; ++c) {
                float p = expf(sECsr[c] - m) * inv;
                const int s2 = sSrcCsr[c];
#pragma unroll
                for (int o = 0; o < 5; ++o) hr[o] += p * sH5a[s2 * 5 + o];
            }
        }
        WSYNC();
        // ---- MHA A: q regs, k -> sH5d, v -> sH5a ----
        float qr[5];
        if (lane < NN) {
#pragma unroll
            for (int o = 0; o < 5; ++o) {
                float q_ = sMib[o], k_ = sMib[o + 5], v_ = sMib[o + 10];
#pragma unroll
                for (int k = 0; k < 5; ++k) {
                    q_ += hr[k] * sMiw[o * 5 + k];
                    k_ += hr[k] * sMiw[(o + 5) * 5 + k];
                    v_ += hr[k] * sMiw[(o + 10) * 5 + k];
                }
                qr[o] = q_;
                sH5d[lane * 5 + o] = k_;
                sH5a[lane * 5 + o] = v_;
            }
        }
        WSYNC();
        // ---- MHA B: lane-local softmax + attn@v + out proj ----
        float hm[5];
        if (lane < NN) {
            float* srow = &sL[lane * LS];
            float m = -1e30f;
            for (int j = 0; j < NN; ++j) {
                float acc = 0.0f;
#pragma unroll
                for (int k = 0; k < 5; ++k) acc += qr[k] * sH5d[j * 5 + k];
                acc *= inv_sqrt5;
                srow[j] = acc;
                m = fmaxf(m, acc);
            }
            float su = 0.0f;
            for (int j = 0; j < NN; ++j) {
                float p = expf(srow[j] - m);
                srow[j] = p;
                su += p;
            }
            float inv = 1.0f / su;
            float a5[5] = {0.0f, 0.0f, 0.0f, 0.0f, 0.0f};
            for (int j = 0; j < NN; ++j) {
                float p = srow[j];
#pragma unroll
                for (int f = 0; f < 5; ++f) a5[f] += p * sH5a[j * 5 + f];
            }
#pragma unroll
            for (int f = 0; f < 5; ++f) a5[f] *= inv;
#pragma unroll
            for (int o = 0; o < 5; ++o) {
                float acc = sMob[o];
#pragma unroll
                for (int k = 0; k < 5; ++k) acc += a5[k] * sMow[o * 5 + k];
                hm[o] = acc;
            }
        }
        WSYNC();
        // ---- TC A ----
        float skip[5];
        if (lane < NN) {
#pragma unroll
            for (int o = 0; o < 5; ++o) {
                float q_ = sBq[o], k_ = sBk[o], v_ = sBv[o], s_ = sBsk[o];
#pragma unroll
                for (int k = 0; k < 5; ++k) {
                    q_ += hm[k] * sWq[o * 5 + k];
                    k_ += hm[k] * sWk[o * 5 + k];
                    v_ += hm[k] * sWv[o * 5 + k];
                    s_ += hm[k] * sWsk[o * 5 + k];
                }
                sH5b[lane * 5 + o] = q_;
                sH5d[lane * 5 + o] = k_;
                sH5a[lane * 5 + o] = v_;
                skip[o] = s_;
            }
        }
        WSYNC();
        // ---- TC B: edge scores ----
#pragma unroll
        for (int c = 0; c < 8; ++c) {
            int e = lane + 64 * c;
            if (e < ET) {
                const int s2 = sSrcCsr[e], d2 = sDstCsr[e];
                float acc = 0.0f;
#pragma unroll
                for (int k = 0; k < 5; ++k) acc += sH5b[d2 * 5 + k] * sH5d[s2 * 5 + k];
                sECsr[e] = acc * inv_sqrt5;
            }
        }
        WSYNC();
        // ---- TC C: fused softmax + aggregate + skip ----
        if (lane < NN) {
            const int c0 = sOff[lane], c1 = sOff[lane + 1];
            float m = -1e30f;
            for (int c = c0; c < c1; ++c) m = fmaxf(m, sECsr[c]);
            float su = 0.0f;
            for (int c = c0; c < c1; ++c) su += expf(sECsr[c] - m);
            float inv = 1.0f / (su + 1e-16f);
            float acc[5];
#pragma unroll
            for (int o = 0; o < 5; ++o) acc[o] = skip[o];
            for (int c = c0; c < c1; ++c) {
                float p = expf(sECsr[c] - m) * inv;
                const int s2 = sSrcCsr[c];
#pragma unroll
                for (int o = 0; o < 5; ++o) acc[o] += p * sH5a[s2 * 5 + o];
            }
#pragma unroll
            for (int o = 0; o < 5; ++o) sH5b[lane * 5 + o] = acc[o];
        }
        WSYNC();
        // ---- MLP1 (lane = hidden unit) ----
        {
            float wv5[5];
#pragma unroll
            for (int k = 0; k < 5; ++k) wv5[k] = sMw1[lane * 5 + k];
            const float bo = sMb1[lane];
            for (int i = 0; i < NN; ++i) {
                float acc = bo;
#pragma unroll
                for (int k = 0; k < 5; ++k) acc += sH5b[i * 5 + k] * wv5[k];
                sS[i * 64 + lane] = fmaxf(acc, 0.0f);
            }
        }
    }
    __syncthreads();

    // ---------------- MLP2 + fused critic (4 waves) ----------------
    float part = 0.0f;
    for (int t = tid; t < NN * NN; t += NTHR) {
        int i = t / NN, j = t - i * NN;
        const float4* sp4 = (const float4*)&sS[i * 64];
        const float4* wp4 = (const float4*)&sMw2[j * MS];
        float a0 = 0.0f, a1 = 0.0f, a2 = 0.0f, a3 = 0.0f;
        for (int k = 0; k < 16; ++k) {
            float4 a = sp4[k], b = wp4[k];
            a0 += a.x * b.x; a1 += a.y * b.y;
            a2 += a.z * b.z; a3 += a.w * b.w;
        }
        float acc = sMb2[j] + (a0 + a1) + (a2 + a3);
        out[t] = acc * sMask[j];
        part += acc * sCw[j];
    }
    for (int off = 32; off > 0; off >>= 1) part += __shfl_xor(part, off);
    if ((tid & 63) == 0) sred[tid >> 6] = part;
    __syncthreads();
    if (tid == 0)
        out[2500] = (sred[0] + sred[1] + sred[2] + sred[3]) * (1.0f / NN) + sCb0[0];
}

extern "C" void kernel_launch(void* const* d_in, const int* in_sizes, int n_in,
                              void* d_out, int out_size, void* d_ws, size_t ws_size,
                              hipStream_t stream) {
    (void)in_sizes; (void)n_in; (void)d_ws; (void)ws_size; (void)out_size;
    opn_kernel<<<1, NTHR, 0, stream>>>(
        (const float*)d_in[0], (const int*)d_in[1], (const float*)d_in[2],
        (const float*)d_in[3], (const float*)d_in[4], (const float*)d_in[5], (const float*)d_in[6],
        (const float*)d_in[7], (const float*)d_in[8], (const float*)d_in[9], (const float*)d_in[10],
        (const float*)d_in[11], (const float*)d_in[12], (const float*)d_in[13], (const float*)d_in[14],
        (const float*)d_in[15], (const float*)d_in[16], (const float*)d_in[17], (const float*)d_in[18],
        (const float*)d_in[19], (const float*)d_in[20], (const float*)d_in[21], (const float*)d_in[22],
        (const float*)d_in[23], (const float*)d_in[24], (const float*)d_in[25], (const float*)d_in[26],
        (const float*)d_in[27], (const float*)d_in[28],
        (float*)d_out);
}

// Round 12
// 73.591 us; speedup vs baseline: 4.7930x; 1.0457x over previous
//
#include <hip/hip_runtime.h>
#include <math.h>

#define NN 50
#define E2 400
#define ET 450
#define NTHR 256
#define KL 10            // Lanczos iterations
#define QS 52            // padded row stride (16B-aligned rows)
#define MS 68            // padded sMw2 row stride
#define LS 53            // MHA score-row stride (odd -> conflict-free)

// Intra-wave LDS handoff fence: drain LDS ops, forbid compiler reordering.
#define WSYNC() do { asm volatile("s_waitcnt lgkmcnt(0)" ::: "memory"); \
                     __builtin_amdgcn_sched_barrier(0); } while (0)

__global__ __launch_bounds__(NTHR, 1) void opn_kernel(
    const float* __restrict__ gx, const int* __restrict__ gedge,
    const float* __restrict__ gmask,
    const float* __restrict__ w1, const float* __restrict__ as1,
    const float* __restrict__ ad1, const float* __restrict__ b1,
    const float* __restrict__ w2, const float* __restrict__ as2,
    const float* __restrict__ ad2, const float* __restrict__ b2,
    const float* __restrict__ miw, const float* __restrict__ mib,
    const float* __restrict__ mow, const float* __restrict__ mob,
    const float* __restrict__ wq, const float* __restrict__ bq,
    const float* __restrict__ wk, const float* __restrict__ bk,
    const float* __restrict__ wv, const float* __restrict__ bv,
    const float* __restrict__ ws, const float* __restrict__ bs,
    const float* __restrict__ mw1, const float* __restrict__ mb1,
    const float* __restrict__ mw2, const float* __restrict__ mb2,
    const float* __restrict__ cw, const float* __restrict__ cb,
    float* __restrict__ out)
{
    const int tid = threadIdx.x;

    __shared__ float sM[NN * NN];                    // adjacency counts
    __shared__ alignas(16) float sS[3200];           // GAT1 h8 -> MLP hid64
    __shared__ alignas(16) float sL[2656];           // padded L (QS) -> MHA scores (LS)
    __shared__ alignas(16) float sQ2[(KL + 2) * QS]; // Lanczos vectors
    __shared__ float sAl_[KL + 2];
    __shared__ float sBe_[KL + 2];
    __shared__ float sY[KL + 2];
    __shared__ float sCp[KL + 2];
    __shared__ float sDp2[KL + 2];
    __shared__ int   sKeff;
    __shared__ float sH5a[NN * 5];   // h5 / v / tv
    __shared__ float sH5b[NN * 5];   // tq / tc-out
    __shared__ float sH5d[NN * 5];   // k / tk
    __shared__ int   sSrc[ET];
    __shared__ int   sDst[ET];
    __shared__ int   sSrcCsr[ET];
    __shared__ int   sDstCsr[ET];
    __shared__ float sECsr[ET];
    __shared__ float sAs[NN];
    __shared__ float sAd[NN];
    __shared__ float sdis[NN];
    __shared__ float sred[4];
    __shared__ int   sOff[NN + 1];
    __shared__ int   sCnt[NN];
    // staged weights (filled by waves 2-3 during Lanczos)
    __shared__ float sW1[40], sAs1[8], sAd1[8], sB1[8];
    __shared__ float sW2[40], sAs2[5], sAd2[5], sB2[5];
    __shared__ float sMiw[75], sMib[15], sMow[25], sMob[5];
    __shared__ float sWq[25], sBq[5], sWk[25], sBk[5];
    __shared__ float sWv[25], sBv[5], sWsk[25], sBsk[5];
    __shared__ float sMw1[320], sMb1[64];
    __shared__ alignas(16) float sMw2[NN * MS];
    __shared__ float sMb2[NN], sCw[NN], sCb0[1], sMask[NN], sGx[NN * 3];

    // ---------------- edges (with self loops) + adjacency + counts ----------------
    for (int t = tid; t < ET; t += NTHR) {
        int s, d;
        if (t < E2) { s = gedge[t]; d = gedge[E2 + t]; }
        else        { s = t - E2;   d = t - E2; }
        sSrc[t] = s; sDst[t] = d;
    }
    for (int t = tid; t < NN * NN; t += NTHR) sM[t] = 0.0f;
    for (int i = tid; i < NN; i += NTHR) sCnt[i] = 0;
    if (tid == 0) sKeff = KL;
    __syncthreads();
    for (int t = tid; t < E2; t += NTHR)
        atomicAdd(&sM[sSrc[t] * NN + sDst[t]], 1.0f);
    for (int e = tid; e < ET; e += NTHR)
        atomicAdd(&sCnt[sDst[e]], 1);
    __syncthreads();

    // ---------------- degree + u0 raw + sOff scan (merged phase) ----------------
    for (int i = tid; i < NN; i += NTHR) {
        float dsum = 0.0f;
        for (int j = 0; j < NN; ++j) dsum += sM[i * NN + j];
        sdis[i] = (dsum > 0.0f) ? (1.0f / sqrtf(fmaxf(dsum, 1e-12f))) : 0.0f;
        sQ2[i] = sqrtf(dsum);
    }
    if (tid == 0) {
        int acc = 0;
        for (int i = 0; i < NN; ++i) { sOff[i] = acc; acc += sCnt[i]; }
        sOff[NN] = acc;
    }
    __syncthreads();
    for (int t = tid; t < NN * QS; t += NTHR) {
        int i = t / QS, k = t - i * QS;
        sL[t] = (k < NN)
              ? (((i == k) ? 1.0f : 0.0f) - sdis[i] * sM[i * NN + k] * sdis[k])
              : 0.0f;
    }
    __syncthreads();

    // ==== wave0: 3-term Lanczos | wave1: CSR + ei out | waves2-3: staging ====
    if (tid < 64) {
        const int lane = tid;
        float q0r, qprev = 0.0f, qcur;
        {   // normalize u0; deterministic start q1 orthogonal to u0
            float q0 = (lane < NN) ? sQ2[lane] : 0.0f;
            float nn = q0 * q0;
            for (int off = 32; off > 0; off >>= 1) nn += __shfl_xor(nn, off);
            q0 *= rsqrtf(nn);
            unsigned u = (unsigned)lane * 2654435761u + 12345u;
            u ^= u >> 13; u *= 2246822519u; u ^= u >> 11;
            float q1 = (lane < NN) ? ((float)(u & 0xFFFF) * (1.0f / 65536.0f) - 0.5f) : 0.0f;
            for (int pass = 0; pass < 2; ++pass) {
                float d = q0 * q1;
                for (int off = 32; off > 0; off >>= 1) d += __shfl_xor(d, off);
                q1 -= d * q0;
            }
            float n1 = q1 * q1;
            for (int off = 32; off > 0; off >>= 1) n1 += __shfl_xor(n1, off);
            q1 *= rsqrtf(n1);
            q0r = q0; qcur = q1;
            if (lane < NN) { sQ2[lane] = q0; sQ2[QS + lane] = q1; }
            WSYNC();
        }
        for (int j = 1; j <= KL; ++j) {
            const float* qp = &sQ2[j * QS];
            const float4* qp4 = (const float4*)qp;
            float w = 0.0f;
            if (lane < NN) {
                const float* rp = &sL[lane * QS];
                const float4* rp4 = (const float4*)rp;
                float a0 = 0.0f, a1 = 0.0f, a2 = 0.0f, a3 = 0.0f;
                for (int k = 0; k < 12; ++k) {
                    float4 r = rp4[k], q = qp4[k];
                    a0 += r.x * q.x; a1 += r.y * q.y;
                    a2 += r.z * q.z; a3 += r.w * q.w;
                }
                a0 += rp[48] * qp[48];
                a1 += rp[49] * qp[49];
                w = 2.0f * qcur - (a0 + a1 + a2 + a3);
            }
            // register-only reorth: q0 (deflation) + q_{j-1} + q_j
            float c0 = q0r * w, c1 = qprev * w, ca = qcur * w;
#pragma unroll
            for (int off = 32; off > 0; off >>= 1) {
                c0 += __shfl_xor(c0, off);
                c1 += __shfl_xor(c1, off);
                ca += __shfl_xor(ca, off);
            }
            w -= c0 * q0r + c1 * qprev + ca * qcur;
            float nn2 = w * w;
#pragma unroll
            for (int off = 32; off > 0; off >>= 1) nn2 += __shfl_xor(nn2, off);
            float beta = sqrtf(nn2);
            if (lane == 0) { sAl_[j] = ca; sBe_[j] = beta; }
            if (j < KL) {
                if (beta > 1e-10f) {
                    qprev = qcur;
                    qcur = w * (1.0f / beta);
                    if (lane < NN) sQ2[(j + 1) * QS + lane] = qcur;
                    WSYNC();
                } else {
                    if (lane == 0) sKeff = j;
                    break;
                }
            }
        }
        WSYNC();
    } else if (tid < 128) {
        const int d = tid - 64;
        if (d < NN) {                             // CSR scatter (deterministic)
            int pos = sOff[d];
            for (int e = 0; e < ET; ++e)
                if (sDst[e] == d) { sSrcCsr[pos] = sSrc[e]; sDstCsr[pos] = d; pos++; }
        }
        for (int t = tid - 64; t < 2 * ET; t += 64) {
            int val = (t < ET) ? sSrc[t] : sDst[t - ET];
            out[2751 + t] = (float)val;
        }
    } else {
        // ---- staging: issue ALL loads (clamped, unconditional), then store ----
        const int t0 = tid - 128;
        float vW1  = w1 [t0 < 40 ? t0 : 39];
        float vAs1 = as1[t0 < 8  ? t0 : 7];
        float vAd1 = ad1[t0 < 8  ? t0 : 7];
        float vB1  = b1 [t0 < 8  ? t0 : 7];
        float vW2  = w2 [t0 < 40 ? t0 : 39];
        float vAs2 = as2[t0 < 5  ? t0 : 4];
        float vAd2 = ad2[t0 < 5  ? t0 : 4];
        float vB2  = b2 [t0 < 5  ? t0 : 4];
        float vMiw = miw[t0 < 75 ? t0 : 74];
        float vMib = mib[t0 < 15 ? t0 : 14];
        float vMow = mow[t0 < 25 ? t0 : 24];
        float vMob = mob[t0 < 5  ? t0 : 4];
        float vWq  = wq [t0 < 25 ? t0 : 24];
        float vBq  = bq [t0 < 5  ? t0 : 4];
        float vWk  = wk [t0 < 25 ? t0 : 24];
        float vBk  = bk [t0 < 5  ? t0 : 4];
        float vWv  = wv [t0 < 25 ? t0 : 24];
        float vBv  = bv [t0 < 5  ? t0 : 4];
        float vWs  = ws [t0 < 25 ? t0 : 24];
        float vBs  = bs [t0 < 5  ? t0 : 4];
        float vMb1 = mb1[t0 < 64 ? t0 : 63];
        float vMb2 = mb2[t0 < NN ? t0 : NN - 1];
        float vCw  = cw [t0 < NN ? t0 : NN - 1];
        float vCb  = cb[0];
        float vMsk = gmask[t0 < NN ? t0 : NN - 1];
        float vGxa = gx[t0 < 150 ? t0 : 149];
        int   gb   = t0 + 128;
        float vGxb = gx[gb < 150 ? gb : 149];
        // mw1: gathered 5 used columns of each of 64 rows (320 scalars)
        int ta = t0, tb2 = t0 + 128, tc = (t0 + 256 < 320) ? t0 + 256 : 319;
        float vM1a = mw1[(ta  / 5) * 250 + (ta  % 5)];
        float vM1b = mw1[(tb2 / 5) * 250 + (tb2 % 5)];
        float vM1c = mw1[(tc  / 5) * 250 + (tc  % 5)];
        // mw2: 800 float4 units
        const float4* m2 = (const float4*)mw2;
        float4 v2[7];
#pragma unroll
        for (int u = 0; u < 7; ++u) {
            int t = t0 + u * 128;
            v2[u] = m2[t < 800 ? t : 799];
        }
        // ---- stores (guarded) ----
        if (t0 < 40) sW1[t0]  = vW1;
        if (t0 < 8)  { sAs1[t0] = vAs1; sAd1[t0] = vAd1; sB1[t0] = vB1; }
        if (t0 < 40) sW2[t0]  = vW2;
        if (t0 < 5)  { sAs2[t0] = vAs2; sAd2[t0] = vAd2; sB2[t0] = vB2; }
        if (t0 < 75) sMiw[t0] = vMiw;
        if (t0 < 15) sMib[t0] = vMib;
        if (t0 < 25) { sMow[t0] = vMow; sWq[t0] = vWq; sWk[t0] = vWk;
                       sWv[t0] = vWv;  sWsk[t0] = vWs; }
        if (t0 < 5)  { sMob[t0] = vMob; sBq[t0] = vBq; sBk[t0] = vBk;
                       sBv[t0] = vBv;  sBsk[t0] = vBs; }
        if (t0 < 64) sMb1[t0] = vMb1;
        if (t0 < NN) { sMb2[t0] = vMb2; sCw[t0] = vCw; sMask[t0] = vMsk; }
        if (t0 == 0) sCb0[0] = vCb;
        if (t0 < 150) sGx[t0] = vGxa;
        if (gb < 150) sGx[gb] = vGxb;
        sMw1[ta]  = vM1a;
        sMw1[tb2] = vM1b;
        if (t0 + 256 < 320) sMw1[t0 + 256] = vM1c;
#pragma unroll
        for (int u = 0; u < 7; ++u) {
            int t = t0 + u * 128;
            if (t < 800) {
                int o = t >> 4, k4 = t & 15;
                *(float4*)&sMw2[o * MS + k4 * 4] = v2[u];
            }
        }
    }
    __syncthreads();   // staged weights + CSR visible to wave 0

    const float inv_sqrt5 = 0.4472135954999579f;

    // ==== wave 0: extraction + full GNN tail (zero barriers inside) ====
    if (tid < 64) {
        const int lane = tid;
        const int keff = sKeff;
        // ---- bisection for top Ritz value (lo/hi lane-uniform) ----
        float lo = 1e30f, hi = -1e30f;
        for (int m = 1; m <= keff; ++m) {
            float r = ((m > 1) ? fabsf(sBe_[m - 1]) : 0.0f)
                    + ((m < keff) ? fabsf(sBe_[m]) : 0.0f);
            lo = fminf(lo, sAl_[m] - r);
            hi = fmaxf(hi, sAl_[m] + r);
        }
        for (int round = 0; round < 4; ++round) {
            float h = (hi - lo) * (1.0f / 65.0f);
            float x = lo + (float)(lane + 1) * h;
            int cnt = 0;
            float d = sAl_[1] - x;
            if (d < 0.0f) cnt++;
            for (int m = 2; m <= keff; ++m) {
                float b = sBe_[m - 1];
                float dd = (fabsf(d) < 1e-20f) ? ((d >= 0.0f) ? 1e-20f : -1e-20f) : d;
                d = sAl_[m] - x - b * b / dd;
                if (d < 0.0f) cnt++;
            }
            unsigned long long msk = __ballot(cnt >= keff);
            int f = (msk == 0ULL) ? 64 : (__ffsll((unsigned long long)msk) - 1);
            float nlo = (f == 0) ? lo : (lo + (float)f * h);
            float nhi = (f == 64) ? hi : (lo + (float)(f + 1) * h);
            lo = nlo; hi = nhi;
        }
        const float th = 0.5f * (lo + hi);
        if (lane == 0) {
            if (keff == 1) {
                sY[1] = 1.0f;
            } else {
                float inv0 = rsqrtf((float)keff);
                for (int m = 1; m <= keff; ++m) sY[m] = inv0;
                float d1 = sAl_[1] - th;
                if (fabsf(d1) < 1e-10f) d1 = (d1 >= 0.0f) ? 1e-10f : -1e-10f;
                sCp[1] = sBe_[1] / d1;
                sDp2[1] = sY[1] / d1;
                for (int m = 2; m <= keff; ++m) {
                    float den = sAl_[m] - th - sBe_[m - 1] * sCp[m - 1];
                    if (fabsf(den) < 1e-10f) den = (den >= 0.0f) ? 1e-10f : -1e-10f;
                    if (m < keff) sCp[m] = sBe_[m] / den;
                    sDp2[m] = (sY[m] - sBe_[m - 1] * sDp2[m - 1]) / den;
                }
                sY[keff] = sDp2[keff];
                for (int m = keff - 1; m >= 1; --m)
                    sY[m] = sDp2[m] - sCp[m] * sY[m + 1];
                float nn = 0.0f;
                for (int m = 1; m <= keff; ++m) nn += sY[m] * sY[m];
                float sc = rsqrtf(nn);
                for (int m = 1; m <= keff; ++m) sY[m] *= sc;
            }
        }
        WSYNC();
        // ---- Fiedler = Q y, normalize, canonical sign ----
        float v = 0.0f;
        if (lane < NN)
            for (int m = 1; m <= keff; ++m) v += sY[m] * sQ2[m * QS + lane];
        {
            float nn = v * v;
            for (int off = 32; off > 0; off >>= 1) nn += __shfl_xor(nn, off);
            float av = fabsf(v);
            for (int off = 32; off > 0; off >>= 1) av = fmaxf(av, __shfl_xor(av, off));
            unsigned long long msk = __ballot((fabsf(v) == av) && (lane < NN));
            int fl = __ffsll((unsigned long long)msk) - 1;
            float sv = __shfl(v, fl);
            v *= ((sv >= 0.0f) ? 1.0f : -1.0f) * rsqrtf(nn);
        }
        // ---- x_combined ----
        float xr[5];
        if (lane < NN) {
            xr[0] = sGx[lane * 3 + 0];
            xr[1] = sGx[lane * 3 + 1];
            xr[2] = sGx[lane * 3 + 2];
            xr[3] = sQ2[lane];
            xr[4] = v;
#pragma unroll
            for (int k = 0; k < 5; ++k) out[2501 + lane * 5 + k] = xr[k];
        }

        float* h8 = sS;                       // 50x8
        // ---- GAT1 A ----
        float h8r[8];
        if (lane < NN) {
            float a = 0.0f, b = 0.0f;
#pragma unroll
            for (int o = 0; o < 8; ++o) {
                float acc = 0.0f;
#pragma unroll
                for (int k = 0; k < 5; ++k) acc += xr[k] * sW1[o * 5 + k];
                h8r[o] = acc;
                h8[lane * 8 + o] = acc;
                a += acc * sAs1[o];
                b += acc * sAd1[o];
            }
            sAs[lane] = a; sAd[lane] = b;
        }
        WSYNC();
        // ---- GAT1 B ----
#pragma unroll
        for (int c = 0; c < 8; ++c) {
            int e = lane + 64 * c;
            if (e < ET) {
                float vv = sAs[sSrcCsr[e]] + sAd[sDstCsr[e]];
                sECsr[e] = (vv > 0.0f) ? vv : 0.2f * vv;
            }
        }
        WSYNC();
        // ---- GAT1 C: fused softmax (exp stored once) + aggregate + ReLU ----
        float o8r[8];
        if (lane < NN) {
            const int c0 = sOff[lane], c1 = sOff[lane + 1];
            float m = -1e30f;
            for (int c = c0; c < c1; ++c) m = fmaxf(m, sECsr[c]);
            float su = 0.0f;
            for (int c = c0; c < c1; ++c) {
                float p = __expf(sECsr[c] - m);
                sECsr[c] = p;
                su += p;
            }
            float inv = 1.0f / (su + 1e-16f);
            float acc[8];
#pragma unroll
            for (int o = 0; o < 8; ++o) acc[o] = sB1[o];
            for (int c = c0; c < c1; ++c) {
                float p = sECsr[c] * inv;
                const int s2 = sSrcCsr[c];
#pragma unroll
                for (int o = 0; o < 8; ++o) acc[o] += p * h8[s2 * 8 + o];
            }
#pragma unroll
            for (int o = 0; o < 8; ++o) o8r[o] = fmaxf(acc[o], 0.0f);
        }
        WSYNC();
        // ---- GAT2 A ----
        if (lane < NN) {
            float a = 0.0f, b = 0.0f;
#pragma unroll
            for (int o = 0; o < 5; ++o) {
                float acc = 0.0f;
#pragma unroll
                for (int k = 0; k < 8; ++k) acc += o8r[k] * sW2[o * 8 + k];
                sH5a[lane * 5 + o] = acc;
                a += acc * sAs2[o];
                b += acc * sAd2[o];
            }
            sAs[lane] = a; sAd[lane] = b;
        }
        WSYNC();
#pragma unroll
        for (int c = 0; c < 8; ++c) {
            int e = lane + 64 * c;
            if (e < ET) {
                float vv = sAs[sSrcCsr[e]] + sAd[sDstCsr[e]];
                sECsr[e] = (vv > 0.0f) ? vv : 0.2f * vv;
            }
        }
        WSYNC();
        float hr[5];
        if (lane < NN) {
            const int c0 = sOff[lane], c1 = sOff[lane + 1];
            float m = -1e30f;
            for (int c = c0; c < c1; ++c) m = fmaxf(m, sECsr[c]);
            float su = 0.0f;
            for (int c = c0; c < c1; ++c) {
                float p = __expf(sECsr[c] - m);
                sECsr[c] = p;
                su += p;
            }
            float inv = 1.0f / (su + 1e-16f);
#pragma unroll
            for (int o = 0; o < 5; ++o) hr[o] = sB2[o];
            for (int c = c0; c < c1; ++c) {
                float p = sECsr[c] * inv;
                const int s2 = sSrcCsr[c];
#pragma unroll
                for (int o = 0; o < 5; ++o) hr[o] += p * sH5a[s2 * 5 + o];
            }
        }
        WSYNC();
        // ---- MHA A ----
        float qr[5];
        if (lane < NN) {
#pragma unroll
            for (int o = 0; o < 5; ++o) {
                float q_ = sMib[o], k_ = sMib[o + 5], v_ = sMib[o + 10];
#pragma unroll
                for (int k = 0; k < 5; ++k) {
                    q_ += hr[k] * sMiw[o * 5 + k];
                    k_ += hr[k] * sMiw[(o + 5) * 5 + k];
                    v_ += hr[k] * sMiw[(o + 10) * 5 + k];
                }
                qr[o] = q_;
                sH5d[lane * 5 + o] = k_;
                sH5a[lane * 5 + o] = v_;
            }
        }
        WSYNC();
        // ---- MHA B ----
        float hm[5];
        if (lane < NN) {
            float* srow = &sL[lane * LS];
            float m = -1e30f;
            for (int j = 0; j < NN; ++j) {
                float acc = 0.0f;
#pragma unroll
                for (int k = 0; k < 5; ++k) acc += qr[k] * sH5d[j * 5 + k];
                acc *= inv_sqrt5;
                srow[j] = acc;
                m = fmaxf(m, acc);
            }
            float su = 0.0f;
            for (int j = 0; j < NN; ++j) {
                float p = __expf(srow[j] - m);
                srow[j] = p;
                su += p;
            }
            float inv = 1.0f / su;
            float a5[5] = {0.0f, 0.0f, 0.0f, 0.0f, 0.0f};
            for (int j = 0; j < NN; ++j) {
                float p = srow[j];
#pragma unroll
                for (int f = 0; f < 5; ++f) a5[f] += p * sH5a[j * 5 + f];
            }
#pragma unroll
            for (int f = 0; f < 5; ++f) a5[f] *= inv;
#pragma unroll
            for (int o = 0; o < 5; ++o) {
                float acc = sMob[o];
#pragma unroll
                for (int k = 0; k < 5; ++k) acc += a5[k] * sMow[o * 5 + k];
                hm[o] = acc;
            }
        }
        WSYNC();
        // ---- TC A ----
        float skip[5];
        if (lane < NN) {
#pragma unroll
            for (int o = 0; o < 5; ++o) {
                float q_ = sBq[o], k_ = sBk[o], v_ = sBv[o], s_ = sBsk[o];
#pragma unroll
                for (int k = 0; k < 5; ++k) {
                    q_ += hm[k] * sWq[o * 5 + k];
                    k_ += hm[k] * sWk[o * 5 + k];
                    v_ += hm[k] * sWv[o * 5 + k];
                    s_ += hm[k] * sWsk[o * 5 + k];
                }
                sH5b[lane * 5 + o] = q_;
                sH5d[lane * 5 + o] = k_;
                sH5a[lane * 5 + o] = v_;
                skip[o] = s_;
            }
        }
        WSYNC();
        // ---- TC B ----
#pragma unroll
        for (int c = 0; c < 8; ++c) {
            int e = lane + 64 * c;
            if (e < ET) {
                const int s2 = sSrcCsr[e], d2 = sDstCsr[e];
                float acc = 0.0f;
#pragma unroll
                for (int k = 0; k < 5; ++k) acc += sH5b[d2 * 5 + k] * sH5d[s2 * 5 + k];
                sECsr[e] = acc * inv_sqrt5;
            }
        }
        WSYNC();
        // ---- TC C ----
        if (lane < NN) {
            const int c0 = sOff[lane], c1 = sOff[lane + 1];
            float m = -1e30f;
            for (int c = c0; c < c1; ++c) m = fmaxf(m, sECsr[c]);
            float su = 0.0f;
            for (int c = c0; c < c1; ++c) {
                float p = __expf(sECsr[c] - m);
                sECsr[c] = p;
                su += p;
            }
            float inv = 1.0f / (su + 1e-16f);
            float acc[5];
#pragma unroll
            for (int o = 0; o < 5; ++o) acc[o] = skip[o];
            for (int c = c0; c < c1; ++c) {
                float p = sECsr[c] * inv;
                const int s2 = sSrcCsr[c];
#pragma unroll
                for (int o = 0; o < 5; ++o) acc[o] += p * sH5a[s2 * 5 + o];
            }
#pragma unroll
            for (int o = 0; o < 5; ++o) sH5b[lane * 5 + o] = acc[o];
        }
        WSYNC();
        // ---- MLP1 (lane = hidden unit) ----
        {
            float wv5[5];
#pragma unroll
            for (int k = 0; k < 5; ++k) wv5[k] = sMw1[lane * 5 + k];
            const float bo = sMb1[lane];
            for (int i = 0; i < NN; ++i) {
                float acc = bo;
#pragma unroll
                for (int k = 0; k < 5; ++k) acc += sH5b[i * 5 + k] * wv5[k];
                sS[i * 64 + lane] = fmaxf(acc, 0.0f);
            }
        }
    }
    __syncthreads();

    // ---------------- MLP2 + fused critic (4 waves) ----------------
    float part = 0.0f;
    for (int t = tid; t < NN * NN; t += NTHR) {
        int i = t / NN, j = t - i * NN;
        const float4* sp4 = (const float4*)&sS[i * 64];
        const float4* wp4 = (const float4*)&sMw2[j * MS];
        float a0 = 0.0f, a1 = 0.0f, a2 = 0.0f, a3 = 0.0f;
        for (int k = 0; k < 16; ++k) {
            float4 a = sp4[k], b = wp4[k];
            a0 += a.x * b.x; a1 += a.y * b.y;
            a2 += a.z * b.z; a3 += a.w * b.w;
        }
        float acc = sMb2[j] + (a0 + a1) + (a2 + a3);
        out[t] = acc * sMask[j];
        part += acc * sCw[j];
    }
    for (int off = 32; off > 0; off >>= 1) part += __shfl_xor(part, off);
    if ((tid & 63) == 0) sred[tid >> 6] = part;
    __syncthreads();
    if (tid == 0)
        out[2500] = (sred[0] + sred[1] + sred[2] + sred[3]) * (1.0f / NN) + sCb0[0];
}

extern "C" void kernel_launch(void* const* d_in, const int* in_sizes, int n_in,
                              void* d_out, int out_size, void* d_ws, size_t ws_size,
                              hipStream_t stream) {
    (void)in_sizes; (void)n_in; (void)d_ws; (void)ws_size; (void)out_size;
    opn_kernel<<<1, NTHR, 0, stream>>>(
        (const float*)d_in[0], (const int*)d_in[1], (const float*)d_in[2],
        (const float*)d_in[3], (const float*)d_in[4], (const float*)d_in[5], (const float*)d_in[6],
        (const float*)d_in[7], (const float*)d_in[8], (const float*)d_in[9], (const float*)d_in[10],
        (const float*)d_in[11], (const float*)d_in[12], (const float*)d_in[13], (const float*)d_in[14],
        (const float*)d_in[15], (const float*)d_in[16], (const float*)d_in[17], (const float*)d_in[18],
        (const float*)d_in[19], (const float*)d_in[20], (const float*)d_in[21], (const float*)d_in[22],
        (const float*)d_in[23], (const float*)d_in[24], (const float*)d_in[25], (const float*)d_in[26],
        (const float*)d_in[27], (const float*)d_in[28],
        (float*)d_out);
}

// Round 13
// 61.927 us; speedup vs baseline: 5.6957x; 1.1884x over previous
//
#include <hip/hip_runtime.h>
#include <math.h>

#define NN 50
#define E2 400
#define ET 450
#define NTHR 256
#define KL 8             // Lanczos iterations
#define QS 52            // padded row stride (16B-aligned rows)
#define MS 68            // padded sMw2 row stride

// Intra-wave LDS handoff fence: drain LDS ops, forbid compiler reordering.
#define WSYNC() do { asm volatile("s_waitcnt lgkmcnt(0)" ::: "memory"); \
                     __builtin_amdgcn_sched_barrier(0); } while (0)

__global__ __launch_bounds__(NTHR, 1) void opn_kernel(
    const float* __restrict__ gx, const int* __restrict__ gedge,
    const float* __restrict__ gmask,
    const float* __restrict__ w1, const float* __restrict__ as1,
    const float* __restrict__ ad1, const float* __restrict__ b1,
    const float* __restrict__ w2, const float* __restrict__ as2,
    const float* __restrict__ ad2, const float* __restrict__ b2,
    const float* __restrict__ miw, const float* __restrict__ mib,
    const float* __restrict__ mow, const float* __restrict__ mob,
    const float* __restrict__ wq, const float* __restrict__ bq,
    const float* __restrict__ wk, const float* __restrict__ bk,
    const float* __restrict__ wv, const float* __restrict__ bv,
    const float* __restrict__ ws, const float* __restrict__ bs,
    const float* __restrict__ mw1, const float* __restrict__ mb1,
    const float* __restrict__ mw2, const float* __restrict__ mb2,
    const float* __restrict__ cw, const float* __restrict__ cb,
    float* __restrict__ out)
{
    const int tid = threadIdx.x;

    __shared__ float sM[NN * NN];                    // adjacency counts
    __shared__ alignas(16) float sS[3200];           // GAT1 h8 -> MLP hid64
    __shared__ alignas(16) float sL[NN * QS];        // padded Laplacian
    __shared__ alignas(16) float sQ2[(KL + 2) * QS]; // Lanczos vectors
    __shared__ float sAl_[KL + 2];
    __shared__ float sBe_[KL + 2];
    __shared__ float sY[KL + 2];
    __shared__ float sCp[KL + 2];
    __shared__ float sDp2[KL + 2];
    __shared__ int   sKeff;
    __shared__ float sB5h[NN * 5];   // GAT2 h5
    __shared__ float sKv[NN * 5];    // MHA k
    __shared__ float sVv[NN * 5];    // MHA v
    __shared__ float sTk[NN * 5];    // TC k
    __shared__ float sTv[NN * 5];    // TC v
    __shared__ float sTo[NN * 5];    // TC out
    __shared__ int   sSrc[ET];
    __shared__ int   sDst[ET];
    __shared__ int   sSrcCsr[ET];
    __shared__ float sAs[NN];        // GAT1 src coeffs
    __shared__ float sAsB[NN];       // GAT2 src coeffs
    __shared__ float sdis[NN];
    __shared__ float sred[4];
    __shared__ int   sOff[NN + 1];
    // staged weights (filled by waves 2-3)
    __shared__ float sW1[40], sAs1[8], sAd1[8], sB1[8];
    __shared__ float sW2[40], sAs2[5], sAd2[5], sB2[5];
    __shared__ float sMiw[75], sMib[15], sMow[25], sMob[5];
    __shared__ float sWq[25], sBq[5], sWk[25], sBk[5];
    __shared__ float sWv[25], sBv[5], sWsk[25], sBsk[5];
    __shared__ float sMw1[320], sMb1[64];
    __shared__ alignas(16) float sMw2[NN * MS];
    __shared__ float sMb2[NN], sCw[NN], sCb0[1], sMask[NN];

    const float inv_sqrt5 = 0.4472135954999579f;
    float xr0 = 0, xr1 = 0, xr2 = 0, xr3 = 0, xr4 = 0;   // x_combined row (wave 0)

    // ======== parallel section: zero shared barriers ========
    if (tid < 64) {
        // -------- wave 0: adjacency -> Laplacian -> Lanczos -> extraction ----
        const int lane = tid;
        {   // early global loads (latency hidden under zeroing)
            int gi = (lane < NN) ? lane : NN - 1;
            xr0 = gx[gi * 3 + 0]; xr1 = gx[gi * 3 + 1]; xr2 = gx[gi * 3 + 2];
        }
        int es[7], ed[7];
#pragma unroll
        for (int u = 0; u < 7; ++u) {
            int e = lane + u * 64;
            int ec = (e < E2) ? e : E2 - 1;
            es[u] = gedge[ec]; ed[u] = gedge[E2 + ec];
        }
        if (lane == 0) sKeff = KL;
        for (int t = lane; t < NN * NN; t += 64) sM[t] = 0.0f;
        WSYNC();
#pragma unroll
        for (int u = 0; u < 7; ++u) {
            int e = lane + u * 64;
            if (e < E2) atomicAdd(&sM[es[u] * NN + ed[u]], 1.0f);
        }
        WSYNC();
        float dsum = 0.0f;
        if (lane < NN) {
            const float* rp = &sM[lane * NN];
            for (int k = 0; k < NN; ++k) dsum += rp[k];
        }
        float disl = (dsum > 0.0f) ? (1.0f / sqrtf(fmaxf(dsum, 1e-12f))) : 0.0f;
        if (lane < NN) sdis[lane] = disl;
        WSYNC();
        for (int t = lane; t < NN * QS; t += 64) {
            int i = t / QS, k = t - i * QS;
            sL[t] = (k < NN)
                  ? (((i == k) ? 1.0f : 0.0f) - sdis[i] * sM[i * NN + k] * sdis[k])
                  : 0.0f;
        }
        // u0 normalize + deterministic q1
        float q0r, qprev = 0.0f, qcur;
        {
            float q0 = (lane < NN) ? sqrtf(dsum) : 0.0f;
            float nn = q0 * q0;
            for (int off = 32; off > 0; off >>= 1) nn += __shfl_xor(nn, off);
            q0 *= rsqrtf(nn);
            unsigned u = (unsigned)lane * 2654435761u + 12345u;
            u ^= u >> 13; u *= 2246822519u; u ^= u >> 11;
            float q1 = (lane < NN) ? ((float)(u & 0xFFFF) * (1.0f / 65536.0f) - 0.5f) : 0.0f;
            for (int pass = 0; pass < 2; ++pass) {
                float d = q0 * q1;
                for (int off = 32; off > 0; off >>= 1) d += __shfl_xor(d, off);
                q1 -= d * q0;
            }
            float n1 = q1 * q1;
            for (int off = 32; off > 0; off >>= 1) n1 += __shfl_xor(n1, off);
            q1 *= rsqrtf(n1);
            q0r = q0; qcur = q1;
            if (lane < NN) { sQ2[lane] = q0; sQ2[QS + lane] = q1; }
            WSYNC();          // sL + q rows visible before matvec
        }
        // -------- 3-term Lanczos on B = 2I - L --------
        for (int j = 1; j <= KL; ++j) {
            const float* qp = &sQ2[j * QS];
            const float4* qp4 = (const float4*)qp;
            float w = 0.0f;
            if (lane < NN) {
                const float* rp = &sL[lane * QS];
                const float4* rp4 = (const float4*)rp;
                float a0 = 0.0f, a1 = 0.0f, a2 = 0.0f, a3 = 0.0f;
                for (int k = 0; k < 12; ++k) {
                    float4 r = rp4[k], q = qp4[k];
                    a0 += r.x * q.x; a1 += r.y * q.y;
                    a2 += r.z * q.z; a3 += r.w * q.w;
                }
                a0 += rp[48] * qp[48];
                a1 += rp[49] * qp[49];
                w = 2.0f * qcur - (a0 + a1 + a2 + a3);
            }
            float c0 = q0r * w, c1 = qprev * w, ca = qcur * w;
#pragma unroll
            for (int off = 32; off > 0; off >>= 1) {
                c0 += __shfl_xor(c0, off);
                c1 += __shfl_xor(c1, off);
                ca += __shfl_xor(ca, off);
            }
            w -= c0 * q0r + c1 * qprev + ca * qcur;
            float nn2 = w * w;
#pragma unroll
            for (int off = 32; off > 0; off >>= 1) nn2 += __shfl_xor(nn2, off);
            float beta = sqrtf(nn2);
            if (lane == 0) { sAl_[j] = ca; sBe_[j] = beta; }
            if (j < KL) {
                if (beta > 1e-10f) {
                    qprev = qcur;
                    qcur = w * (1.0f / beta);
                    if (lane < NN) sQ2[(j + 1) * QS + lane] = qcur;
                    WSYNC();
                } else {
                    if (lane == 0) sKeff = j;
                    break;
                }
            }
        }
        WSYNC();
        // -------- extraction: bisection + Thomas + Fiedler --------
        const int keff = sKeff;
        float lo = 1e30f, hi = -1e30f;
        for (int m = 1; m <= keff; ++m) {
            float r = ((m > 1) ? fabsf(sBe_[m - 1]) : 0.0f)
                    + ((m < keff) ? fabsf(sBe_[m]) : 0.0f);
            lo = fminf(lo, sAl_[m] - r);
            hi = fmaxf(hi, sAl_[m] + r);
        }
        for (int round = 0; round < 4; ++round) {
            float h = (hi - lo) * (1.0f / 65.0f);
            float x = lo + (float)(lane + 1) * h;
            int cnt = 0;
            float d = sAl_[1] - x;
            if (d < 0.0f) cnt++;
            for (int m = 2; m <= keff; ++m) {
                float b = sBe_[m - 1];
                float dd = (fabsf(d) < 1e-20f) ? ((d >= 0.0f) ? 1e-20f : -1e-20f) : d;
                d = sAl_[m] - x - b * b / dd;
                if (d < 0.0f) cnt++;
            }
            unsigned long long msk = __ballot(cnt >= keff);
            int f = (msk == 0ULL) ? 64 : (__ffsll((unsigned long long)msk) - 1);
            float nlo = (f == 0) ? lo : (lo + (float)f * h);
            float nhi = (f == 64) ? hi : (lo + (float)(f + 1) * h);
            lo = nlo; hi = nhi;
        }
        const float th = 0.5f * (lo + hi);
        if (lane == 0) {
            if (keff == 1) {
                sY[1] = 1.0f;
            } else {
                float inv0 = rsqrtf((float)keff);
                for (int m = 1; m <= keff; ++m) sY[m] = inv0;
                float d1 = sAl_[1] - th;
                if (fabsf(d1) < 1e-10f) d1 = (d1 >= 0.0f) ? 1e-10f : -1e-10f;
                sCp[1] = sBe_[1] / d1;
                sDp2[1] = sY[1] / d1;
                for (int m = 2; m <= keff; ++m) {
                    float den = sAl_[m] - th - sBe_[m - 1] * sCp[m - 1];
                    if (fabsf(den) < 1e-10f) den = (den >= 0.0f) ? 1e-10f : -1e-10f;
                    if (m < keff) sCp[m] = sBe_[m] / den;
                    sDp2[m] = (sY[m] - sBe_[m - 1] * sDp2[m - 1]) / den;
                }
                sY[keff] = sDp2[keff];
                for (int m = keff - 1; m >= 1; --m)
                    sY[m] = sDp2[m] - sCp[m] * sY[m + 1];
                float nn = 0.0f;
                for (int m = 1; m <= keff; ++m) nn += sY[m] * sY[m];
                float sc = rsqrtf(nn);
                for (int m = 1; m <= keff; ++m) sY[m] *= sc;
            }
        }
        WSYNC();
        float v = 0.0f;
        if (lane < NN)
            for (int m = 1; m <= keff; ++m) v += sY[m] * sQ2[m * QS + lane];
        {
            float nn = v * v;
            for (int off = 32; off > 0; off >>= 1) nn += __shfl_xor(nn, off);
            float av = fabsf(v);
            for (int off = 32; off > 0; off >>= 1) av = fmaxf(av, __shfl_xor(av, off));
            unsigned long long msk = __ballot((fabsf(v) == av) && (lane < NN));
            int fl = __ffsll((unsigned long long)msk) - 1;
            float sv = __shfl(v, fl);
            v *= ((sv >= 0.0f) ? 1.0f : -1.0f) * rsqrtf(nn);
        }
        xr3 = q0r; xr4 = v;
        if (lane < NN) {
            out[2501 + lane * 5 + 0] = xr0;
            out[2501 + lane * 5 + 1] = xr1;
            out[2501 + lane * 5 + 2] = xr2;
            out[2501 + lane * 5 + 3] = xr3;
            out[2501 + lane * 5 + 4] = xr4;
        }
    } else if (tid < 128) {
        // -------- wave 1: edges, counts (regs), prefix scan, CSR, ei out ----
        const int l = tid - 64;
        for (int t = l; t < ET; t += 64) {
            int s, d;
            if (t < E2) { s = gedge[t]; d = gedge[E2 + t]; }
            else        { s = t - E2;   d = t - E2; }
            sSrc[t] = s; sDst[t] = d;
        }
        WSYNC();
        int cnt = 0;
        if (l < NN)
            for (int e = 0; e < ET; ++e) cnt += (sDst[e] == l) ? 1 : 0;
        int inc = cnt;
#pragma unroll
        for (int off = 1; off < 64; off <<= 1) {
            int n = __shfl_up(inc, off);
            if (l >= off) inc += n;
        }
        int exc = inc - cnt;
        if (l < NN) sOff[l] = exc;
        if (l == NN - 1) sOff[NN] = inc;
        if (l < NN) {
            int pos = exc;
            for (int e = 0; e < ET; ++e)
                if (sDst[e] == l) { sSrcCsr[pos] = sSrc[e]; ++pos; }
        }
        for (int t = l; t < 2 * ET; t += 64) {
            int val = (t < ET) ? sSrc[t] : sDst[t - ET];
            out[2751 + t] = (float)val;
        }
    } else {
        // -------- waves 2-3: staging (issue all loads, then store) ----------
        const int t0 = tid - 128;
        float vW1  = w1 [t0 < 40 ? t0 : 39];
        float vAs1 = as1[t0 < 8  ? t0 : 7];
        float vAd1 = ad1[t0 < 8  ? t0 : 7];
        float vB1  = b1 [t0 < 8  ? t0 : 7];
        float vW2  = w2 [t0 < 40 ? t0 : 39];
        float vAs2 = as2[t0 < 5  ? t0 : 4];
        float vAd2 = ad2[t0 < 5  ? t0 : 4];
        float vB2  = b2 [t0 < 5  ? t0 : 4];
        float vMiw = miw[t0 < 75 ? t0 : 74];
        float vMib = mib[t0 < 15 ? t0 : 14];
        float vMow = mow[t0 < 25 ? t0 : 24];
        float vMob = mob[t0 < 5  ? t0 : 4];
        float vWq  = wq [t0 < 25 ? t0 : 24];
        float vBq  = bq [t0 < 5  ? t0 : 4];
        float vWk  = wk [t0 < 25 ? t0 : 24];
        float vBk  = bk [t0 < 5  ? t0 : 4];
        float vWv  = wv [t0 < 25 ? t0 : 24];
        float vBv  = bv [t0 < 5  ? t0 : 4];
        float vWs  = ws [t0 < 25 ? t0 : 24];
        float vBs  = bs [t0 < 5  ? t0 : 4];
        float vMb1 = mb1[t0 < 64 ? t0 : 63];
        float vMb2 = mb2[t0 < NN ? t0 : NN - 1];
        float vCw  = cw [t0 < NN ? t0 : NN - 1];
        float vCb  = cb[0];
        float vMsk = gmask[t0 < NN ? t0 : NN - 1];
        int ta = t0, tb2 = t0 + 128, tc = (t0 + 256 < 320) ? t0 + 256 : 319;
        float vM1a = mw1[(ta  / 5) * 250 + (ta  % 5)];
        float vM1b = mw1[(tb2 / 5) * 250 + (tb2 % 5)];
        float vM1c = mw1[(tc  / 5) * 250 + (tc  % 5)];
        const float4* m2 = (const float4*)mw2;
        float4 v2[7];
#pragma unroll
        for (int u = 0; u < 7; ++u) {
            int t = t0 + u * 128;
            v2[u] = m2[t < 800 ? t : 799];
        }
        if (t0 < 40) sW1[t0]  = vW1;
        if (t0 < 8)  { sAs1[t0] = vAs1; sAd1[t0] = vAd1; sB1[t0] = vB1; }
        if (t0 < 40) sW2[t0]  = vW2;
        if (t0 < 5)  { sAs2[t0] = vAs2; sAd2[t0] = vAd2; sB2[t0] = vB2; }
        if (t0 < 75) sMiw[t0] = vMiw;
        if (t0 < 15) sMib[t0] = vMib;
        if (t0 < 25) { sMow[t0] = vMow; sWq[t0] = vWq; sWk[t0] = vWk;
                       sWv[t0] = vWv;  sWsk[t0] = vWs; }
        if (t0 < 5)  { sMob[t0] = vMob; sBq[t0] = vBq; sBk[t0] = vBk;
                       sBv[t0] = vBv;  sBsk[t0] = vBs; }
        if (t0 < 64) sMb1[t0] = vMb1;
        if (t0 < NN) { sMb2[t0] = vMb2; sCw[t0] = vCw; sMask[t0] = vMsk; }
        if (t0 == 0) sCb0[0] = vCb;
        sMw1[ta]  = vM1a;
        sMw1[tb2] = vM1b;
        if (t0 + 256 < 320) sMw1[t0 + 256] = vM1c;
#pragma unroll
        for (int u = 0; u < 7; ++u) {
            int t = t0 + u * 128;
            if (t < 800) {
                int o = t >> 4, k4 = t & 15;
                *(float4*)&sMw2[o * MS + k4 * 4] = v2[u];
            }
        }
    }
    __syncthreads();   // join: weights + CSR visible to wave 0

    // ==== wave 0: fused 5-phase GNN tail ====
    if (tid < 64) {
        const int lane = tid;
        float* h8 = sS;
        // ---- P0: GAT1 linear + src coeff (dst coeff in reg) ----
        float adl = 0.0f;
        if (lane < NN) {
            float a = 0.0f;
#pragma unroll
            for (int o = 0; o < 8; ++o) {
                float acc = xr0 * sW1[o * 5 + 0] + xr1 * sW1[o * 5 + 1]
                          + xr2 * sW1[o * 5 + 2] + xr3 * sW1[o * 5 + 3]
                          + xr4 * sW1[o * 5 + 4];
                h8[lane * 8 + o] = acc;
                a   += acc * sAs1[o];
                adl += acc * sAd1[o];
            }
            sAs[lane] = a;
        }
        WSYNC();
        // ---- P1: GAT1 fused score+softmax+agg (no max-shift) + GAT2 linear --
        float adlB = 0.0f;
        if (lane < NN) {
            const int c0 = sOff[lane], c1 = sOff[lane + 1];
            float su = 0.0f;
            float acc[8] = {0, 0, 0, 0, 0, 0, 0, 0};
            for (int c = c0; c < c1; ++c) {
                const int s2 = sSrcCsr[c];
                float sc = sAs[s2] + adl;
                sc = (sc > 0.0f) ? sc : 0.2f * sc;
                float p = __expf(sc);
                su += p;
                const float* hp = &h8[s2 * 8];
#pragma unroll
                for (int o = 0; o < 8; ++o) acc[o] += p * hp[o];
            }
            float inv = 1.0f / (su + 1e-16f);
            float o8r[8];
#pragma unroll
            for (int o = 0; o < 8; ++o) o8r[o] = fmaxf(sB1[o] + acc[o] * inv, 0.0f);
            float aB = 0.0f;
#pragma unroll
            for (int o = 0; o < 5; ++o) {
                float a2 = 0.0f;
#pragma unroll
                for (int k = 0; k < 8; ++k) a2 += o8r[k] * sW2[o * 8 + k];
                sB5h[lane * 5 + o] = a2;
                aB   += a2 * sAs2[o];
                adlB += a2 * sAd2[o];
            }
            sAsB[lane] = aB;
        }
        WSYNC();
        // ---- P2: GAT2 fused agg + MHA in-proj ----
        float qr[5];
        if (lane < NN) {
            const int c0 = sOff[lane], c1 = sOff[lane + 1];
            float su = 0.0f;
            float acc[5] = {0, 0, 0, 0, 0};
            for (int c = c0; c < c1; ++c) {
                const int s2 = sSrcCsr[c];
                float sc = sAsB[s2] + adlB;
                sc = (sc > 0.0f) ? sc : 0.2f * sc;
                float p = __expf(sc);
                su += p;
                const float* hp = &sB5h[s2 * 5];
#pragma unroll
                for (int o = 0; o < 5; ++o) acc[o] += p * hp[o];
            }
            float inv = 1.0f / (su + 1e-16f);
            float hr[5];
#pragma unroll
            for (int o = 0; o < 5; ++o) hr[o] = sB2[o] + acc[o] * inv;
#pragma unroll
            for (int o = 0; o < 5; ++o) {
                float q_ = sMib[o], k_ = sMib[o + 5], v_ = sMib[o + 10];
#pragma unroll
                for (int k = 0; k < 5; ++k) {
                    q_ += hr[k] * sMiw[o * 5 + k];
                    k_ += hr[k] * sMiw[(o + 5) * 5 + k];
                    v_ += hr[k] * sMiw[(o + 10) * 5 + k];
                }
                qr[o] = q_;
                sKv[lane * 5 + o] = k_;
                sVv[lane * 5 + o] = v_;
            }
        }
        WSYNC();
        // ---- P3: MHA single-pass attn (no max-shift) + out-proj + TC linear -
        float tq[5], skip[5];
        if (lane < NN) {
            float su = 0.0f;
            float a5[5] = {0, 0, 0, 0, 0};
#pragma unroll 2
            for (int j = 0; j < NN; ++j) {
                const float* kp = &sKv[j * 5];
                float d = qr[0] * kp[0] + qr[1] * kp[1] + qr[2] * kp[2]
                        + qr[3] * kp[3] + qr[4] * kp[4];
                float p = __expf(d * inv_sqrt5);
                su += p;
                const float* vp = &sVv[j * 5];
#pragma unroll
                for (int f = 0; f < 5; ++f) a5[f] += p * vp[f];
            }
            float inv = 1.0f / su;
#pragma unroll
            for (int f = 0; f < 5; ++f) a5[f] *= inv;
            float hm[5];
#pragma unroll
            for (int o = 0; o < 5; ++o) {
                float acc = sMob[o];
#pragma unroll
                for (int k = 0; k < 5; ++k) acc += a5[k] * sMow[o * 5 + k];
                hm[o] = acc;
            }
#pragma unroll
            for (int o = 0; o < 5; ++o) {
                float q_ = sBq[o], k_ = sBk[o], v_ = sBv[o], s_ = sBsk[o];
#pragma unroll
                for (int k = 0; k < 5; ++k) {
                    q_ += hm[k] * sWq[o * 5 + k];
                    k_ += hm[k] * sWk[o * 5 + k];
                    v_ += hm[k] * sWv[o * 5 + k];
                    s_ += hm[k] * sWsk[o * 5 + k];
                }
                tq[o] = q_;
                sTk[lane * 5 + o] = k_;
                sTv[lane * 5 + o] = v_;
                skip[o] = s_;
            }
        }
        WSYNC();
        // ---- P4: TC fused score+softmax+agg + skip ----
        if (lane < NN) {
            const int c0 = sOff[lane], c1 = sOff[lane + 1];
            float su = 0.0f;
            float acc[5] = {0, 0, 0, 0, 0};
            for (int c = c0; c < c1; ++c) {
                const int s2 = sSrcCsr[c];
                const float* kp = &sTk[s2 * 5];
                float d = tq[0] * kp[0] + tq[1] * kp[1] + tq[2] * kp[2]
                        + tq[3] * kp[3] + tq[4] * kp[4];
                float p = __expf(d * inv_sqrt5);
                su += p;
                const float* vp = &sTv[s2 * 5];
#pragma unroll
                for (int o = 0; o < 5; ++o) acc[o] += p * vp[o];
            }
            float inv = 1.0f / (su + 1e-16f);
#pragma unroll
            for (int o = 0; o < 5; ++o) sTo[lane * 5 + o] = skip[o] + acc[o] * inv;
        }
        WSYNC();
        // ---- P5: MLP1 (lane = hidden unit) ----
        {
            float wv5[5];
#pragma unroll
            for (int k = 0; k < 5; ++k) wv5[k] = sMw1[lane * 5 + k];
            const float bo = sMb1[lane];
            for (int i = 0; i < NN; ++i) {
                float acc = bo;
#pragma unroll
                for (int k = 0; k < 5; ++k) acc += sTo[i * 5 + k] * wv5[k];
                sS[i * 64 + lane] = fmaxf(acc, 0.0f);
            }
        }
    }
    __syncthreads();

    // ---------------- MLP2 + fused critic (4 waves) ----------------
    float part = 0.0f;
    for (int t = tid; t < NN * NN; t += NTHR) {
        int i = t / NN, j = t - i * NN;
        const float4* sp4 = (const float4*)&sS[i * 64];
        const float4* wp4 = (const float4*)&sMw2[j * MS];
        float a0 = 0.0f, a1 = 0.0f, a2 = 0.0f, a3 = 0.0f;
        for (int k = 0; k < 16; ++k) {
            float4 a = sp4[k], b = wp4[k];
            a0 += a.x * b.x; a1 += a.y * b.y;
            a2 += a.z * b.z; a3 += a.w * b.w;
        }
        float acc = sMb2[j] + (a0 + a1) + (a2 + a3);
        out[t] = acc * sMask[j];
        part += acc * sCw[j];
    }
    for (int off = 32; off > 0; off >>= 1) part += __shfl_xor(part, off);
    if ((tid & 63) == 0) sred[tid >> 6] = part;
    __syncthreads();
    if (tid == 0)
        out[2500] = (sred[0] + sred[1] + sred[2] + sred[3]) * (1.0f / NN) + sCb0[0];
}

extern "C" void kernel_launch(void* const* d_in, const int* in_sizes, int n_in,
                              void* d_out, int out_size, void* d_ws, size_t ws_size,
                              hipStream_t stream) {
    (void)in_sizes; (void)n_in; (void)d_ws; (void)ws_size; (void)out_size;
    opn_kernel<<<1, NTHR, 0, stream>>>(
        (const float*)d_in[0], (const int*)d_in[1], (const float*)d_in[2],
        (const float*)d_in[3], (const float*)d_in[4], (const float*)d_in[5], (const float*)d_in[6],
        (const float*)d_in[7], (const float*)d_in[8], (const float*)d_in[9], (const float*)d_in[10],
        (const float*)d_in[11], (const float*)d_in[12], (const float*)d_in[13], (const float*)d_in[14],
        (const float*)d_in[15], (const float*)d_in[16], (const float*)d_in[17], (const float*)d_in[18],
        (const float*)d_in[19], (const float*)d_in[20], (const float*)d_in[21], (const float*)d_in[22],
        (const float*)d_in[23], (const float*)d_in[24], (const float*)d_in[25], (const float*)d_in[26],
        (const float*)d_in[27], (const float*)d_in[28],
        (float*)d_out);
}